// Round 7
// baseline (1885.286 us; speedup 1.0000x reference)
//
#include <hip/hip_runtime.h>
#include <math.h>

#define HH 96
#define WW 96
#define HW 9216
#define TT 5

typedef __attribute__((ext_vector_type(8))) short bf16x8;
typedef __attribute__((ext_vector_type(4))) float f32x4;

__device__ __forceinline__ float sigf(float x) { return 1.0f / (1.0f + expf(-x)); }
__device__ __forceinline__ unsigned short bhi(float x) {
    return (unsigned short)(__float_as_uint(x) >> 16);
}
__device__ __forceinline__ unsigned short blo(float x) {
    float h = __uint_as_float(__float_as_uint(x) & 0xffff0000u);
    return (unsigned short)(__float_as_uint(x - h) >> 16);
}
__device__ __forceinline__ float b2f(unsigned short u) {
    return __uint_as_float(((unsigned)u) << 16);
}

// ---------------------------------------------------------------------------
// Weight expansion: src [OC][IC][9] fp32 -> dst [9][OCP][2][IC] bf16 hi/lo.
// ---------------------------------------------------------------------------
__global__ __launch_bounds__(256) void wexp3_kernel(
    const float* __restrict__ w, unsigned short* __restrict__ dst,
    int OC, int OCP, int IC)
{
    long i = (long)blockIdx.x * 256 + threadIdx.x;
    int ic = (int)(i % IC);
    long r = i / IC;
    int oc = (int)(r % OCP);
    int tap = (int)(r / OCP);
    float v = (oc < OC) ? w[((long)oc * IC + ic) * 9 + tap] : 0.f;
    long base = (((long)tap * OCP + oc) * 2) * IC + ic;
    dst[base] = bhi(v);
    dst[base + IC] = blo(v);
}

// dcn_w [128][576] (576 = c*9+k) -> [128][2][576] with K re-ordered k-major:
// dst K-slot (k*64 + c) = src (c*9 + k).
__global__ __launch_bounds__(256) void wexp1_kernel(
    const float* __restrict__ w, unsigned short* __restrict__ dst)
{
    int i = blockIdx.x * 256 + threadIdx.x;   // over 128*576 dst slots
    int slot = i % 576;                        // k*64 + c
    int oc = i / 576;
    int k = slot >> 6, c = slot & 63;
    float v = w[(long)oc * 576 + c * 9 + k];
    dst[((long)oc * 2) * 576 + slot] = bhi(v);
    dst[((long)oc * 2 + 1) * 576 + slot] = blo(v);
}

// input [b][t][64][HW] fp32 -> xbf [(t*2+b)][p][64] bf16
__global__ __launch_bounds__(256) void xprep_kernel(
    const float* __restrict__ input, unsigned short* __restrict__ xbf)
{
    long i = (long)blockIdx.x * 256 + threadIdx.x;
    int p = (int)(i % HW);
    long r = i / HW;
    int c = (int)(r % 64);
    long bt = r / 64;
    int b = (int)(bt / TT), t = (int)(bt % TT);
    float v = input[i];
    xbf[(((long)(t * 2 + b) * HW) + p) * 64 + c] = bhi(v);
}

// ===========================================================================
// Conv kernels: pixel tile 4x16 (64 px), halo 6x18=108 cells.
// big_conv_gates: two-phase channel staging halves its LDS so 4 blocks/CU
// fit -> all 576 blocks co-resident (the residency win of round 4) while
// keeping acc[2][4]=32 f32 which fits the 64-VGPR schedule with NO spill
// (round 4/5's acc[2][6]=48 spilled 37.7 MB to scratch; the 64-VGPR cap
// has survived launch_bounds, waves_per_eu, and source prefetch attempts).
// ===========================================================================

// ---------------------------------------------------------------------------
// Fuse conv: x (single, ic 0..63) + h (hl, ic 64..127) -> comb bf16 NHWC.
// ---------------------------------------------------------------------------
__global__ __launch_bounds__(256) void fuse_conv(
    const unsigned short* __restrict__ xbf,
    const unsigned short* __restrict__ hbuf,
    const unsigned short* __restrict__ Wf,   // [9][64][2][128]
    const float* __restrict__ bias,
    unsigned short* __restrict__ comb,
    int t0, int t1)
{
    __shared__ unsigned short sX[108 * 200];
    const int tid = threadIdx.x;
    const int wave = tid >> 6, lane = tid & 63;
    const int m = lane & 15, quad = lane >> 4;
    const int tY = blockIdx.x / 6, tX = blockIdx.x % 6;
    const int z = blockIdx.z;
    const int imgX = ((z < 2) ? t0 : t1) * 2 + (z & 1);

    const unsigned short* xb = xbf + (long)imgX * HW * 64;
    const unsigned short* hb = hbuf + (long)z * HW * 128;

    for (int i = tid; i < 108 * 24; i += 256) {
        int cell = i / 24, v = i - cell * 24;
        int row = cell / 18, col = cell - row * 18;
        int gy = tY * 4 + row - 1, gx = tX * 16 + col - 1;
        bool ok = (gy >= 0 && gy < HH && gx >= 0 && gx < WW);
        int p = gy * WW + gx;
        bf16x8 val = (bf16x8){0,0,0,0,0,0,0,0};
        int dst;
        if (v < 8) {
            if (ok) val = *(const bf16x8*)(xb + (long)p * 64 + v * 8);
            dst = cell * 200 + v * 8;
        } else {
            int v2 = v - 8;
            int pl = v2 >> 3, c = (v2 & 7) >> 2, g = v2 & 3;
            if (ok) val = *(const bf16x8*)(hb + (long)p * 128 + pl * 64 + c * 32 + g * 8);
            dst = cell * 200 + 64 + (c * 2 + pl) * 32 + g * 8;
        }
        *(bf16x8*)&sX[dst] = val;
    }
    __syncthreads();

    f32x4 acc[4];
#pragma unroll
    for (int nf = 0; nf < 4; ++nf) acc[nf] = (f32x4){0.f, 0.f, 0.f, 0.f};

#pragma unroll
    for (int c = 0; c < 2; ++c) {
#pragma unroll
        for (int kx = 0; kx < 3; ++kx) {
            bf16x8 B[6];
#pragma unroll
            for (int r = 0; r < 6; ++r)
                B[r] = *(const bf16x8*)&sX[(r * 18 + kx + m) * 200 + c * 32 + quad * 8];
            bf16x8 Ah[3], Al[3];
#pragma unroll
            for (int ky = 0; ky < 3; ++ky) {
                const unsigned short* wp = Wf + (((long)(ky * 3 + kx) * 64 + wave * 16 + m) * 2) * 128 + c * 32 + quad * 8;
                Ah[ky] = *(const bf16x8*)wp;
                Al[ky] = *(const bf16x8*)(wp + 128);
            }
#pragma unroll
            for (int ky = 0; ky < 3; ++ky)
#pragma unroll
                for (int nf = 0; nf < 4; ++nf) {
                    acc[nf] = __builtin_amdgcn_mfma_f32_16x16x32_bf16(Ah[ky], B[nf + ky], acc[nf], 0, 0, 0);
                    acc[nf] = __builtin_amdgcn_mfma_f32_16x16x32_bf16(Al[ky], B[nf + ky], acc[nf], 0, 0, 0);
                }
        }
    }
#pragma unroll
    for (int c = 0; c < 2; ++c) {
#pragma unroll
        for (int kx = 0; kx < 3; ++kx) {
            bf16x8 Bh[6], Bl[6];
#pragma unroll
            for (int r = 0; r < 6; ++r) {
                int base = (r * 18 + kx + m) * 200 + 64 + (c * 2) * 32 + quad * 8;
                Bh[r] = *(const bf16x8*)&sX[base];
                Bl[r] = *(const bf16x8*)&sX[base + 32];
            }
            bf16x8 Ah[3], Al[3];
#pragma unroll
            for (int ky = 0; ky < 3; ++ky) {
                const unsigned short* wp = Wf + (((long)(ky * 3 + kx) * 64 + wave * 16 + m) * 2) * 128 + (2 + c) * 32 + quad * 8;
                Ah[ky] = *(const bf16x8*)wp;
                Al[ky] = *(const bf16x8*)(wp + 128);
            }
#pragma unroll
            for (int ky = 0; ky < 3; ++ky)
#pragma unroll
                for (int nf = 0; nf < 4; ++nf) {
                    acc[nf] = __builtin_amdgcn_mfma_f32_16x16x32_bf16(Ah[ky], Bh[nf + ky], acc[nf], 0, 0, 0);
                    acc[nf] = __builtin_amdgcn_mfma_f32_16x16x32_bf16(Al[ky], Bh[nf + ky], acc[nf], 0, 0, 0);
                    acc[nf] = __builtin_amdgcn_mfma_f32_16x16x32_bf16(Ah[ky], Bl[nf + ky], acc[nf], 0, 0, 0);
                }
        }
    }

    int ocl = wave * 16 + quad * 4;
    float b0 = bias[ocl], b1 = bias[ocl + 1], b2 = bias[ocl + 2], b3 = bias[ocl + 3];
#pragma unroll
    for (int nf = 0; nf < 4; ++nf) {
        int p = (tY * 4 + nf) * WW + tX * 16 + m;
        ushort4 hv;
        hv.x = bhi(acc[nf].x + b0); hv.y = bhi(acc[nf].y + b1);
        hv.z = bhi(acc[nf].z + b2); hv.w = bhi(acc[nf].w + b3);
        *(ushort4*)&comb[((long)z * HW + p) * 64 + ocl] = hv;
    }
}

// ---------------------------------------------------------------------------
// om conv: comb (single, IC=64) -> om fp32 NCHW (216 of 256 oc).
// ---------------------------------------------------------------------------
__global__ __launch_bounds__(512) void om_conv(
    const unsigned short* __restrict__ comb,
    const unsigned short* __restrict__ Wo,   // [9][256][2][64]
    const float* __restrict__ bias,
    float* __restrict__ om)                  // [z][216][HW]
{
    __shared__ unsigned short sX[108 * 72];
    const int tid = threadIdx.x;
    const int wave = tid >> 6, lane = tid & 63;
    const int m = lane & 15, quad = lane >> 4;
    const int tY = blockIdx.x / 6, tX = blockIdx.x % 6;
    const int z = blockIdx.z;
    const unsigned short* cbp = comb + (long)z * HW * 64;

    for (int i = tid; i < 108 * 8; i += 512) {
        int cell = i >> 3, v = i & 7;
        int row = cell / 18, col = cell - row * 18;
        int gy = tY * 4 + row - 1, gx = tX * 16 + col - 1;
        bf16x8 val = (bf16x8){0,0,0,0,0,0,0,0};
        if (gy >= 0 && gy < HH && gx >= 0 && gx < WW)
            val = *(const bf16x8*)(cbp + (long)(gy * WW + gx) * 64 + v * 8);
        *(bf16x8*)&sX[cell * 72 + v * 8] = val;
    }
    __syncthreads();

    f32x4 acc[2][4];
#pragma unroll
    for (int mi = 0; mi < 2; ++mi)
#pragma unroll
        for (int nf = 0; nf < 4; ++nf) acc[mi][nf] = (f32x4){0.f, 0.f, 0.f, 0.f};

#pragma unroll
    for (int c = 0; c < 2; ++c) {
#pragma unroll
        for (int kx = 0; kx < 3; ++kx) {
            bf16x8 B[6];
#pragma unroll
            for (int r = 0; r < 6; ++r)
                B[r] = *(const bf16x8*)&sX[(r * 18 + kx + m) * 72 + c * 32 + quad * 8];
            bf16x8 Ah[3][2], Al[3][2];
#pragma unroll
            for (int ky = 0; ky < 3; ++ky)
#pragma unroll
                for (int mi = 0; mi < 2; ++mi) {
                    const unsigned short* wp = Wo + (((long)(ky * 3 + kx) * 256 + (wave * 2 + mi) * 16 + m) * 2) * 64 + c * 32 + quad * 8;
                    Ah[ky][mi] = *(const bf16x8*)wp;
                    Al[ky][mi] = *(const bf16x8*)(wp + 64);
                }
#pragma unroll
            for (int ky = 0; ky < 3; ++ky)
#pragma unroll
                for (int mi = 0; mi < 2; ++mi)
#pragma unroll
                    for (int nf = 0; nf < 4; ++nf) {
                        acc[mi][nf] = __builtin_amdgcn_mfma_f32_16x16x32_bf16(Ah[ky][mi], B[nf + ky], acc[mi][nf], 0, 0, 0);
                        acc[mi][nf] = __builtin_amdgcn_mfma_f32_16x16x32_bf16(Al[ky][mi], B[nf + ky], acc[mi][nf], 0, 0, 0);
                    }
        }
    }

#pragma unroll
    for (int mi = 0; mi < 2; ++mi) {
#pragma unroll
        for (int reg = 0; reg < 4; ++reg) {
            int oc = (wave * 2 + mi) * 16 + quad * 4 + reg;
            if (oc < 216) {
                float bv = bias[oc];
#pragma unroll
                for (int nf = 0; nf < 4; ++nf) {
                    int p = (tY * 4 + nf) * WW + tX * 16 + m;
                    om[((long)z * 216 + oc) * HW + p] = acc[mi][nf][reg] + bv;
                }
            }
        }
    }
}

// ---------------------------------------------------------------------------
// Deformable sampling. Output K is k-major: samp[(z*HW+p)*576 + k*64 + c].
// Each thread writes ONE contiguous bf16x8 (16 B).
// ---------------------------------------------------------------------------
__global__ __launch_bounds__(256) void dcn_sample_kernel(
    const unsigned short* __restrict__ hbuf,  // [4][p][128] hl
    const float* __restrict__ om,             // [4][216][HW]
    unsigned short* __restrict__ samp)        // [4][p][576] k-major
{
    int i = blockIdx.x * 256 + threadIdx.x;   // 4*G*KK*HW
    int p = i % HW;
    int r = i / HW;
    int k = r % 9;
    int g = (r / 9) % 8;
    int zz = r / 72;
    int y = p / WW, x = p - (p / WW) * WW;
    int ky = k / 3, kx = k - ky * 3;

    const float* omb = om + (long)zz * 216 * HW;
    float offy = omb[(g * 18 + k * 2) * HW + p];
    float offx = omb[(g * 18 + k * 2 + 1) * HW + p];
    float mm = sigf(omb[(144 + g * 9 + k) * HW + p]);

    float py = (float)(y + ky - 1) + offy;
    float px = (float)(x + kx - 1) + offx;
    float y0f = floorf(py), x0f = floorf(px);
    float wy = py - y0f, wx = px - x0f;
    int y0 = (int)y0f, x0 = (int)x0f;
    int y1 = y0 + 1, x1 = x0 + 1;

    bool vy0 = (y0 >= 0) && (y0 < HH), vy1 = (y1 >= 0) && (y1 < HH);
    bool vx0 = (x0 >= 0) && (x0 < WW), vx1 = (x1 >= 0) && (x1 < WW);
    int cy0 = min(max(y0, 0), HH - 1), cy1 = min(max(y1, 0), HH - 1);
    int cx0 = min(max(x0, 0), WW - 1), cx1 = min(max(x1, 0), WW - 1);
    long i00 = cy0 * WW + cx0, i01 = cy0 * WW + cx1;
    long i10 = cy1 * WW + cx0, i11 = cy1 * WW + cx1;
    float w00 = (1.f - wy) * (1.f - wx) * ((vy0 && vx0) ? mm : 0.f);
    float w01 = (1.f - wy) * wx         * ((vy0 && vx1) ? mm : 0.f);
    float w10 = wy * (1.f - wx)         * ((vy1 && vx0) ? mm : 0.f);
    float w11 = wy * wx                 * ((vy1 && vx1) ? mm : 0.f);

    const unsigned short* hzb = hbuf + (long)zz * HW * 128 + g * 8;
    bf16x8 h00 = *(const bf16x8*)(hzb + i00 * 128);
    bf16x8 l00 = *(const bf16x8*)(hzb + i00 * 128 + 64);
    bf16x8 h01 = *(const bf16x8*)(hzb + i01 * 128);
    bf16x8 l01 = *(const bf16x8*)(hzb + i01 * 128 + 64);
    bf16x8 h10 = *(const bf16x8*)(hzb + i10 * 128);
    bf16x8 l10 = *(const bf16x8*)(hzb + i10 * 128 + 64);
    bf16x8 h11 = *(const bf16x8*)(hzb + i11 * 128);
    bf16x8 l11 = *(const bf16x8*)(hzb + i11 * 128 + 64);

    bf16x8 outv;
#pragma unroll
    for (int cg = 0; cg < 8; ++cg) {
        float v00 = b2f((unsigned short)h00[cg]) + b2f((unsigned short)l00[cg]);
        float v01 = b2f((unsigned short)h01[cg]) + b2f((unsigned short)l01[cg]);
        float v10 = b2f((unsigned short)h10[cg]) + b2f((unsigned short)l10[cg]);
        float v11 = b2f((unsigned short)h11[cg]) + b2f((unsigned short)l11[cg]);
        float v = w00 * v00 + w01 * v01 + w10 * v10 + w11 * v11;
        outv[cg] = (short)bhi(v);
    }
    *(bf16x8*)(samp + ((long)zz * HW + p) * 576 + k * 64 + g * 8) = outv;
}

// ---------------------------------------------------------------------------
// 1x1 DCN einsum (pipelined). K ordering is k-major to match samp/W1.
// ---------------------------------------------------------------------------
__global__ __launch_bounds__(256) void conv1x1_hl(
    const unsigned short* __restrict__ samp,
    const unsigned short* __restrict__ w1,   // [128][2][576] k-major
    const float* __restrict__ bias,
    unsigned short* __restrict__ fused)      // [z][p][256] hl
{
    __shared__ unsigned short sX[64 * 76];
    const int tid  = threadIdx.x;
    const int wave = tid >> 6, lane = tid & 63;
    const int m = lane & 15, quad = lane >> 4;
    const int pt = blockIdx.x;
    const int zz = blockIdx.y;

    const unsigned short* sbase = samp + (long)zz * HW * 576 + (long)pt * 64 * 576;
    const int cell0 = tid >> 3, g0 = tid & 7;
    const int cell1 = (tid + 256) >> 3, g1 = tid & 7;

    bf16x8 R0, R1;
    auto loadCB = [&](int cb) {
        R0 = *(const bf16x8*)(sbase + (long)cell0 * 576 + cb * 64 + g0 * 8);
        R1 = *(const bf16x8*)(sbase + (long)cell1 * 576 + cb * 64 + g1 * 8);
    };

    f32x4 acc[2][4];
#pragma unroll
    for (int mm = 0; mm < 2; ++mm)
#pragma unroll
        for (int nf = 0; nf < 4; ++nf) acc[mm][nf] = (f32x4){0.f, 0.f, 0.f, 0.f};

    loadCB(0);
    for (int cb = 0; cb < 9; ++cb) {
        if (cb) __syncthreads();
        *(bf16x8*)&sX[cell0 * 76 + g0 * 8] = R0;
        *(bf16x8*)&sX[cell1 * 76 + g1 * 8] = R1;
        __syncthreads();
        if (cb + 1 < 9) loadCB(cb + 1);

        bf16x8 Bv[2][4];
#pragma unroll
        for (int sub = 0; sub < 2; ++sub)
#pragma unroll
            for (int nf = 0; nf < 4; ++nf)
                Bv[sub][nf] = *(const bf16x8*)&sX[(nf * 16 + m) * 76 + sub * 32 + quad * 8];
        bf16x8 Ah[2][2], Al[2][2];
#pragma unroll
        for (int sub = 0; sub < 2; ++sub)
#pragma unroll
            for (int mm = 0; mm < 2; ++mm) {
                const unsigned short* wp = w1 + ((long)((wave * 2 + mm) * 16 + m) * 2) * 576
                                           + cb * 64 + sub * 32 + quad * 8;
                Ah[sub][mm] = *(const bf16x8*)wp;
                Al[sub][mm] = *(const bf16x8*)(wp + 576);
            }
#pragma unroll
        for (int sub = 0; sub < 2; ++sub)
#pragma unroll
            for (int mm = 0; mm < 2; ++mm)
#pragma unroll
                for (int nf = 0; nf < 4; ++nf) {
                    acc[mm][nf] = __builtin_amdgcn_mfma_f32_16x16x32_bf16(
                        Ah[sub][mm], Bv[sub][nf], acc[mm][nf], 0, 0, 0);
                    acc[mm][nf] = __builtin_amdgcn_mfma_f32_16x16x32_bf16(
                        Al[sub][mm], Bv[sub][nf], acc[mm][nf], 0, 0, 0);
                }
    }

#pragma unroll
    for (int mm = 0; mm < 2; ++mm) {
        int ocl = (wave * 2 + mm) * 16 + quad * 4;
        float b0 = bias[ocl], b1 = bias[ocl + 1], b2 = bias[ocl + 2], b3 = bias[ocl + 3];
#pragma unroll
        for (int nf = 0; nf < 4; ++nf) {
            int p = pt * 64 + nf * 16 + m;
            float v0 = fmaxf(acc[mm][nf].x + b0, 0.f);
            float v1 = fmaxf(acc[mm][nf].y + b1, 0.f);
            float v2 = fmaxf(acc[mm][nf].z + b2, 0.f);
            float v3 = fmaxf(acc[mm][nf].w + b3, 0.f);
            unsigned short* op = fused + ((long)zz * HW + p) * 256 + ocl;
            ushort4 hv, lv;
            hv.x = bhi(v0); hv.y = bhi(v1); hv.z = bhi(v2); hv.w = bhi(v3);
            lv.x = blo(v0); lv.y = blo(v1); lv.z = blo(v2); lv.w = blo(v3);
            *(ushort4*)op = hv;
            *(ushort4*)(op + 128) = lv;
        }
    }
}

// ---------------------------------------------------------------------------
// Big conv (IC=128 hl, OC=256) FUSED with LSTM gates.
// Pixel tile 4x16; TWO-PHASE channel staging: stage c={0,1} (28.5 KB), MFMA,
// barrier, stage c={2,3} into the same buffer, MFMA. LDS = max(28.5 KB,
// 34.8 KB gates region) = 34.8 KB -> 4 blocks/CU (wave-capped) -> all 576
// blocks co-resident (round-0's 57 KB gave only 2/CU -> 40% serialization
// tail). acc[2][4]=32 f32 fits the 64-VGPR schedule with no scratch spill
// (proven round 0); global c-order 0,1,2,3 preserved -> identical numerics.
// ---------------------------------------------------------------------------
__global__ __launch_bounds__(512) void big_conv_gates(
    const unsigned short* __restrict__ fusedb,  // [z][p][256] hl
    const unsigned short* __restrict__ Wc,      // [9][256][2][128]
    const float* __restrict__ bias,
    float* __restrict__ cst,                    // [z][p][64] fp32
    unsigned short* __restrict__ hbuf,          // [z][p][128] hl
    unsigned short* __restrict__ hseq,          // [(t*2+b)][p][128]
    int t0, int t1)
{
    // 17408 ush = 34816 B: staging uses 108*132=14256, gates use 8704 floats.
    __shared__ unsigned short sX[17408];
    const int tid = threadIdx.x;
    const int wave = tid >> 6, lane = tid & 63;
    const int m = lane & 15, quad = lane >> 4;
    const int tY = blockIdx.x / 6, tX = blockIdx.x % 6;
    const int z = blockIdx.z;

    const unsigned short* fb = fusedb + (long)z * HW * 256;

    f32x4 acc[2][4];
#pragma unroll
    for (int mi = 0; mi < 2; ++mi)
#pragma unroll
        for (int nf = 0; nf < 4; ++nf) acc[mi][nf] = (f32x4){0.f, 0.f, 0.f, 0.f};

#pragma unroll
    for (int h = 0; h < 2; ++h) {
        if (h) __syncthreads();   // prior half's MFMAs must finish before overwrite
        // stage channels c = {2h, 2h+1}: per cell 2c x 2pl x 4g bf16x8 = 16 vals
        for (int i = tid; i < 108 * 16; i += 512) {
            int cell = i >> 4, v = i & 15;
            int row = cell / 18, col = cell - row * 18;
            int gy = tY * 4 + row - 1, gx = tX * 16 + col - 1;
            int cl = v >> 3, pl = (v >> 2) & 1, g = v & 3;
            bf16x8 val = (bf16x8){0,0,0,0,0,0,0,0};
            if (gy >= 0 && gy < HH && gx >= 0 && gx < WW)
                val = *(const bf16x8*)(fb + (long)(gy * WW + gx) * 256 + pl * 128 + (h * 2 + cl) * 32 + g * 8);
            *(bf16x8*)&sX[cell * 132 + (cl * 2 + pl) * 32 + g * 8] = val;
        }
        __syncthreads();

#pragma unroll
        for (int cl = 0; cl < 2; ++cl) {
            const int c = h * 2 + cl;
#pragma unroll
            for (int kx = 0; kx < 3; ++kx) {
                bf16x8 Bh[6], Bl[6];
#pragma unroll
                for (int r = 0; r < 6; ++r) {
                    int base = (r * 18 + kx + m) * 132 + (cl * 2) * 32 + quad * 8;
                    Bh[r] = *(const bf16x8*)&sX[base];
                    Bl[r] = *(const bf16x8*)&sX[base + 32];
                }
                bf16x8 Ah[3][2], Al[3][2];
#pragma unroll
                for (int ky = 0; ky < 3; ++ky)
#pragma unroll
                    for (int mi = 0; mi < 2; ++mi) {
                        int mig = wave + mi * 8;
                        const unsigned short* wp = Wc + (((long)(ky * 3 + kx) * 256 + mig * 16 + m) * 2) * 128 + c * 32 + quad * 8;
                        Ah[ky][mi] = *(const bf16x8*)wp;
                        Al[ky][mi] = *(const bf16x8*)(wp + 128);
                    }
#pragma unroll
                for (int ky = 0; ky < 3; ++ky)
#pragma unroll
                    for (int mi = 0; mi < 2; ++mi)
#pragma unroll
                        for (int nf = 0; nf < 4; ++nf) {
                            acc[mi][nf] = __builtin_amdgcn_mfma_f32_16x16x32_bf16(Ah[ky][mi], Bh[nf + ky], acc[mi][nf], 0, 0, 0);
                            acc[mi][nf] = __builtin_amdgcn_mfma_f32_16x16x32_bf16(Al[ky][mi], Bh[nf + ky], acc[mi][nf], 0, 0, 0);
                            acc[mi][nf] = __builtin_amdgcn_mfma_f32_16x16x32_bf16(Ah[ky][mi], Bl[nf + ky], acc[mi][nf], 0, 0, 0);
                        }
            }
        }
    }

    // ---- gates epilogue ----
    float* sG = (float*)sX;
    float ba0[4], ba1[4];
    {
        int oc0 = wave * 16 + quad * 4;
        int oc1 = (wave + 8) * 16 + quad * 4;
#pragma unroll
        for (int r = 0; r < 4; ++r) { ba0[r] = bias[oc0 + r]; ba1[r] = bias[oc1 + r]; }
    }
    __syncthreads();
    if (wave >= 4) {
        int chb = (wave - 4) * 16 + quad * 4;
#pragma unroll
        for (int nf = 0; nf < 4; ++nf) {
            int px = nf * 16 + m;
            float* f0 = &sG[(long)px * 68 + chb];
            float* f1 = &sG[64 * 68 + (long)px * 68 + chb];
#pragma unroll
            for (int r = 0; r < 4; ++r) {
                f0[r] = acc[0][nf][r] + ba0[r];
                f1[r] = acc[1][nf][r] + ba1[r];
            }
        }
    }
    __syncthreads();
    if (wave < 4) {
        int t = (z < 2) ? t0 : t1;
        int b = z & 1, dir = z >> 1;
        int chb = wave * 16 + quad * 4;
        unsigned short* hsq = hseq + ((long)(t * 2 + b) * HW) * 128 + dir * 64;
#pragma unroll
        for (int nf = 0; nf < 4; ++nf) {
            int px = nf * 16 + m;
            int p = (tY * 4 + nf) * WW + tX * 16 + m;
            float4 cf4 = *(float4*)&sG[(long)px * 68 + chb];
            float4 cg4 = *(float4*)&sG[64 * 68 + (long)px * 68 + chb];
            float* cp = &cst[((long)z * HW + p) * 64 + chb];
            float4 cold = *(float4*)cp;
            float cfv[4] = {cf4.x, cf4.y, cf4.z, cf4.w};
            float cgv[4] = {cg4.x, cg4.y, cg4.z, cg4.w};
            float coldv[4] = {cold.x, cold.y, cold.z, cold.w};
            float c2v[4], h2v[4];
#pragma unroll
            for (int r = 0; r < 4; ++r) {
                float civ = acc[0][nf][r] + ba0[r];
                float cov = acc[1][nf][r] + ba1[r];
                float c2 = sigf(cfv[r]) * coldv[r] + sigf(civ) * tanhf(cgv[r]);
                float h2 = sigf(cov) * tanhf(c2);
                c2v[r] = c2; h2v[r] = h2;
            }
            *(float4*)cp = (float4){c2v[0], c2v[1], c2v[2], c2v[3]};
            unsigned short* hp = hbuf + ((long)z * HW + p) * 128 + chb;
            ushort4 hv = {bhi(h2v[0]), bhi(h2v[1]), bhi(h2v[2]), bhi(h2v[3])};
            ushort4 lv = {blo(h2v[0]), blo(h2v[1]), blo(h2v[2]), blo(h2v[3])};
            *(ushort4*)hp = hv;
            *(ushort4*)(hp + 64) = lv;
            *(ushort4*)&hsq[(long)p * 128 + chb] = hv;
        }
    }
}

// ---------------------------------------------------------------------------
// cat conv: hseq (single-plane, IC=128) -> out fp32 NCHW with (t,b) permute.
// ---------------------------------------------------------------------------
__global__ __launch_bounds__(256) void cat_conv(
    const unsigned short* __restrict__ hseq,
    const unsigned short* __restrict__ Wk,     // [9][64][2][128]
    const float* __restrict__ bias,
    float* __restrict__ out)
{
    __shared__ unsigned short sX[108 * 136];
    const int tid = threadIdx.x;
    const int wave = tid >> 6, lane = tid & 63;
    const int m = lane & 15, quad = lane >> 4;
    const int tY = blockIdx.x / 6, tX = blockIdx.x % 6;
    const int img = blockIdx.z;
    const unsigned short* hp = hseq + (long)img * HW * 128;

    for (int i = tid; i < 108 * 16; i += 256) {
        int cell = i >> 4, v = i & 15;
        int row = cell / 18, col = cell - row * 18;
        int gy = tY * 4 + row - 1, gx = tX * 16 + col - 1;
        bf16x8 val = (bf16x8){0,0,0,0,0,0,0,0};
        if (gy >= 0 && gy < HH && gx >= 0 && gx < WW)
            val = *(const bf16x8*)(hp + (long)(gy * WW + gx) * 128 + v * 8);
        *(bf16x8*)&sX[cell * 136 + v * 8] = val;
    }
    __syncthreads();

    f32x4 acc[4];
#pragma unroll
    for (int nf = 0; nf < 4; ++nf) acc[nf] = (f32x4){0.f, 0.f, 0.f, 0.f};

#pragma unroll
    for (int c = 0; c < 4; ++c) {
#pragma unroll
        for (int kx = 0; kx < 3; ++kx) {
            bf16x8 B[6];
#pragma unroll
            for (int r = 0; r < 6; ++r)
                B[r] = *(const bf16x8*)&sX[(r * 18 + kx + m) * 136 + c * 32 + quad * 8];
            bf16x8 Ah[3], Al[3];
#pragma unroll
            for (int ky = 0; ky < 3; ++ky) {
                const unsigned short* wp = Wk + (((long)(ky * 3 + kx) * 64 + wave * 16 + m) * 2) * 128 + c * 32 + quad * 8;
                Ah[ky] = *(const bf16x8*)wp;
                Al[ky] = *(const bf16x8*)(wp + 128);
            }
#pragma unroll
            for (int ky = 0; ky < 3; ++ky)
#pragma unroll
                for (int nf = 0; nf < 4; ++nf) {
                    acc[nf] = __builtin_amdgcn_mfma_f32_16x16x32_bf16(Ah[ky], B[nf + ky], acc[nf], 0, 0, 0);
                    acc[nf] = __builtin_amdgcn_mfma_f32_16x16x32_bf16(Al[ky], B[nf + ky], acc[nf], 0, 0, 0);
                }
        }
    }

    int t = img >> 1, b = img & 1;
    long imgOut = (long)(b * TT + t) * 64 * HW;
#pragma unroll
    for (int reg = 0; reg < 4; ++reg) {
        int oc = wave * 16 + quad * 4 + reg;
        float bv = bias[oc];
#pragma unroll
        for (int nf = 0; nf < 4; ++nf) {
            int p = (tY * 4 + nf) * WW + tX * 16 + m;
            out[imgOut + (long)oc * HW + p] = acc[nf][reg] + bv;
        }
    }
}

// ---------------------------------------------------------------------------
extern "C" void kernel_launch(void* const* d_in, const int* in_sizes, int n_in,
                              void* d_out, int out_size, void* d_ws, size_t ws_size,
                              hipStream_t stream)
{
    const float* input  = (const float*)d_in[0];
    const float* fuse_w = (const float*)d_in[1];
    const float* fuse_b = (const float*)d_in[2];
    const float* om_w   = (const float*)d_in[3];
    const float* om_b   = (const float*)d_in[4];
    const float* dcn_w  = (const float*)d_in[5];
    const float* dcn_b  = (const float*)d_in[6];
    const float* conv_w = (const float*)d_in[7];
    const float* conv_b = (const float*)d_in[8];
    const float* cat_w  = (const float*)d_in[9];
    const float* cat_b  = (const float*)d_in[10];
    float* out = (float*)d_out;

    char* w = (char*)d_ws;
    size_t off = 0;
    auto alloc = [&](size_t bytes) { void* p = w + off; off += (bytes + 255) & ~(size_t)255; return p; };

    unsigned short* xbf    = (unsigned short*)alloc(10L * HW * 64 * 2);
    unsigned short* hbuf   = (unsigned short*)alloc(4L * HW * 128 * 2);
    unsigned short* comb   = (unsigned short*)alloc(4L * HW * 64 * 2);
    float*          omb    = (float*)alloc(4L * 216 * HW * 4);
    unsigned short* sampb  = (unsigned short*)alloc(4L * HW * 576 * 2);
    unsigned short* fusedb = (unsigned short*)alloc(4L * HW * 256 * 2);
    float*          cbufs  = (float*)alloc(4L * HW * 64 * 4);
    unsigned short* hseqb  = (unsigned short*)alloc(10L * HW * 128 * 2);
    unsigned short* Wf = (unsigned short*)alloc(9L * 64 * 2 * 128 * 2);
    unsigned short* Wo = (unsigned short*)alloc(9L * 256 * 2 * 64 * 2);
    unsigned short* Wc = (unsigned short*)alloc(9L * 256 * 2 * 128 * 2);
    unsigned short* Wk = (unsigned short*)alloc(9L * 64 * 2 * 128 * 2);
    unsigned short* W1 = (unsigned short*)alloc(128L * 2 * 576 * 2);

    dim3 blk(256);
    wexp3_kernel<<<dim3(288), blk, 0, stream>>>(fuse_w, Wf, 64, 64, 128);
    wexp3_kernel<<<dim3(576), blk, 0, stream>>>(om_w, Wo, 216, 256, 64);
    wexp3_kernel<<<dim3(1152), blk, 0, stream>>>(conv_w, Wc, 256, 256, 128);
    wexp3_kernel<<<dim3(288), blk, 0, stream>>>(cat_w, Wk, 64, 64, 128);
    wexp1_kernel<<<dim3(288), blk, 0, stream>>>(dcn_w, W1);
    xprep_kernel<<<dim3(23040), blk, 0, stream>>>(input, xbf);

    hipMemsetAsync(hbuf, 0, 4L * HW * 128 * 2, stream);
    hipMemsetAsync(cbufs, 0, 4L * HW * 64 * 4, stream);

    for (int s = 0; s < TT; ++s) {
        int t0 = s, t1 = TT - 1 - s;
        fuse_conv<<<dim3(144, 1, 4), blk, 0, stream>>>(
            xbf, hbuf, Wf, fuse_b, comb, t0, t1);
        om_conv<<<dim3(144, 1, 4), dim3(512), 0, stream>>>(
            comb, Wo, om_b, omb);
        dcn_sample_kernel<<<dim3(10368), blk, 0, stream>>>(hbuf, omb, sampb);
        conv1x1_hl<<<dim3(144, 4), blk, 0, stream>>>(sampb, W1, dcn_b, fusedb);
        big_conv_gates<<<dim3(144, 1, 4), dim3(512), 0, stream>>>(
            fusedb, Wc, conv_b, cbufs, hbuf, hseqb, t0, t1);
    }
    cat_conv<<<dim3(144, 1, 10), blk, 0, stream>>>(hseqb, Wk, cat_b, out);
}

// Round 8
// 1735.454 us; speedup vs baseline: 1.0863x; 1.0863x over previous
//
#include <hip/hip_runtime.h>
#include <math.h>

#define HH 96
#define WW 96
#define HW 9216
#define TT 5

typedef __attribute__((ext_vector_type(8))) short bf16x8;
typedef __attribute__((ext_vector_type(4))) float f32x4;

__device__ __forceinline__ float sigf(float x) { return 1.0f / (1.0f + expf(-x)); }
__device__ __forceinline__ unsigned short bhi(float x) {
    return (unsigned short)(__float_as_uint(x) >> 16);
}
__device__ __forceinline__ unsigned short blo(float x) {
    float h = __uint_as_float(__float_as_uint(x) & 0xffff0000u);
    return (unsigned short)(__float_as_uint(x - h) >> 16);
}
__device__ __forceinline__ float b2f(unsigned short u) {
    return __uint_as_float(((unsigned)u) << 16);
}

// ---------------------------------------------------------------------------
// Weight expansion: src [OC][IC][9] fp32 -> dst [9][OCP][2][IC] bf16 hi/lo.
// ---------------------------------------------------------------------------
__global__ __launch_bounds__(256) void wexp3_kernel(
    const float* __restrict__ w, unsigned short* __restrict__ dst,
    int OC, int OCP, int IC)
{
    long i = (long)blockIdx.x * 256 + threadIdx.x;
    int ic = (int)(i % IC);
    long r = i / IC;
    int oc = (int)(r % OCP);
    int tap = (int)(r / OCP);
    float v = (oc < OC) ? w[((long)oc * IC + ic) * 9 + tap] : 0.f;
    long base = (((long)tap * OCP + oc) * 2) * IC + ic;
    dst[base] = bhi(v);
    dst[base + IC] = blo(v);
}

// dcn_w [128][576] (576 = c*9+k) -> [128][2][576] with K re-ordered k-major:
// dst K-slot (k*64 + c) = src (c*9 + k).
__global__ __launch_bounds__(256) void wexp1_kernel(
    const float* __restrict__ w, unsigned short* __restrict__ dst)
{
    int i = blockIdx.x * 256 + threadIdx.x;   // over 128*576 dst slots
    int slot = i % 576;                        // k*64 + c
    int oc = i / 576;
    int k = slot >> 6, c = slot & 63;
    float v = w[(long)oc * 576 + c * 9 + k];
    dst[((long)oc * 2) * 576 + slot] = bhi(v);
    dst[((long)oc * 2 + 1) * 576 + slot] = blo(v);
}

// input [b][t][64][HW] fp32 -> xbf [(t*2+b)][p][64] bf16
__global__ __launch_bounds__(256) void xprep_kernel(
    const float* __restrict__ input, unsigned short* __restrict__ xbf)
{
    long i = (long)blockIdx.x * 256 + threadIdx.x;
    int p = (int)(i % HW);
    long r = i / HW;
    int c = (int)(r % 64);
    long bt = r / 64;
    int b = (int)(bt / TT), t = (int)(bt % TT);
    float v = input[i];
    xbf[(((long)(t * 2 + b) * HW) + p) * 64 + c] = bhi(v);
}

// ===========================================================================
// History (big_conv_gates): perf tracks BLOCK COUNT (weight re-fetch/block),
// not occupancy: 1152blk=186us, 576blk=126-128us (at 57/34.8KB LDS alike),
// 384blk=105.7us even WITH a 37.7MB acc-spill. This round: keep 384 blocks
// (6x16 tile), remove the spill via 16-wave blocks (1024 thr): wave=oc-block,
// acc[6]=24 VGPR, 6 weight loads per (c,kx) for 54 MFMAs (2x the ratio).
// ===========================================================================

// ---------------------------------------------------------------------------
// Fuse conv: x (single, ic 0..63) + h (hl, ic 64..127) -> comb bf16 NHWC.
// ---------------------------------------------------------------------------
__global__ __launch_bounds__(256) void fuse_conv(
    const unsigned short* __restrict__ xbf,
    const unsigned short* __restrict__ hbuf,
    const unsigned short* __restrict__ Wf,   // [9][64][2][128]
    const float* __restrict__ bias,
    unsigned short* __restrict__ comb,
    int t0, int t1)
{
    __shared__ unsigned short sX[108 * 200];
    const int tid = threadIdx.x;
    const int wave = tid >> 6, lane = tid & 63;
    const int m = lane & 15, quad = lane >> 4;
    const int tY = blockIdx.x / 6, tX = blockIdx.x % 6;
    const int z = blockIdx.z;
    const int imgX = ((z < 2) ? t0 : t1) * 2 + (z & 1);

    const unsigned short* xb = xbf + (long)imgX * HW * 64;
    const unsigned short* hb = hbuf + (long)z * HW * 128;

    for (int i = tid; i < 108 * 24; i += 256) {
        int cell = i / 24, v = i - cell * 24;
        int row = cell / 18, col = cell - row * 18;
        int gy = tY * 4 + row - 1, gx = tX * 16 + col - 1;
        bool ok = (gy >= 0 && gy < HH && gx >= 0 && gx < WW);
        int p = gy * WW + gx;
        bf16x8 val = (bf16x8){0,0,0,0,0,0,0,0};
        int dst;
        if (v < 8) {
            if (ok) val = *(const bf16x8*)(xb + (long)p * 64 + v * 8);
            dst = cell * 200 + v * 8;
        } else {
            int v2 = v - 8;
            int pl = v2 >> 3, c = (v2 & 7) >> 2, g = v2 & 3;
            if (ok) val = *(const bf16x8*)(hb + (long)p * 128 + pl * 64 + c * 32 + g * 8);
            dst = cell * 200 + 64 + (c * 2 + pl) * 32 + g * 8;
        }
        *(bf16x8*)&sX[dst] = val;
    }
    __syncthreads();

    f32x4 acc[4];
#pragma unroll
    for (int nf = 0; nf < 4; ++nf) acc[nf] = (f32x4){0.f, 0.f, 0.f, 0.f};

#pragma unroll
    for (int c = 0; c < 2; ++c) {
#pragma unroll
        for (int kx = 0; kx < 3; ++kx) {
            bf16x8 B[6];
#pragma unroll
            for (int r = 0; r < 6; ++r)
                B[r] = *(const bf16x8*)&sX[(r * 18 + kx + m) * 200 + c * 32 + quad * 8];
            bf16x8 Ah[3], Al[3];
#pragma unroll
            for (int ky = 0; ky < 3; ++ky) {
                const unsigned short* wp = Wf + (((long)(ky * 3 + kx) * 64 + wave * 16 + m) * 2) * 128 + c * 32 + quad * 8;
                Ah[ky] = *(const bf16x8*)wp;
                Al[ky] = *(const bf16x8*)(wp + 128);
            }
#pragma unroll
            for (int ky = 0; ky < 3; ++ky)
#pragma unroll
                for (int nf = 0; nf < 4; ++nf) {
                    acc[nf] = __builtin_amdgcn_mfma_f32_16x16x32_bf16(Ah[ky], B[nf + ky], acc[nf], 0, 0, 0);
                    acc[nf] = __builtin_amdgcn_mfma_f32_16x16x32_bf16(Al[ky], B[nf + ky], acc[nf], 0, 0, 0);
                }
        }
    }
#pragma unroll
    for (int c = 0; c < 2; ++c) {
#pragma unroll
        for (int kx = 0; kx < 3; ++kx) {
            bf16x8 Bh[6], Bl[6];
#pragma unroll
            for (int r = 0; r < 6; ++r) {
                int base = (r * 18 + kx + m) * 200 + 64 + (c * 2) * 32 + quad * 8;
                Bh[r] = *(const bf16x8*)&sX[base];
                Bl[r] = *(const bf16x8*)&sX[base + 32];
            }
            bf16x8 Ah[3], Al[3];
#pragma unroll
            for (int ky = 0; ky < 3; ++ky) {
                const unsigned short* wp = Wf + (((long)(ky * 3 + kx) * 64 + wave * 16 + m) * 2) * 128 + (2 + c) * 32 + quad * 8;
                Ah[ky] = *(const bf16x8*)wp;
                Al[ky] = *(const bf16x8*)(wp + 128);
            }
#pragma unroll
            for (int ky = 0; ky < 3; ++ky)
#pragma unroll
                for (int nf = 0; nf < 4; ++nf) {
                    acc[nf] = __builtin_amdgcn_mfma_f32_16x16x32_bf16(Ah[ky], Bh[nf + ky], acc[nf], 0, 0, 0);
                    acc[nf] = __builtin_amdgcn_mfma_f32_16x16x32_bf16(Al[ky], Bh[nf + ky], acc[nf], 0, 0, 0);
                    acc[nf] = __builtin_amdgcn_mfma_f32_16x16x32_bf16(Ah[ky], Bl[nf + ky], acc[nf], 0, 0, 0);
                }
        }
    }

    int ocl = wave * 16 + quad * 4;
    float b0 = bias[ocl], b1 = bias[ocl + 1], b2 = bias[ocl + 2], b3 = bias[ocl + 3];
#pragma unroll
    for (int nf = 0; nf < 4; ++nf) {
        int p = (tY * 4 + nf) * WW + tX * 16 + m;
        ushort4 hv;
        hv.x = bhi(acc[nf].x + b0); hv.y = bhi(acc[nf].y + b1);
        hv.z = bhi(acc[nf].z + b2); hv.w = bhi(acc[nf].w + b3);
        *(ushort4*)&comb[((long)z * HW + p) * 64 + ocl] = hv;
    }
}

// ---------------------------------------------------------------------------
// om conv: comb (single, IC=64) -> om fp32 NCHW (216 of 256 oc).
// ---------------------------------------------------------------------------
__global__ __launch_bounds__(512) void om_conv(
    const unsigned short* __restrict__ comb,
    const unsigned short* __restrict__ Wo,   // [9][256][2][64]
    const float* __restrict__ bias,
    float* __restrict__ om)                  // [z][216][HW]
{
    __shared__ unsigned short sX[108 * 72];
    const int tid = threadIdx.x;
    const int wave = tid >> 6, lane = tid & 63;
    const int m = lane & 15, quad = lane >> 4;
    const int tY = blockIdx.x / 6, tX = blockIdx.x % 6;
    const int z = blockIdx.z;
    const unsigned short* cbp = comb + (long)z * HW * 64;

    for (int i = tid; i < 108 * 8; i += 512) {
        int cell = i >> 3, v = i & 7;
        int row = cell / 18, col = cell - row * 18;
        int gy = tY * 4 + row - 1, gx = tX * 16 + col - 1;
        bf16x8 val = (bf16x8){0,0,0,0,0,0,0,0};
        if (gy >= 0 && gy < HH && gx >= 0 && gx < WW)
            val = *(const bf16x8*)(cbp + (long)(gy * WW + gx) * 64 + v * 8);
        *(bf16x8*)&sX[cell * 72 + v * 8] = val;
    }
    __syncthreads();

    f32x4 acc[2][4];
#pragma unroll
    for (int mi = 0; mi < 2; ++mi)
#pragma unroll
        for (int nf = 0; nf < 4; ++nf) acc[mi][nf] = (f32x4){0.f, 0.f, 0.f, 0.f};

#pragma unroll
    for (int c = 0; c < 2; ++c) {
#pragma unroll
        for (int kx = 0; kx < 3; ++kx) {
            bf16x8 B[6];
#pragma unroll
            for (int r = 0; r < 6; ++r)
                B[r] = *(const bf16x8*)&sX[(r * 18 + kx + m) * 72 + c * 32 + quad * 8];
            bf16x8 Ah[3][2], Al[3][2];
#pragma unroll
            for (int ky = 0; ky < 3; ++ky)
#pragma unroll
                for (int mi = 0; mi < 2; ++mi) {
                    const unsigned short* wp = Wo + (((long)(ky * 3 + kx) * 256 + (wave * 2 + mi) * 16 + m) * 2) * 64 + c * 32 + quad * 8;
                    Ah[ky][mi] = *(const bf16x8*)wp;
                    Al[ky][mi] = *(const bf16x8*)(wp + 64);
                }
#pragma unroll
            for (int ky = 0; ky < 3; ++ky)
#pragma unroll
                for (int mi = 0; mi < 2; ++mi)
#pragma unroll
                    for (int nf = 0; nf < 4; ++nf) {
                        acc[mi][nf] = __builtin_amdgcn_mfma_f32_16x16x32_bf16(Ah[ky][mi], B[nf + ky], acc[mi][nf], 0, 0, 0);
                        acc[mi][nf] = __builtin_amdgcn_mfma_f32_16x16x32_bf16(Al[ky][mi], B[nf + ky], acc[mi][nf], 0, 0, 0);
                    }
        }
    }

#pragma unroll
    for (int mi = 0; mi < 2; ++mi) {
#pragma unroll
        for (int reg = 0; reg < 4; ++reg) {
            int oc = (wave * 2 + mi) * 16 + quad * 4 + reg;
            if (oc < 216) {
                float bv = bias[oc];
#pragma unroll
                for (int nf = 0; nf < 4; ++nf) {
                    int p = (tY * 4 + nf) * WW + tX * 16 + m;
                    om[((long)z * 216 + oc) * HW + p] = acc[mi][nf][reg] + bv;
                }
            }
        }
    }
}

// ---------------------------------------------------------------------------
// Deformable sampling. Output K is k-major: samp[(z*HW+p)*576 + k*64 + c].
// Each thread writes ONE contiguous bf16x8 (16 B).
// ---------------------------------------------------------------------------
__global__ __launch_bounds__(256) void dcn_sample_kernel(
    const unsigned short* __restrict__ hbuf,  // [4][p][128] hl
    const float* __restrict__ om,             // [4][216][HW]
    unsigned short* __restrict__ samp)        // [4][p][576] k-major
{
    int i = blockIdx.x * 256 + threadIdx.x;   // 4*G*KK*HW
    int p = i % HW;
    int r = i / HW;
    int k = r % 9;
    int g = (r / 9) % 8;
    int zz = r / 72;
    int y = p / WW, x = p - (p / WW) * WW;
    int ky = k / 3, kx = k - ky * 3;

    const float* omb = om + (long)zz * 216 * HW;
    float offy = omb[(g * 18 + k * 2) * HW + p];
    float offx = omb[(g * 18 + k * 2 + 1) * HW + p];
    float mm = sigf(omb[(144 + g * 9 + k) * HW + p]);

    float py = (float)(y + ky - 1) + offy;
    float px = (float)(x + kx - 1) + offx;
    float y0f = floorf(py), x0f = floorf(px);
    float wy = py - y0f, wx = px - x0f;
    int y0 = (int)y0f, x0 = (int)x0f;
    int y1 = y0 + 1, x1 = x0 + 1;

    bool vy0 = (y0 >= 0) && (y0 < HH), vy1 = (y1 >= 0) && (y1 < HH);
    bool vx0 = (x0 >= 0) && (x0 < WW), vx1 = (x1 >= 0) && (x1 < WW);
    int cy0 = min(max(y0, 0), HH - 1), cy1 = min(max(y1, 0), HH - 1);
    int cx0 = min(max(x0, 0), WW - 1), cx1 = min(max(x1, 0), WW - 1);
    long i00 = cy0 * WW + cx0, i01 = cy0 * WW + cx1;
    long i10 = cy1 * WW + cx0, i11 = cy1 * WW + cx1;
    float w00 = (1.f - wy) * (1.f - wx) * ((vy0 && vx0) ? mm : 0.f);
    float w01 = (1.f - wy) * wx         * ((vy0 && vx1) ? mm : 0.f);
    float w10 = wy * (1.f - wx)         * ((vy1 && vx0) ? mm : 0.f);
    float w11 = wy * wx                 * ((vy1 && vx1) ? mm : 0.f);

    const unsigned short* hzb = hbuf + (long)zz * HW * 128 + g * 8;
    bf16x8 h00 = *(const bf16x8*)(hzb + i00 * 128);
    bf16x8 l00 = *(const bf16x8*)(hzb + i00 * 128 + 64);
    bf16x8 h01 = *(const bf16x8*)(hzb + i01 * 128);
    bf16x8 l01 = *(const bf16x8*)(hzb + i01 * 128 + 64);
    bf16x8 h10 = *(const bf16x8*)(hzb + i10 * 128);
    bf16x8 l10 = *(const bf16x8*)(hzb + i10 * 128 + 64);
    bf16x8 h11 = *(const bf16x8*)(hzb + i11 * 128);
    bf16x8 l11 = *(const bf16x8*)(hzb + i11 * 128 + 64);

    bf16x8 outv;
#pragma unroll
    for (int cg = 0; cg < 8; ++cg) {
        float v00 = b2f((unsigned short)h00[cg]) + b2f((unsigned short)l00[cg]);
        float v01 = b2f((unsigned short)h01[cg]) + b2f((unsigned short)l01[cg]);
        float v10 = b2f((unsigned short)h10[cg]) + b2f((unsigned short)l10[cg]);
        float v11 = b2f((unsigned short)h11[cg]) + b2f((unsigned short)l11[cg]);
        float v = w00 * v00 + w01 * v01 + w10 * v10 + w11 * v11;
        outv[cg] = (short)bhi(v);
    }
    *(bf16x8*)(samp + ((long)zz * HW + p) * 576 + k * 64 + g * 8) = outv;
}

// ---------------------------------------------------------------------------
// 1x1 DCN einsum (pipelined). K ordering is k-major to match samp/W1.
// ---------------------------------------------------------------------------
__global__ __launch_bounds__(256) void conv1x1_hl(
    const unsigned short* __restrict__ samp,
    const unsigned short* __restrict__ w1,   // [128][2][576] k-major
    const float* __restrict__ bias,
    unsigned short* __restrict__ fused)      // [z][p][256] hl
{
    __shared__ unsigned short sX[64 * 76];
    const int tid  = threadIdx.x;
    const int wave = tid >> 6, lane = tid & 63;
    const int m = lane & 15, quad = lane >> 4;
    const int pt = blockIdx.x;
    const int zz = blockIdx.y;

    const unsigned short* sbase = samp + (long)zz * HW * 576 + (long)pt * 64 * 576;
    const int cell0 = tid >> 3, g0 = tid & 7;
    const int cell1 = (tid + 256) >> 3, g1 = tid & 7;

    bf16x8 R0, R1;
    auto loadCB = [&](int cb) {
        R0 = *(const bf16x8*)(sbase + (long)cell0 * 576 + cb * 64 + g0 * 8);
        R1 = *(const bf16x8*)(sbase + (long)cell1 * 576 + cb * 64 + g1 * 8);
    };

    f32x4 acc[2][4];
#pragma unroll
    for (int mm = 0; mm < 2; ++mm)
#pragma unroll
        for (int nf = 0; nf < 4; ++nf) acc[mm][nf] = (f32x4){0.f, 0.f, 0.f, 0.f};

    loadCB(0);
    for (int cb = 0; cb < 9; ++cb) {
        if (cb) __syncthreads();
        *(bf16x8*)&sX[cell0 * 76 + g0 * 8] = R0;
        *(bf16x8*)&sX[cell1 * 76 + g1 * 8] = R1;
        __syncthreads();
        if (cb + 1 < 9) loadCB(cb + 1);

        bf16x8 Bv[2][4];
#pragma unroll
        for (int sub = 0; sub < 2; ++sub)
#pragma unroll
            for (int nf = 0; nf < 4; ++nf)
                Bv[sub][nf] = *(const bf16x8*)&sX[(nf * 16 + m) * 76 + sub * 32 + quad * 8];
        bf16x8 Ah[2][2], Al[2][2];
#pragma unroll
        for (int sub = 0; sub < 2; ++sub)
#pragma unroll
            for (int mm = 0; mm < 2; ++mm) {
                const unsigned short* wp = w1 + ((long)((wave * 2 + mm) * 16 + m) * 2) * 576
                                           + cb * 64 + sub * 32 + quad * 8;
                Ah[sub][mm] = *(const bf16x8*)wp;
                Al[sub][mm] = *(const bf16x8*)(wp + 576);
            }
#pragma unroll
        for (int sub = 0; sub < 2; ++sub)
#pragma unroll
            for (int mm = 0; mm < 2; ++mm)
#pragma unroll
                for (int nf = 0; nf < 4; ++nf) {
                    acc[mm][nf] = __builtin_amdgcn_mfma_f32_16x16x32_bf16(
                        Ah[sub][mm], Bv[sub][nf], acc[mm][nf], 0, 0, 0);
                    acc[mm][nf] = __builtin_amdgcn_mfma_f32_16x16x32_bf16(
                        Al[sub][mm], Bv[sub][nf], acc[mm][nf], 0, 0, 0);
                }
    }

#pragma unroll
    for (int mm = 0; mm < 2; ++mm) {
        int ocl = (wave * 2 + mm) * 16 + quad * 4;
        float b0 = bias[ocl], b1 = bias[ocl + 1], b2 = bias[ocl + 2], b3 = bias[ocl + 3];
#pragma unroll
        for (int nf = 0; nf < 4; ++nf) {
            int p = pt * 64 + nf * 16 + m;
            float v0 = fmaxf(acc[mm][nf].x + b0, 0.f);
            float v1 = fmaxf(acc[mm][nf].y + b1, 0.f);
            float v2 = fmaxf(acc[mm][nf].z + b2, 0.f);
            float v3 = fmaxf(acc[mm][nf].w + b3, 0.f);
            unsigned short* op = fused + ((long)zz * HW + p) * 256 + ocl;
            ushort4 hv, lv;
            hv.x = bhi(v0); hv.y = bhi(v1); hv.z = bhi(v2); hv.w = bhi(v3);
            lv.x = blo(v0); lv.y = blo(v1); lv.z = blo(v2); lv.w = blo(v3);
            *(ushort4*)op = hv;
            *(ushort4*)(op + 128) = lv;
        }
    }
}

// ---------------------------------------------------------------------------
// Big conv (IC=128 hl, OC=256) FUSED with LSTM gates.
// 16-wave blocks (1024 thr), 6x16 tile, 384 blocks (the proven-fastest block
// count). Each wave owns ONE oc-16 block (wave = oc>>4): acc[6] = 24 VGPR
// (no spill; R4's acc[2][6]=48 spilled 37.7 MB), 6 weight loads per (c,kx)
// feed 54 MFMAs (2x R4's MFMA/load ratio). LDS 78.3 KB -> 2 blocks/CU =
// 32 waves/CU (2x R4's TLP). Per-oc accumulation order unchanged ->
// bitwise-identical numerics. Gates: ci=w0-3, cf=w4-7, co=w8-11, cg=w12-15;
// cf/co/cg exchanged via LDS (stride 68: 16B-aligned, bank-spread).
// ---------------------------------------------------------------------------
__global__ __launch_bounds__(1024) void big_conv_gates(
    const unsigned short* __restrict__ fusedb,  // [z][p][256] hl
    const unsigned short* __restrict__ Wc,      // [9][256][2][128]
    const float* __restrict__ bias,
    float* __restrict__ cst,                    // [z][p][64] fp32
    unsigned short* __restrict__ hbuf,          // [z][p][128] hl
    unsigned short* __restrict__ hseq,          // [(t*2+b)][p][128]
    int t0, int t1)
{
    // 39168 ush = 78336 B. Staging: 144 cells x 264 = 38016 ush (76032 B).
    // Gates: 3 regions x 96 px x 68 floats = 19584 floats = 78336 B.
    __shared__ unsigned short sX[39168];
    const int tid = threadIdx.x;
    const int wave = tid >> 6, lane = tid & 63;
    const int m = lane & 15, quad = lane >> 4;
    const int tY = blockIdx.x / 6, tX = blockIdx.x % 6;   // tY 0..15
    const int z = blockIdx.z;

    const unsigned short* fb = fusedb + (long)z * HW * 256;

    for (int i = tid; i < 144 * 32; i += 1024) {
        int cell = i >> 5, v = i & 31;
        int row = cell / 18, col = cell - row * 18;
        int gy = tY * 6 + row - 1, gx = tX * 16 + col - 1;
        int pl = v >> 4, c = (v & 15) >> 2, g = v & 3;
        bf16x8 val = (bf16x8){0,0,0,0,0,0,0,0};
        if (gy >= 0 && gy < HH && gx >= 0 && gx < WW)
            val = *(const bf16x8*)(fb + (long)(gy * WW + gx) * 256 + pl * 128 + c * 32 + g * 8);
        *(bf16x8*)&sX[cell * 264 + (c * 2 + pl) * 32 + g * 8] = val;
    }
    __syncthreads();

    f32x4 acc[6];
#pragma unroll
    for (int nf = 0; nf < 6; ++nf) acc[nf] = (f32x4){0.f, 0.f, 0.f, 0.f};

#pragma unroll
    for (int c = 0; c < 4; ++c) {
#pragma unroll
        for (int kx = 0; kx < 3; ++kx) {
            bf16x8 Ah[3], Al[3];
#pragma unroll
            for (int ky = 0; ky < 3; ++ky) {
                const unsigned short* wp = Wc + (((long)(ky * 3 + kx) * 256 + wave * 16 + m) * 2) * 128 + c * 32 + quad * 8;
                Ah[ky] = *(const bf16x8*)wp;
                Al[ky] = *(const bf16x8*)(wp + 128);
            }
            bf16x8 Bh[8], Bl[8];
#pragma unroll
            for (int r = 0; r < 3; ++r) {
                int base = (r * 18 + kx + m) * 264 + (c * 2) * 32 + quad * 8;
                Bh[r] = *(const bf16x8*)&sX[base];
                Bl[r] = *(const bf16x8*)&sX[base + 32];
            }
            // nf-outer, rolling 3-row B window: row nf+2 loaded at nf>0, rows
            // < nf dead -> ~6 live B regs. Per-acc (ky, term) order unchanged.
#pragma unroll
            for (int nf = 0; nf < 6; ++nf) {
                if (nf) {
                    int r = nf + 2;
                    int base = (r * 18 + kx + m) * 264 + (c * 2) * 32 + quad * 8;
                    Bh[r] = *(const bf16x8*)&sX[base];
                    Bl[r] = *(const bf16x8*)&sX[base + 32];
                }
#pragma unroll
                for (int ky = 0; ky < 3; ++ky) {
                    acc[nf] = __builtin_amdgcn_mfma_f32_16x16x32_bf16(Ah[ky], Bh[nf + ky], acc[nf], 0, 0, 0);
                    acc[nf] = __builtin_amdgcn_mfma_f32_16x16x32_bf16(Al[ky], Bh[nf + ky], acc[nf], 0, 0, 0);
                    acc[nf] = __builtin_amdgcn_mfma_f32_16x16x32_bf16(Ah[ky], Bl[nf + ky], acc[nf], 0, 0, 0);
                }
            }
        }
    }

    // ---- gates epilogue ----
    // wave w owns oc block w: ci = w0-3, cf = w4-7, co = w8-11, cg = w12-15.
    float* sG = (float*)sX;
    float ba[4];
    {
        int oc0 = wave * 16 + quad * 4;
#pragma unroll
        for (int r = 0; r < 4; ++r) ba[r] = bias[oc0 + r];
    }
    __syncthreads();
    if (wave >= 4) {
        int reg = (wave >> 2) - 1;            // 0=cf, 1=co, 2=cg
        int chb = (wave & 3) * 16 + quad * 4;
#pragma unroll
        for (int nf = 0; nf < 6; ++nf) {
            int px = nf * 16 + m;
            float* f = &sG[reg * 96 * 68 + (long)px * 68 + chb];
#pragma unroll
            for (int r = 0; r < 4; ++r) f[r] = acc[nf][r] + ba[r];
        }
    }
    __syncthreads();
    if (wave < 4) {
        int t = (z < 2) ? t0 : t1;
        int b = z & 1, dir = z >> 1;
        int chb = wave * 16 + quad * 4;
        unsigned short* hsq = hseq + ((long)(t * 2 + b) * HW) * 128 + dir * 64;
#pragma unroll
        for (int nf = 0; nf < 6; ++nf) {
            int px = nf * 16 + m;
            int p = (tY * 6 + nf) * WW + tX * 16 + m;
            float4 cf4 = *(float4*)&sG[0 * 96 * 68 + (long)px * 68 + chb];
            float4 co4 = *(float4*)&sG[1 * 96 * 68 + (long)px * 68 + chb];
            float4 cg4 = *(float4*)&sG[2 * 96 * 68 + (long)px * 68 + chb];
            float* cp = &cst[((long)z * HW + p) * 64 + chb];
            float4 cold = *(float4*)cp;
            float cfv[4] = {cf4.x, cf4.y, cf4.z, cf4.w};
            float cov[4] = {co4.x, co4.y, co4.z, co4.w};
            float cgv[4] = {cg4.x, cg4.y, cg4.z, cg4.w};
            float coldv[4] = {cold.x, cold.y, cold.z, cold.w};
            float c2v[4], h2v[4];
#pragma unroll
            for (int r = 0; r < 4; ++r) {
                float civ = acc[nf][r] + ba[r];
                float c2 = sigf(cfv[r]) * coldv[r] + sigf(civ) * tanhf(cgv[r]);
                float h2 = sigf(cov[r]) * tanhf(c2);
                c2v[r] = c2; h2v[r] = h2;
            }
            *(float4*)cp = (float4){c2v[0], c2v[1], c2v[2], c2v[3]};
            unsigned short* hp = hbuf + ((long)z * HW + p) * 128 + chb;
            ushort4 hv = {bhi(h2v[0]), bhi(h2v[1]), bhi(h2v[2]), bhi(h2v[3])};
            ushort4 lv = {blo(h2v[0]), blo(h2v[1]), blo(h2v[2]), blo(h2v[3])};
            *(ushort4*)hp = hv;
            *(ushort4*)(hp + 64) = lv;
            *(ushort4*)&hsq[(long)p * 128 + chb] = hv;
        }
    }
}

// ---------------------------------------------------------------------------
// cat conv: hseq (single-plane, IC=128) -> out fp32 NCHW with (t,b) permute.
// ---------------------------------------------------------------------------
__global__ __launch_bounds__(256) void cat_conv(
    const unsigned short* __restrict__ hseq,
    const unsigned short* __restrict__ Wk,     // [9][64][2][128]
    const float* __restrict__ bias,
    float* __restrict__ out)
{
    __shared__ unsigned short sX[108 * 136];
    const int tid = threadIdx.x;
    const int wave = tid >> 6, lane = tid & 63;
    const int m = lane & 15, quad = lane >> 4;
    const int tY = blockIdx.x / 6, tX = blockIdx.x % 6;
    const int img = blockIdx.z;
    const unsigned short* hp = hseq + (long)img * HW * 128;

    for (int i = tid; i < 108 * 16; i += 256) {
        int cell = i >> 4, v = i & 15;
        int row = cell / 18, col = cell - row * 18;
        int gy = tY * 4 + row - 1, gx = tX * 16 + col - 1;
        bf16x8 val = (bf16x8){0,0,0,0,0,0,0,0};
        if (gy >= 0 && gy < HH && gx >= 0 && gx < WW)
            val = *(const bf16x8*)(hp + (long)(gy * WW + gx) * 128 + v * 8);
        *(bf16x8*)&sX[cell * 136 + v * 8] = val;
    }
    __syncthreads();

    f32x4 acc[4];
#pragma unroll
    for (int nf = 0; nf < 4; ++nf) acc[nf] = (f32x4){0.f, 0.f, 0.f, 0.f};

#pragma unroll
    for (int c = 0; c < 4; ++c) {
#pragma unroll
        for (int kx = 0; kx < 3; ++kx) {
            bf16x8 B[6];
#pragma unroll
            for (int r = 0; r < 6; ++r)
                B[r] = *(const bf16x8*)&sX[(r * 18 + kx + m) * 136 + c * 32 + quad * 8];
            bf16x8 Ah[3], Al[3];
#pragma unroll
            for (int ky = 0; ky < 3; ++ky) {
                const unsigned short* wp = Wk + (((long)(ky * 3 + kx) * 64 + wave * 16 + m) * 2) * 128 + c * 32 + quad * 8;
                Ah[ky] = *(const bf16x8*)wp;
                Al[ky] = *(const bf16x8*)(wp + 128);
            }
#pragma unroll
            for (int ky = 0; ky < 3; ++ky)
#pragma unroll
                for (int nf = 0; nf < 4; ++nf) {
                    acc[nf] = __builtin_amdgcn_mfma_f32_16x16x32_bf16(Ah[ky], B[nf + ky], acc[nf], 0, 0, 0);
                    acc[nf] = __builtin_amdgcn_mfma_f32_16x16x32_bf16(Al[ky], B[nf + ky], acc[nf], 0, 0, 0);
                }
        }
    }

    int t = img >> 1, b = img & 1;
    long imgOut = (long)(b * TT + t) * 64 * HW;
#pragma unroll
    for (int reg = 0; reg < 4; ++reg) {
        int oc = wave * 16 + quad * 4 + reg;
        float bv = bias[oc];
#pragma unroll
        for (int nf = 0; nf < 4; ++nf) {
            int p = (tY * 4 + nf) * WW + tX * 16 + m;
            out[imgOut + (long)oc * HW + p] = acc[nf][reg] + bv;
        }
    }
}

// ---------------------------------------------------------------------------
extern "C" void kernel_launch(void* const* d_in, const int* in_sizes, int n_in,
                              void* d_out, int out_size, void* d_ws, size_t ws_size,
                              hipStream_t stream)
{
    const float* input  = (const float*)d_in[0];
    const float* fuse_w = (const float*)d_in[1];
    const float* fuse_b = (const float*)d_in[2];
    const float* om_w   = (const float*)d_in[3];
    const float* om_b   = (const float*)d_in[4];
    const float* dcn_w  = (const float*)d_in[5];
    const float* dcn_b  = (const float*)d_in[6];
    const float* conv_w = (const float*)d_in[7];
    const float* conv_b = (const float*)d_in[8];
    const float* cat_w  = (const float*)d_in[9];
    const float* cat_b  = (const float*)d_in[10];
    float* out = (float*)d_out;

    char* w = (char*)d_ws;
    size_t off = 0;
    auto alloc = [&](size_t bytes) { void* p = w + off; off += (bytes + 255) & ~(size_t)255; return p; };

    unsigned short* xbf    = (unsigned short*)alloc(10L * HW * 64 * 2);
    unsigned short* hbuf   = (unsigned short*)alloc(4L * HW * 128 * 2);
    unsigned short* comb   = (unsigned short*)alloc(4L * HW * 64 * 2);
    float*          omb    = (float*)alloc(4L * 216 * HW * 4);
    unsigned short* sampb  = (unsigned short*)alloc(4L * HW * 576 * 2);
    unsigned short* fusedb = (unsigned short*)alloc(4L * HW * 256 * 2);
    float*          cbufs  = (float*)alloc(4L * HW * 64 * 4);
    unsigned short* hseqb  = (unsigned short*)alloc(10L * HW * 128 * 2);
    unsigned short* Wf = (unsigned short*)alloc(9L * 64 * 2 * 128 * 2);
    unsigned short* Wo = (unsigned short*)alloc(9L * 256 * 2 * 64 * 2);
    unsigned short* Wc = (unsigned short*)alloc(9L * 256 * 2 * 128 * 2);
    unsigned short* Wk = (unsigned short*)alloc(9L * 64 * 2 * 128 * 2);
    unsigned short* W1 = (unsigned short*)alloc(128L * 2 * 576 * 2);

    dim3 blk(256);
    wexp3_kernel<<<dim3(288), blk, 0, stream>>>(fuse_w, Wf, 64, 64, 128);
    wexp3_kernel<<<dim3(576), blk, 0, stream>>>(om_w, Wo, 216, 256, 64);
    wexp3_kernel<<<dim3(1152), blk, 0, stream>>>(conv_w, Wc, 256, 256, 128);
    wexp3_kernel<<<dim3(288), blk, 0, stream>>>(cat_w, Wk, 64, 64, 128);
    wexp1_kernel<<<dim3(288), blk, 0, stream>>>(dcn_w, W1);
    xprep_kernel<<<dim3(23040), blk, 0, stream>>>(input, xbf);

    hipMemsetAsync(hbuf, 0, 4L * HW * 128 * 2, stream);
    hipMemsetAsync(cbufs, 0, 4L * HW * 64 * 4, stream);

    for (int s = 0; s < TT; ++s) {
        int t0 = s, t1 = TT - 1 - s;
        fuse_conv<<<dim3(144, 1, 4), blk, 0, stream>>>(
            xbf, hbuf, Wf, fuse_b, comb, t0, t1);
        om_conv<<<dim3(144, 1, 4), dim3(512), 0, stream>>>(
            comb, Wo, om_b, omb);
        dcn_sample_kernel<<<dim3(10368), blk, 0, stream>>>(hbuf, omb, sampb);
        conv1x1_hl<<<dim3(144, 4), blk, 0, stream>>>(sampb, W1, dcn_b, fusedb);
        big_conv_gates<<<dim3(96, 1, 4), dim3(1024), 0, stream>>>(
            fusedb, Wc, conv_b, cbufs, hbuf, hseqb, t0, t1);
    }
    cat_conv<<<dim3(144, 1, 10), blk, 0, stream>>>(hseqb, Wk, cat_b, out);
}

// Round 9
// 1735.447 us; speedup vs baseline: 1.0863x; 1.0000x over previous
//
#include <hip/hip_runtime.h>
#include <math.h>

#define HH 96
#define WW 96
#define HW 9216
#define TT 5

typedef __attribute__((ext_vector_type(8))) short bf16x8;
typedef __attribute__((ext_vector_type(4))) float f32x4;

__device__ __forceinline__ float sigf(float x) { return 1.0f / (1.0f + expf(-x)); }
__device__ __forceinline__ unsigned short bhi(float x) {
    return (unsigned short)(__float_as_uint(x) >> 16);
}
__device__ __forceinline__ unsigned short blo(float x) {
    float h = __uint_as_float(__float_as_uint(x) & 0xffff0000u);
    return (unsigned short)(__float_as_uint(x - h) >> 16);
}
__device__ __forceinline__ float b2f(unsigned short u) {
    return __uint_as_float(((unsigned)u) << 16);
}

// ---------------------------------------------------------------------------
// Weight expansion: src [OC][IC][9] fp32 -> dst [9][OCP][2][IC] bf16 hi/lo.
// ---------------------------------------------------------------------------
__global__ __launch_bounds__(256) void wexp3_kernel(
    const float* __restrict__ w, unsigned short* __restrict__ dst,
    int OC, int OCP, int IC)
{
    long i = (long)blockIdx.x * 256 + threadIdx.x;
    int ic = (int)(i % IC);
    long r = i / IC;
    int oc = (int)(r % OCP);
    int tap = (int)(r / OCP);
    float v = (oc < OC) ? w[((long)oc * IC + ic) * 9 + tap] : 0.f;
    long base = (((long)tap * OCP + oc) * 2) * IC + ic;
    dst[base] = bhi(v);
    dst[base + IC] = blo(v);
}

// dcn_w [128][576] (576 = c*9+k) -> [128][2][576] with K re-ordered k-major:
// dst K-slot (k*64 + c) = src (c*9 + k).
__global__ __launch_bounds__(256) void wexp1_kernel(
    const float* __restrict__ w, unsigned short* __restrict__ dst)
{
    int i = blockIdx.x * 256 + threadIdx.x;   // over 128*576 dst slots
    int slot = i % 576;                        // k*64 + c
    int oc = i / 576;
    int k = slot >> 6, c = slot & 63;
    float v = w[(long)oc * 576 + c * 9 + k];
    dst[((long)oc * 2) * 576 + slot] = bhi(v);
    dst[((long)oc * 2 + 1) * 576 + slot] = blo(v);
}

// input [b][t][64][HW] fp32 -> xbf [(t*2+b)][p][64] bf16
__global__ __launch_bounds__(256) void xprep_kernel(
    const float* __restrict__ input, unsigned short* __restrict__ xbf)
{
    long i = (long)blockIdx.x * 256 + threadIdx.x;
    int p = (int)(i % HW);
    long r = i / HW;
    int c = (int)(r % 64);
    long bt = r / 64;
    int b = (int)(bt / TT), t = (int)(bt % TT);
    float v = input[i];
    xbf[(((long)(t * 2 + b) * HW) + p) * 64 + c] = bhi(v);
}

// ===========================================================================
// History (big_conv_gates): perf tracks BLOCK COUNT (weight re-fetch/block);
// R8 config (384 blk, 16-wave, acc[6], no spill) = 102us is the best found.
// This round targets the OTHER ~215us/step: dcn_sample is FUSED into
// conv1x1 (each samp element had exactly one consumer block), killing a
// 10368-block launch + 42.5MB write + 42.5MB read per step.
// ===========================================================================

// ---------------------------------------------------------------------------
// Fuse conv: x (single, ic 0..63) + h (hl, ic 64..127) -> comb bf16 NHWC.
// ---------------------------------------------------------------------------
__global__ __launch_bounds__(256) void fuse_conv(
    const unsigned short* __restrict__ xbf,
    const unsigned short* __restrict__ hbuf,
    const unsigned short* __restrict__ Wf,   // [9][64][2][128]
    const float* __restrict__ bias,
    unsigned short* __restrict__ comb,
    int t0, int t1)
{
    __shared__ unsigned short sX[108 * 200];
    const int tid = threadIdx.x;
    const int wave = tid >> 6, lane = tid & 63;
    const int m = lane & 15, quad = lane >> 4;
    const int tY = blockIdx.x / 6, tX = blockIdx.x % 6;
    const int z = blockIdx.z;
    const int imgX = ((z < 2) ? t0 : t1) * 2 + (z & 1);

    const unsigned short* xb = xbf + (long)imgX * HW * 64;
    const unsigned short* hb = hbuf + (long)z * HW * 128;

    for (int i = tid; i < 108 * 24; i += 256) {
        int cell = i / 24, v = i - cell * 24;
        int row = cell / 18, col = cell - row * 18;
        int gy = tY * 4 + row - 1, gx = tX * 16 + col - 1;
        bool ok = (gy >= 0 && gy < HH && gx >= 0 && gx < WW);
        int p = gy * WW + gx;
        bf16x8 val = (bf16x8){0,0,0,0,0,0,0,0};
        int dst;
        if (v < 8) {
            if (ok) val = *(const bf16x8*)(xb + (long)p * 64 + v * 8);
            dst = cell * 200 + v * 8;
        } else {
            int v2 = v - 8;
            int pl = v2 >> 3, c = (v2 & 7) >> 2, g = v2 & 3;
            if (ok) val = *(const bf16x8*)(hb + (long)p * 128 + pl * 64 + c * 32 + g * 8);
            dst = cell * 200 + 64 + (c * 2 + pl) * 32 + g * 8;
        }
        *(bf16x8*)&sX[dst] = val;
    }
    __syncthreads();

    f32x4 acc[4];
#pragma unroll
    for (int nf = 0; nf < 4; ++nf) acc[nf] = (f32x4){0.f, 0.f, 0.f, 0.f};

#pragma unroll
    for (int c = 0; c < 2; ++c) {
#pragma unroll
        for (int kx = 0; kx < 3; ++kx) {
            bf16x8 B[6];
#pragma unroll
            for (int r = 0; r < 6; ++r)
                B[r] = *(const bf16x8*)&sX[(r * 18 + kx + m) * 200 + c * 32 + quad * 8];
            bf16x8 Ah[3], Al[3];
#pragma unroll
            for (int ky = 0; ky < 3; ++ky) {
                const unsigned short* wp = Wf + (((long)(ky * 3 + kx) * 64 + wave * 16 + m) * 2) * 128 + c * 32 + quad * 8;
                Ah[ky] = *(const bf16x8*)wp;
                Al[ky] = *(const bf16x8*)(wp + 128);
            }
#pragma unroll
            for (int ky = 0; ky < 3; ++ky)
#pragma unroll
                for (int nf = 0; nf < 4; ++nf) {
                    acc[nf] = __builtin_amdgcn_mfma_f32_16x16x32_bf16(Ah[ky], B[nf + ky], acc[nf], 0, 0, 0);
                    acc[nf] = __builtin_amdgcn_mfma_f32_16x16x32_bf16(Al[ky], B[nf + ky], acc[nf], 0, 0, 0);
                }
        }
    }
#pragma unroll
    for (int c = 0; c < 2; ++c) {
#pragma unroll
        for (int kx = 0; kx < 3; ++kx) {
            bf16x8 Bh[6], Bl[6];
#pragma unroll
            for (int r = 0; r < 6; ++r) {
                int base = (r * 18 + kx + m) * 200 + 64 + (c * 2) * 32 + quad * 8;
                Bh[r] = *(const bf16x8*)&sX[base];
                Bl[r] = *(const bf16x8*)&sX[base + 32];
            }
            bf16x8 Ah[3], Al[3];
#pragma unroll
            for (int ky = 0; ky < 3; ++ky) {
                const unsigned short* wp = Wf + (((long)(ky * 3 + kx) * 64 + wave * 16 + m) * 2) * 128 + (2 + c) * 32 + quad * 8;
                Ah[ky] = *(const bf16x8*)wp;
                Al[ky] = *(const bf16x8*)(wp + 128);
            }
#pragma unroll
            for (int ky = 0; ky < 3; ++ky)
#pragma unroll
                for (int nf = 0; nf < 4; ++nf) {
                    acc[nf] = __builtin_amdgcn_mfma_f32_16x16x32_bf16(Ah[ky], Bh[nf + ky], acc[nf], 0, 0, 0);
                    acc[nf] = __builtin_amdgcn_mfma_f32_16x16x32_bf16(Al[ky], Bh[nf + ky], acc[nf], 0, 0, 0);
                    acc[nf] = __builtin_amdgcn_mfma_f32_16x16x32_bf16(Ah[ky], Bl[nf + ky], acc[nf], 0, 0, 0);
                }
        }
    }

    int ocl = wave * 16 + quad * 4;
    float b0 = bias[ocl], b1 = bias[ocl + 1], b2 = bias[ocl + 2], b3 = bias[ocl + 3];
#pragma unroll
    for (int nf = 0; nf < 4; ++nf) {
        int p = (tY * 4 + nf) * WW + tX * 16 + m;
        ushort4 hv;
        hv.x = bhi(acc[nf].x + b0); hv.y = bhi(acc[nf].y + b1);
        hv.z = bhi(acc[nf].z + b2); hv.w = bhi(acc[nf].w + b3);
        *(ushort4*)&comb[((long)z * HW + p) * 64 + ocl] = hv;
    }
}

// ---------------------------------------------------------------------------
// om conv: comb (single, IC=64) -> om fp32 NCHW (216 of 256 oc).
// ---------------------------------------------------------------------------
__global__ __launch_bounds__(512) void om_conv(
    const unsigned short* __restrict__ comb,
    const unsigned short* __restrict__ Wo,   // [9][256][2][64]
    const float* __restrict__ bias,
    float* __restrict__ om)                  // [z][216][HW]
{
    __shared__ unsigned short sX[108 * 72];
    const int tid = threadIdx.x;
    const int wave = tid >> 6, lane = tid & 63;
    const int m = lane & 15, quad = lane >> 4;
    const int tY = blockIdx.x / 6, tX = blockIdx.x % 6;
    const int z = blockIdx.z;
    const unsigned short* cbp = comb + (long)z * HW * 64;

    for (int i = tid; i < 108 * 8; i += 512) {
        int cell = i >> 3, v = i & 7;
        int row = cell / 18, col = cell - row * 18;
        int gy = tY * 4 + row - 1, gx = tX * 16 + col - 1;
        bf16x8 val = (bf16x8){0,0,0,0,0,0,0,0};
        if (gy >= 0 && gy < HH && gx >= 0 && gx < WW)
            val = *(const bf16x8*)(cbp + (long)(gy * WW + gx) * 64 + v * 8);
        *(bf16x8*)&sX[cell * 72 + v * 8] = val;
    }
    __syncthreads();

    f32x4 acc[2][4];
#pragma unroll
    for (int mi = 0; mi < 2; ++mi)
#pragma unroll
        for (int nf = 0; nf < 4; ++nf) acc[mi][nf] = (f32x4){0.f, 0.f, 0.f, 0.f};

#pragma unroll
    for (int c = 0; c < 2; ++c) {
#pragma unroll
        for (int kx = 0; kx < 3; ++kx) {
            bf16x8 B[6];
#pragma unroll
            for (int r = 0; r < 6; ++r)
                B[r] = *(const bf16x8*)&sX[(r * 18 + kx + m) * 72 + c * 32 + quad * 8];
            bf16x8 Ah[3][2], Al[3][2];
#pragma unroll
            for (int ky = 0; ky < 3; ++ky)
#pragma unroll
                for (int mi = 0; mi < 2; ++mi) {
                    const unsigned short* wp = Wo + (((long)(ky * 3 + kx) * 256 + (wave * 2 + mi) * 16 + m) * 2) * 64 + c * 32 + quad * 8;
                    Ah[ky][mi] = *(const bf16x8*)wp;
                    Al[ky][mi] = *(const bf16x8*)(wp + 64);
                }
#pragma unroll
            for (int ky = 0; ky < 3; ++ky)
#pragma unroll
                for (int mi = 0; mi < 2; ++mi)
#pragma unroll
                    for (int nf = 0; nf < 4; ++nf) {
                        acc[mi][nf] = __builtin_amdgcn_mfma_f32_16x16x32_bf16(Ah[ky][mi], B[nf + ky], acc[mi][nf], 0, 0, 0);
                        acc[mi][nf] = __builtin_amdgcn_mfma_f32_16x16x32_bf16(Al[ky][mi], B[nf + ky], acc[mi][nf], 0, 0, 0);
                    }
        }
    }

#pragma unroll
    for (int mi = 0; mi < 2; ++mi) {
#pragma unroll
        for (int reg = 0; reg < 4; ++reg) {
            int oc = (wave * 2 + mi) * 16 + quad * 4 + reg;
            if (oc < 216) {
                float bv = bias[oc];
#pragma unroll
                for (int nf = 0; nf < 4; ++nf) {
                    int p = (tY * 4 + nf) * WW + tX * 16 + m;
                    om[((long)z * 216 + oc) * HW + p] = acc[mi][nf][reg] + bv;
                }
            }
        }
    }
}

// ---------------------------------------------------------------------------
// FUSED deformable-sampling + 1x1 DCN einsum. Replaces dcn_sample_kernel +
// conv1x1_hl: each samp element had exactly ONE consumer block, so sampling
// is computed in-block (identical arithmetic, bitwise-same bf16 values) and
// written straight to LDS — the 42.5MB samp write + 42.5MB read per step and
// one 10368-block launch are eliminated. Thread map per cb: g = tid>>5,
// cell = tid&31 (+32 for second half) so om reads coalesce over p.
// ---------------------------------------------------------------------------
__global__ __launch_bounds__(256) void conv1x1_fused(
    const unsigned short* __restrict__ hbuf,  // [4][p][128] hl
    const float* __restrict__ om,             // [4][216][HW]
    const unsigned short* __restrict__ w1,    // [128][2][576] k-major
    const float* __restrict__ bias,
    unsigned short* __restrict__ fused)       // [z][p][256] hl
{
    __shared__ unsigned short sX[64 * 76];
    const int tid  = threadIdx.x;
    const int wave = tid >> 6, lane = tid & 63;
    const int m = lane & 15, quad = lane >> 4;
    const int pt = blockIdx.x;
    const int zz = blockIdx.y;

    const float* omb = om + (long)zz * 216 * HW;
    const unsigned short* hz = hbuf + (long)zz * HW * 128;

    const int g0 = tid >> 5;        // 0..7  (channel group)
    const int cellb = tid & 31;     // 0..31 (pixel within half-tile)

    // Bilinear-sample 8 channels (group g0) at pixel p=pt*64+cell, tap cb.
    // Expression-identical to the old dcn_sample_kernel -> bitwise-same bf16.
    auto sample = [&](int cell, int cb) -> bf16x8 {
        int p = pt * 64 + cell;
        int y = p / WW, x = p - y * WW;
        int ky = cb / 3, kx = cb - ky * 3;
        float offy = omb[(g0 * 18 + cb * 2) * HW + p];
        float offx = omb[(g0 * 18 + cb * 2 + 1) * HW + p];
        float mm = sigf(omb[(144 + g0 * 9 + cb) * HW + p]);
        float py = (float)(y + ky - 1) + offy;
        float px = (float)(x + kx - 1) + offx;
        float y0f = floorf(py), x0f = floorf(px);
        float wy = py - y0f, wx = px - x0f;
        int y0 = (int)y0f, x0 = (int)x0f;
        int y1 = y0 + 1, x1 = x0 + 1;
        bool vy0 = (y0 >= 0) && (y0 < HH), vy1 = (y1 >= 0) && (y1 < HH);
        bool vx0 = (x0 >= 0) && (x0 < WW), vx1 = (x1 >= 0) && (x1 < WW);
        int cy0 = min(max(y0, 0), HH - 1), cy1 = min(max(y1, 0), HH - 1);
        int cx0 = min(max(x0, 0), WW - 1), cx1 = min(max(x1, 0), WW - 1);
        long i00 = cy0 * WW + cx0, i01 = cy0 * WW + cx1;
        long i10 = cy1 * WW + cx0, i11 = cy1 * WW + cx1;
        float w00 = (1.f - wy) * (1.f - wx) * ((vy0 && vx0) ? mm : 0.f);
        float w01 = (1.f - wy) * wx         * ((vy0 && vx1) ? mm : 0.f);
        float w10 = wy * (1.f - wx)         * ((vy1 && vx0) ? mm : 0.f);
        float w11 = wy * wx                 * ((vy1 && vx1) ? mm : 0.f);
        const unsigned short* hzb = hz + g0 * 8;
        bf16x8 h00 = *(const bf16x8*)(hzb + i00 * 128);
        bf16x8 l00 = *(const bf16x8*)(hzb + i00 * 128 + 64);
        bf16x8 h01 = *(const bf16x8*)(hzb + i01 * 128);
        bf16x8 l01 = *(const bf16x8*)(hzb + i01 * 128 + 64);
        bf16x8 h10 = *(const bf16x8*)(hzb + i10 * 128);
        bf16x8 l10 = *(const bf16x8*)(hzb + i10 * 128 + 64);
        bf16x8 h11 = *(const bf16x8*)(hzb + i11 * 128);
        bf16x8 l11 = *(const bf16x8*)(hzb + i11 * 128 + 64);
        bf16x8 outv;
#pragma unroll
        for (int cg = 0; cg < 8; ++cg) {
            float v00 = b2f((unsigned short)h00[cg]) + b2f((unsigned short)l00[cg]);
            float v01 = b2f((unsigned short)h01[cg]) + b2f((unsigned short)l01[cg]);
            float v10 = b2f((unsigned short)h10[cg]) + b2f((unsigned short)l10[cg]);
            float v11 = b2f((unsigned short)h11[cg]) + b2f((unsigned short)l11[cg]);
            float v = w00 * v00 + w01 * v01 + w10 * v10 + w11 * v11;
            outv[cg] = (short)bhi(v);
        }
        return outv;
    };

    f32x4 acc[2][4];
#pragma unroll
    for (int mm = 0; mm < 2; ++mm)
#pragma unroll
        for (int nf = 0; nf < 4; ++nf) acc[mm][nf] = (f32x4){0.f, 0.f, 0.f, 0.f};

    for (int cb = 0; cb < 9; ++cb) {
        if (cb) __syncthreads();
        bf16x8 R0 = sample(cellb, cb);
        bf16x8 R1 = sample(32 + cellb, cb);
        *(bf16x8*)&sX[cellb * 76 + g0 * 8] = R0;
        *(bf16x8*)&sX[(32 + cellb) * 76 + g0 * 8] = R1;
        __syncthreads();

        bf16x8 Bv[2][4];
#pragma unroll
        for (int sub = 0; sub < 2; ++sub)
#pragma unroll
            for (int nf = 0; nf < 4; ++nf)
                Bv[sub][nf] = *(const bf16x8*)&sX[(nf * 16 + m) * 76 + sub * 32 + quad * 8];
        bf16x8 Ah[2][2], Al[2][2];
#pragma unroll
        for (int sub = 0; sub < 2; ++sub)
#pragma unroll
            for (int mm = 0; mm < 2; ++mm) {
                const unsigned short* wp = w1 + ((long)((wave * 2 + mm) * 16 + m) * 2) * 576
                                           + cb * 64 + sub * 32 + quad * 8;
                Ah[sub][mm] = *(const bf16x8*)wp;
                Al[sub][mm] = *(const bf16x8*)(wp + 576);
            }
#pragma unroll
        for (int sub = 0; sub < 2; ++sub)
#pragma unroll
            for (int mm = 0; mm < 2; ++mm)
#pragma unroll
                for (int nf = 0; nf < 4; ++nf) {
                    acc[mm][nf] = __builtin_amdgcn_mfma_f32_16x16x32_bf16(
                        Ah[sub][mm], Bv[sub][nf], acc[mm][nf], 0, 0, 0);
                    acc[mm][nf] = __builtin_amdgcn_mfma_f32_16x16x32_bf16(
                        Al[sub][mm], Bv[sub][nf], acc[mm][nf], 0, 0, 0);
                }
    }

#pragma unroll
    for (int mm = 0; mm < 2; ++mm) {
        int ocl = (wave * 2 + mm) * 16 + quad * 4;
        float b0 = bias[ocl], b1 = bias[ocl + 1], b2 = bias[ocl + 2], b3 = bias[ocl + 3];
#pragma unroll
        for (int nf = 0; nf < 4; ++nf) {
            int p = pt * 64 + nf * 16 + m;
            float v0 = fmaxf(acc[mm][nf].x + b0, 0.f);
            float v1 = fmaxf(acc[mm][nf].y + b1, 0.f);
            float v2 = fmaxf(acc[mm][nf].z + b2, 0.f);
            float v3 = fmaxf(acc[mm][nf].w + b3, 0.f);
            unsigned short* op = fused + ((long)zz * HW + p) * 256 + ocl;
            ushort4 hv, lv;
            hv.x = bhi(v0); hv.y = bhi(v1); hv.z = bhi(v2); hv.w = bhi(v3);
            lv.x = blo(v0); lv.y = blo(v1); lv.z = blo(v2); lv.w = blo(v3);
            *(ushort4*)op = hv;
            *(ushort4*)(op + 128) = lv;
        }
    }
}

// ---------------------------------------------------------------------------
// Big conv (IC=128 hl, OC=256) FUSED with LSTM gates.
// 16-wave blocks (1024 thr), 6x16 tile, 384 blocks (the proven-fastest block
// count). Each wave owns ONE oc-16 block (wave = oc>>4): acc[6] = 24 VGPR
// (no spill), 6 weight loads per (c,kx) feed 54 MFMAs. R8-measured: 102us,
// WRITE exactly intended, VGPR 56. Best-known config — unchanged this round.
// ---------------------------------------------------------------------------
__global__ __launch_bounds__(1024) void big_conv_gates(
    const unsigned short* __restrict__ fusedb,  // [z][p][256] hl
    const unsigned short* __restrict__ Wc,      // [9][256][2][128]
    const float* __restrict__ bias,
    float* __restrict__ cst,                    // [z][p][64] fp32
    unsigned short* __restrict__ hbuf,          // [z][p][128] hl
    unsigned short* __restrict__ hseq,          // [(t*2+b)][p][128]
    int t0, int t1)
{
    // 39168 ush = 78336 B. Staging: 144 cells x 264 = 38016 ush (76032 B).
    // Gates: 3 regions x 96 px x 68 floats = 19584 floats = 78336 B.
    __shared__ unsigned short sX[39168];
    const int tid = threadIdx.x;
    const int wave = tid >> 6, lane = tid & 63;
    const int m = lane & 15, quad = lane >> 4;
    const int tY = blockIdx.x / 6, tX = blockIdx.x % 6;   // tY 0..15
    const int z = blockIdx.z;

    const unsigned short* fb = fusedb + (long)z * HW * 256;

    for (int i = tid; i < 144 * 32; i += 1024) {
        int cell = i >> 5, v = i & 31;
        int row = cell / 18, col = cell - row * 18;
        int gy = tY * 6 + row - 1, gx = tX * 16 + col - 1;
        int pl = v >> 4, c = (v & 15) >> 2, g = v & 3;
        bf16x8 val = (bf16x8){0,0,0,0,0,0,0,0};
        if (gy >= 0 && gy < HH && gx >= 0 && gx < WW)
            val = *(const bf16x8*)(fb + (long)(gy * WW + gx) * 256 + pl * 128 + c * 32 + g * 8);
        *(bf16x8*)&sX[cell * 264 + (c * 2 + pl) * 32 + g * 8] = val;
    }
    __syncthreads();

    f32x4 acc[6];
#pragma unroll
    for (int nf = 0; nf < 6; ++nf) acc[nf] = (f32x4){0.f, 0.f, 0.f, 0.f};

#pragma unroll
    for (int c = 0; c < 4; ++c) {
#pragma unroll
        for (int kx = 0; kx < 3; ++kx) {
            bf16x8 Ah[3], Al[3];
#pragma unroll
            for (int ky = 0; ky < 3; ++ky) {
                const unsigned short* wp = Wc + (((long)(ky * 3 + kx) * 256 + wave * 16 + m) * 2) * 128 + c * 32 + quad * 8;
                Ah[ky] = *(const bf16x8*)wp;
                Al[ky] = *(const bf16x8*)(wp + 128);
            }
            bf16x8 Bh[8], Bl[8];
#pragma unroll
            for (int r = 0; r < 3; ++r) {
                int base = (r * 18 + kx + m) * 264 + (c * 2) * 32 + quad * 8;
                Bh[r] = *(const bf16x8*)&sX[base];
                Bl[r] = *(const bf16x8*)&sX[base + 32];
            }
            // nf-outer, rolling 3-row B window: row nf+2 loaded at nf>0, rows
            // < nf dead -> ~6 live B regs. Per-acc (ky, term) order unchanged.
#pragma unroll
            for (int nf = 0; nf < 6; ++nf) {
                if (nf) {
                    int r = nf + 2;
                    int base = (r * 18 + kx + m) * 264 + (c * 2) * 32 + quad * 8;
                    Bh[r] = *(const bf16x8*)&sX[base];
                    Bl[r] = *(const bf16x8*)&sX[base + 32];
                }
#pragma unroll
                for (int ky = 0; ky < 3; ++ky) {
                    acc[nf] = __builtin_amdgcn_mfma_f32_16x16x32_bf16(Ah[ky], Bh[nf + ky], acc[nf], 0, 0, 0);
                    acc[nf] = __builtin_amdgcn_mfma_f32_16x16x32_bf16(Al[ky], Bh[nf + ky], acc[nf], 0, 0, 0);
                    acc[nf] = __builtin_amdgcn_mfma_f32_16x16x32_bf16(Ah[ky], Bl[nf + ky], acc[nf], 0, 0, 0);
                }
            }
        }
    }

    // ---- gates epilogue ----
    // wave w owns oc block w: ci = w0-3, cf = w4-7, co = w8-11, cg = w12-15.
    float* sG = (float*)sX;
    float ba[4];
    {
        int oc0 = wave * 16 + quad * 4;
#pragma unroll
        for (int r = 0; r < 4; ++r) ba[r] = bias[oc0 + r];
    }
    __syncthreads();
    if (wave >= 4) {
        int reg = (wave >> 2) - 1;            // 0=cf, 1=co, 2=cg
        int chb = (wave & 3) * 16 + quad * 4;
#pragma unroll
        for (int nf = 0; nf < 6; ++nf) {
            int px = nf * 16 + m;
            float* f = &sG[reg * 96 * 68 + (long)px * 68 + chb];
#pragma unroll
            for (int r = 0; r < 4; ++r) f[r] = acc[nf][r] + ba[r];
        }
    }
    __syncthreads();
    if (wave < 4) {
        int t = (z < 2) ? t0 : t1;
        int b = z & 1, dir = z >> 1;
        int chb = wave * 16 + quad * 4;
        unsigned short* hsq = hseq + ((long)(t * 2 + b) * HW) * 128 + dir * 64;
#pragma unroll
        for (int nf = 0; nf < 6; ++nf) {
            int px = nf * 16 + m;
            int p = (tY * 6 + nf) * WW + tX * 16 + m;
            float4 cf4 = *(float4*)&sG[0 * 96 * 68 + (long)px * 68 + chb];
            float4 co4 = *(float4*)&sG[1 * 96 * 68 + (long)px * 68 + chb];
            float4 cg4 = *(float4*)&sG[2 * 96 * 68 + (long)px * 68 + chb];
            float* cp = &cst[((long)z * HW + p) * 64 + chb];
            float4 cold = *(float4*)cp;
            float cfv[4] = {cf4.x, cf4.y, cf4.z, cf4.w};
            float cov[4] = {co4.x, co4.y, co4.z, co4.w};
            float cgv[4] = {cg4.x, cg4.y, cg4.z, cg4.w};
            float coldv[4] = {cold.x, cold.y, cold.z, cold.w};
            float c2v[4], h2v[4];
#pragma unroll
            for (int r = 0; r < 4; ++r) {
                float civ = acc[nf][r] + ba[r];
                float c2 = sigf(cfv[r]) * coldv[r] + sigf(civ) * tanhf(cgv[r]);
                float h2 = sigf(cov[r]) * tanhf(c2);
                c2v[r] = c2; h2v[r] = h2;
            }
            *(float4*)cp = (float4){c2v[0], c2v[1], c2v[2], c2v[3]};
            unsigned short* hp = hbuf + ((long)z * HW + p) * 128 + chb;
            ushort4 hv = {bhi(h2v[0]), bhi(h2v[1]), bhi(h2v[2]), bhi(h2v[3])};
            ushort4 lv = {blo(h2v[0]), blo(h2v[1]), blo(h2v[2]), blo(h2v[3])};
            *(ushort4*)hp = hv;
            *(ushort4*)(hp + 64) = lv;
            *(ushort4*)&hsq[(long)p * 128 + chb] = hv;
        }
    }
}

// ---------------------------------------------------------------------------
// cat conv: hseq (single-plane, IC=128) -> out fp32 NCHW with (t,b) permute.
// ---------------------------------------------------------------------------
__global__ __launch_bounds__(256) void cat_conv(
    const unsigned short* __restrict__ hseq,
    const unsigned short* __restrict__ Wk,     // [9][64][2][128]
    const float* __restrict__ bias,
    float* __restrict__ out)
{
    __shared__ unsigned short sX[108 * 136];
    const int tid = threadIdx.x;
    const int wave = tid >> 6, lane = tid & 63;
    const int m = lane & 15, quad = lane >> 4;
    const int tY = blockIdx.x / 6, tX = blockIdx.x % 6;
    const int img = blockIdx.z;
    const unsigned short* hp = hseq + (long)img * HW * 128;

    for (int i = tid; i < 108 * 16; i += 256) {
        int cell = i >> 4, v = i & 15;
        int row = cell / 18, col = cell - row * 18;
        int gy = tY * 4 + row - 1, gx = tX * 16 + col - 1;
        bf16x8 val = (bf16x8){0,0,0,0,0,0,0,0};
        if (gy >= 0 && gy < HH && gx >= 0 && gx < WW)
            val = *(const bf16x8*)(hp + (long)(gy * WW + gx) * 128 + v * 8);
        *(bf16x8*)&sX[cell * 136 + v * 8] = val;
    }
    __syncthreads();

    f32x4 acc[4];
#pragma unroll
    for (int nf = 0; nf < 4; ++nf) acc[nf] = (f32x4){0.f, 0.f, 0.f, 0.f};

#pragma unroll
    for (int c = 0; c < 4; ++c) {
#pragma unroll
        for (int kx = 0; kx < 3; ++kx) {
            bf16x8 B[6];
#pragma unroll
            for (int r = 0; r < 6; ++r)
                B[r] = *(const bf16x8*)&sX[(r * 18 + kx + m) * 136 + c * 32 + quad * 8];
            bf16x8 Ah[3], Al[3];
#pragma unroll
            for (int ky = 0; ky < 3; ++ky) {
                const unsigned short* wp = Wk + (((long)(ky * 3 + kx) * 64 + wave * 16 + m) * 2) * 128 + c * 32 + quad * 8;
                Ah[ky] = *(const bf16x8*)wp;
                Al[ky] = *(const bf16x8*)(wp + 128);
            }
#pragma unroll
            for (int ky = 0; ky < 3; ++ky)
#pragma unroll
                for (int nf = 0; nf < 4; ++nf) {
                    acc[nf] = __builtin_amdgcn_mfma_f32_16x16x32_bf16(Ah[ky], B[nf + ky], acc[nf], 0, 0, 0);
                    acc[nf] = __builtin_amdgcn_mfma_f32_16x16x32_bf16(Al[ky], B[nf + ky], acc[nf], 0, 0, 0);
                }
        }
    }

    int t = img >> 1, b = img & 1;
    long imgOut = (long)(b * TT + t) * 64 * HW;
#pragma unroll
    for (int reg = 0; reg < 4; ++reg) {
        int oc = wave * 16 + quad * 4 + reg;
        float bv = bias[oc];
#pragma unroll
        for (int nf = 0; nf < 4; ++nf) {
            int p = (tY * 4 + nf) * WW + tX * 16 + m;
            out[imgOut + (long)oc * HW + p] = acc[nf][reg] + bv;
        }
    }
}

// ---------------------------------------------------------------------------
extern "C" void kernel_launch(void* const* d_in, const int* in_sizes, int n_in,
                              void* d_out, int out_size, void* d_ws, size_t ws_size,
                              hipStream_t stream)
{
    const float* input  = (const float*)d_in[0];
    const float* fuse_w = (const float*)d_in[1];
    const float* fuse_b = (const float*)d_in[2];
    const float* om_w   = (const float*)d_in[3];
    const float* om_b   = (const float*)d_in[4];
    const float* dcn_w  = (const float*)d_in[5];
    const float* dcn_b  = (const float*)d_in[6];
    const float* conv_w = (const float*)d_in[7];
    const float* conv_b = (const float*)d_in[8];
    const float* cat_w  = (const float*)d_in[9];
    const float* cat_b  = (const float*)d_in[10];
    float* out = (float*)d_out;

    char* w = (char*)d_ws;
    size_t off = 0;
    auto alloc = [&](size_t bytes) { void* p = w + off; off += (bytes + 255) & ~(size_t)255; return p; };

    unsigned short* xbf    = (unsigned short*)alloc(10L * HW * 64 * 2);
    unsigned short* hbuf   = (unsigned short*)alloc(4L * HW * 128 * 2);
    unsigned short* comb   = (unsigned short*)alloc(4L * HW * 64 * 2);
    float*          omb    = (float*)alloc(4L * 216 * HW * 4);
    unsigned short* fusedb = (unsigned short*)alloc(4L * HW * 256 * 2);
    float*          cbufs  = (float*)alloc(4L * HW * 64 * 4);
    unsigned short* hseqb  = (unsigned short*)alloc(10L * HW * 128 * 2);
    unsigned short* Wf = (unsigned short*)alloc(9L * 64 * 2 * 128 * 2);
    unsigned short* Wo = (unsigned short*)alloc(9L * 256 * 2 * 64 * 2);
    unsigned short* Wc = (unsigned short*)alloc(9L * 256 * 2 * 128 * 2);
    unsigned short* Wk = (unsigned short*)alloc(9L * 64 * 2 * 128 * 2);
    unsigned short* W1 = (unsigned short*)alloc(128L * 2 * 576 * 2);

    dim3 blk(256);
    wexp3_kernel<<<dim3(288), blk, 0, stream>>>(fuse_w, Wf, 64, 64, 128);
    wexp3_kernel<<<dim3(576), blk, 0, stream>>>(om_w, Wo, 216, 256, 64);
    wexp3_kernel<<<dim3(1152), blk, 0, stream>>>(conv_w, Wc, 256, 256, 128);
    wexp3_kernel<<<dim3(288), blk, 0, stream>>>(cat_w, Wk, 64, 64, 128);
    wexp1_kernel<<<dim3(288), blk, 0, stream>>>(dcn_w, W1);
    xprep_kernel<<<dim3(23040), blk, 0, stream>>>(input, xbf);

    hipMemsetAsync(hbuf, 0, 4L * HW * 128 * 2, stream);
    hipMemsetAsync(cbufs, 0, 4L * HW * 64 * 4, stream);

    for (int s = 0; s < TT; ++s) {
        int t0 = s, t1 = TT - 1 - s;
        fuse_conv<<<dim3(144, 1, 4), blk, 0, stream>>>(
            xbf, hbuf, Wf, fuse_b, comb, t0, t1);
        om_conv<<<dim3(144, 1, 4), dim3(512), 0, stream>>>(
            comb, Wo, om_b, omb);
        conv1x1_fused<<<dim3(144, 4), blk, 0, stream>>>(
            hbuf, omb, W1, dcn_b, fusedb);
        big_conv_gates<<<dim3(96, 1, 4), dim3(1024), 0, stream>>>(
            fusedb, Wc, conv_b, cbufs, hbuf, hseqb, t0, t1);
    }
    cat_conv<<<dim3(144, 1, 10), blk, 0, stream>>>(hseqb, Wk, cat_b, out);
}

// Round 10
// 1591.349 us; speedup vs baseline: 1.1847x; 1.0906x over previous
//
#include <hip/hip_runtime.h>
#include <math.h>

#define HH 96
#define WW 96
#define HW 9216
#define TT 5

typedef __attribute__((ext_vector_type(8))) short bf16x8;
typedef __attribute__((ext_vector_type(4))) float f32x4;

__device__ __forceinline__ float sigf(float x) { return 1.0f / (1.0f + expf(-x)); }
__device__ __forceinline__ unsigned short bhi(float x) {
    return (unsigned short)(__float_as_uint(x) >> 16);
}
__device__ __forceinline__ unsigned short blo(float x) {
    float h = __uint_as_float(__float_as_uint(x) & 0xffff0000u);
    return (unsigned short)(__float_as_uint(x - h) >> 16);
}
__device__ __forceinline__ float b2f(unsigned short u) {
    return __uint_as_float(((unsigned)u) << 16);
}

// ---------------------------------------------------------------------------
// Weight expansion: src [OC][IC][9] fp32 -> dst [9][OCP][2][IC] bf16 hi/lo.
// ---------------------------------------------------------------------------
__global__ __launch_bounds__(256) void wexp3_kernel(
    const float* __restrict__ w, unsigned short* __restrict__ dst,
    int OC, int OCP, int IC)
{
    long i = (long)blockIdx.x * 256 + threadIdx.x;
    int ic = (int)(i % IC);
    long r = i / IC;
    int oc = (int)(r % OCP);
    int tap = (int)(r / OCP);
    float v = (oc < OC) ? w[((long)oc * IC + ic) * 9 + tap] : 0.f;
    long base = (((long)tap * OCP + oc) * 2) * IC + ic;
    dst[base] = bhi(v);
    dst[base + IC] = blo(v);
}

// dcn_w [128][576] (576 = c*9+k) -> [128][2][576] with K re-ordered k-major:
// dst K-slot (k*64 + c) = src (c*9 + k).
__global__ __launch_bounds__(256) void wexp1_kernel(
    const float* __restrict__ w, unsigned short* __restrict__ dst)
{
    int i = blockIdx.x * 256 + threadIdx.x;   // over 128*576 dst slots
    int slot = i % 576;                        // k*64 + c
    int oc = i / 576;
    int k = slot >> 6, c = slot & 63;
    float v = w[(long)oc * 576 + c * 9 + k];
    dst[((long)oc * 2) * 576 + slot] = bhi(v);
    dst[((long)oc * 2 + 1) * 576 + slot] = blo(v);
}

// input [b][t][64][HW] fp32 -> xbf [(t*2+b)][p][64] bf16
__global__ __launch_bounds__(256) void xprep_kernel(
    const float* __restrict__ input, unsigned short* __restrict__ xbf)
{
    long i = (long)blockIdx.x * 256 + threadIdx.x;
    int p = (int)(i % HW);
    long r = i / HW;
    int c = (int)(r % 64);
    long bt = r / 64;
    int b = (int)(bt / TT), t = (int)(bt % TT);
    float v = input[i];
    xbf[(((long)(t * 2 + b) * HW) + p) * 64 + c] = bhi(v);
}

// ===========================================================================
// R9 counters: conv1x1_fused = 133us, FETCH 252MB vs 41MB unique (6x
// over-fetch: scattered bilinear gathers thrash per-XCD L2 because default
// block->XCD round-robin gives no pt locality), occupancy 18% (grid-limited).
// R10: (1) XCD-aware bijective swizzle (576%8==0) -> each XCD owns a
// contiguous (zz, pt) chunk, hbuf slice ~4.7MB ~ L2-resident; (2) 512-thread
// blocks: 1 sample/thread/tap, 8 MFMA waves each owning one oc-16 block
// (same per-oc accumulation order -> bitwise-identical).
// ===========================================================================

// ---------------------------------------------------------------------------
// Fuse conv: x (single, ic 0..63) + h (hl, ic 64..127) -> comb bf16 NHWC.
// ---------------------------------------------------------------------------
__global__ __launch_bounds__(256) void fuse_conv(
    const unsigned short* __restrict__ xbf,
    const unsigned short* __restrict__ hbuf,
    const unsigned short* __restrict__ Wf,   // [9][64][2][128]
    const float* __restrict__ bias,
    unsigned short* __restrict__ comb,
    int t0, int t1)
{
    __shared__ unsigned short sX[108 * 200];
    const int tid = threadIdx.x;
    const int wave = tid >> 6, lane = tid & 63;
    const int m = lane & 15, quad = lane >> 4;
    const int tY = blockIdx.x / 6, tX = blockIdx.x % 6;
    const int z = blockIdx.z;
    const int imgX = ((z < 2) ? t0 : t1) * 2 + (z & 1);

    const unsigned short* xb = xbf + (long)imgX * HW * 64;
    const unsigned short* hb = hbuf + (long)z * HW * 128;

    for (int i = tid; i < 108 * 24; i += 256) {
        int cell = i / 24, v = i - cell * 24;
        int row = cell / 18, col = cell - row * 18;
        int gy = tY * 4 + row - 1, gx = tX * 16 + col - 1;
        bool ok = (gy >= 0 && gy < HH && gx >= 0 && gx < WW);
        int p = gy * WW + gx;
        bf16x8 val = (bf16x8){0,0,0,0,0,0,0,0};
        int dst;
        if (v < 8) {
            if (ok) val = *(const bf16x8*)(xb + (long)p * 64 + v * 8);
            dst = cell * 200 + v * 8;
        } else {
            int v2 = v - 8;
            int pl = v2 >> 3, c = (v2 & 7) >> 2, g = v2 & 3;
            if (ok) val = *(const bf16x8*)(hb + (long)p * 128 + pl * 64 + c * 32 + g * 8);
            dst = cell * 200 + 64 + (c * 2 + pl) * 32 + g * 8;
        }
        *(bf16x8*)&sX[dst] = val;
    }
    __syncthreads();

    f32x4 acc[4];
#pragma unroll
    for (int nf = 0; nf < 4; ++nf) acc[nf] = (f32x4){0.f, 0.f, 0.f, 0.f};

#pragma unroll
    for (int c = 0; c < 2; ++c) {
#pragma unroll
        for (int kx = 0; kx < 3; ++kx) {
            bf16x8 B[6];
#pragma unroll
            for (int r = 0; r < 6; ++r)
                B[r] = *(const bf16x8*)&sX[(r * 18 + kx + m) * 200 + c * 32 + quad * 8];
            bf16x8 Ah[3], Al[3];
#pragma unroll
            for (int ky = 0; ky < 3; ++ky) {
                const unsigned short* wp = Wf + (((long)(ky * 3 + kx) * 64 + wave * 16 + m) * 2) * 128 + c * 32 + quad * 8;
                Ah[ky] = *(const bf16x8*)wp;
                Al[ky] = *(const bf16x8*)(wp + 128);
            }
#pragma unroll
            for (int ky = 0; ky < 3; ++ky)
#pragma unroll
                for (int nf = 0; nf < 4; ++nf) {
                    acc[nf] = __builtin_amdgcn_mfma_f32_16x16x32_bf16(Ah[ky], B[nf + ky], acc[nf], 0, 0, 0);
                    acc[nf] = __builtin_amdgcn_mfma_f32_16x16x32_bf16(Al[ky], B[nf + ky], acc[nf], 0, 0, 0);
                }
        }
    }
#pragma unroll
    for (int c = 0; c < 2; ++c) {
#pragma unroll
        for (int kx = 0; kx < 3; ++kx) {
            bf16x8 Bh[6], Bl[6];
#pragma unroll
            for (int r = 0; r < 6; ++r) {
                int base = (r * 18 + kx + m) * 200 + 64 + (c * 2) * 32 + quad * 8;
                Bh[r] = *(const bf16x8*)&sX[base];
                Bl[r] = *(const bf16x8*)&sX[base + 32];
            }
            bf16x8 Ah[3], Al[3];
#pragma unroll
            for (int ky = 0; ky < 3; ++ky) {
                const unsigned short* wp = Wf + (((long)(ky * 3 + kx) * 64 + wave * 16 + m) * 2) * 128 + (2 + c) * 32 + quad * 8;
                Ah[ky] = *(const bf16x8*)wp;
                Al[ky] = *(const bf16x8*)(wp + 128);
            }
#pragma unroll
            for (int ky = 0; ky < 3; ++ky)
#pragma unroll
                for (int nf = 0; nf < 4; ++nf) {
                    acc[nf] = __builtin_amdgcn_mfma_f32_16x16x32_bf16(Ah[ky], Bh[nf + ky], acc[nf], 0, 0, 0);
                    acc[nf] = __builtin_amdgcn_mfma_f32_16x16x32_bf16(Al[ky], Bh[nf + ky], acc[nf], 0, 0, 0);
                    acc[nf] = __builtin_amdgcn_mfma_f32_16x16x32_bf16(Ah[ky], Bl[nf + ky], acc[nf], 0, 0, 0);
                }
        }
    }

    int ocl = wave * 16 + quad * 4;
    float b0 = bias[ocl], b1 = bias[ocl + 1], b2 = bias[ocl + 2], b3 = bias[ocl + 3];
#pragma unroll
    for (int nf = 0; nf < 4; ++nf) {
        int p = (tY * 4 + nf) * WW + tX * 16 + m;
        ushort4 hv;
        hv.x = bhi(acc[nf].x + b0); hv.y = bhi(acc[nf].y + b1);
        hv.z = bhi(acc[nf].z + b2); hv.w = bhi(acc[nf].w + b3);
        *(ushort4*)&comb[((long)z * HW + p) * 64 + ocl] = hv;
    }
}

// ---------------------------------------------------------------------------
// om conv: comb (single, IC=64) -> om fp32 NCHW (216 of 256 oc).
// ---------------------------------------------------------------------------
__global__ __launch_bounds__(512) void om_conv(
    const unsigned short* __restrict__ comb,
    const unsigned short* __restrict__ Wo,   // [9][256][2][64]
    const float* __restrict__ bias,
    float* __restrict__ om)                  // [z][216][HW]
{
    __shared__ unsigned short sX[108 * 72];
    const int tid = threadIdx.x;
    const int wave = tid >> 6, lane = tid & 63;
    const int m = lane & 15, quad = lane >> 4;
    const int tY = blockIdx.x / 6, tX = blockIdx.x % 6;
    const int z = blockIdx.z;
    const unsigned short* cbp = comb + (long)z * HW * 64;

    for (int i = tid; i < 108 * 8; i += 512) {
        int cell = i >> 3, v = i & 7;
        int row = cell / 18, col = cell - row * 18;
        int gy = tY * 4 + row - 1, gx = tX * 16 + col - 1;
        bf16x8 val = (bf16x8){0,0,0,0,0,0,0,0};
        if (gy >= 0 && gy < HH && gx >= 0 && gx < WW)
            val = *(const bf16x8*)(cbp + (long)(gy * WW + gx) * 64 + v * 8);
        *(bf16x8*)&sX[cell * 72 + v * 8] = val;
    }
    __syncthreads();

    f32x4 acc[2][4];
#pragma unroll
    for (int mi = 0; mi < 2; ++mi)
#pragma unroll
        for (int nf = 0; nf < 4; ++nf) acc[mi][nf] = (f32x4){0.f, 0.f, 0.f, 0.f};

#pragma unroll
    for (int c = 0; c < 2; ++c) {
#pragma unroll
        for (int kx = 0; kx < 3; ++kx) {
            bf16x8 B[6];
#pragma unroll
            for (int r = 0; r < 6; ++r)
                B[r] = *(const bf16x8*)&sX[(r * 18 + kx + m) * 72 + c * 32 + quad * 8];
            bf16x8 Ah[3][2], Al[3][2];
#pragma unroll
            for (int ky = 0; ky < 3; ++ky)
#pragma unroll
                for (int mi = 0; mi < 2; ++mi) {
                    const unsigned short* wp = Wo + (((long)(ky * 3 + kx) * 256 + (wave * 2 + mi) * 16 + m) * 2) * 64 + c * 32 + quad * 8;
                    Ah[ky][mi] = *(const bf16x8*)wp;
                    Al[ky][mi] = *(const bf16x8*)(wp + 64);
                }
#pragma unroll
            for (int ky = 0; ky < 3; ++ky)
#pragma unroll
                for (int mi = 0; mi < 2; ++mi)
#pragma unroll
                    for (int nf = 0; nf < 4; ++nf) {
                        acc[mi][nf] = __builtin_amdgcn_mfma_f32_16x16x32_bf16(Ah[ky][mi], B[nf + ky], acc[mi][nf], 0, 0, 0);
                        acc[mi][nf] = __builtin_amdgcn_mfma_f32_16x16x32_bf16(Al[ky][mi], B[nf + ky], acc[mi][nf], 0, 0, 0);
                    }
        }
    }

#pragma unroll
    for (int mi = 0; mi < 2; ++mi) {
#pragma unroll
        for (int reg = 0; reg < 4; ++reg) {
            int oc = (wave * 2 + mi) * 16 + quad * 4 + reg;
            if (oc < 216) {
                float bv = bias[oc];
#pragma unroll
                for (int nf = 0; nf < 4; ++nf) {
                    int p = (tY * 4 + nf) * WW + tX * 16 + m;
                    om[((long)z * 216 + oc) * HW + p] = acc[mi][nf][reg] + bv;
                }
            }
        }
    }
}

// ---------------------------------------------------------------------------
// FUSED deformable-sampling + 1x1 DCN einsum (512 threads, XCD-swizzled).
// Sampling: thread (g0 = tid>>6, cell = tid&63) computes ONE bilinear sample
// per tap (expression-identical to before -> bitwise-same bf16). MFMA: 8
// waves, wave w owns oc block w (per-oc accumulation order unchanged).
// Grid is 1D 576 with bijective XCD swizzle: xcd = bid&7 owns a contiguous
// (zz, pt) chunk so its hbuf slice (~4.7MB) stays L2-resident.
// ---------------------------------------------------------------------------
__global__ __launch_bounds__(512) void conv1x1_fused(
    const unsigned short* __restrict__ hbuf,  // [4][p][128] hl
    const float* __restrict__ om,             // [4][216][HW]
    const unsigned short* __restrict__ w1,    // [128][2][576] k-major
    const float* __restrict__ bias,
    unsigned short* __restrict__ fused)       // [z][p][256] hl
{
    __shared__ unsigned short sX[64 * 76];
    const int tid  = threadIdx.x;
    const int wave = tid >> 6, lane = tid & 63;
    const int m = lane & 15, quad = lane >> 4;

    // bijective XCD swizzle over 576 = 8 XCDs x 72 chunks
    const int bid = blockIdx.x;
    const int work = (bid & 7) * 72 + (bid >> 3);
    const int zz = work / 144;
    const int pt = work - zz * 144;

    const float* omb = om + (long)zz * 216 * HW;
    const unsigned short* hz = hbuf + (long)zz * HW * 128;

    const int g0 = tid >> 6;        // 0..7  (channel group; = wave)
    const int cellb = tid & 63;     // 0..63 (pixel within tile)

    // Bilinear-sample 8 channels (group g0) at pixel p=pt*64+cell, tap cb.
    // Expression-identical to the old dcn_sample_kernel -> bitwise-same bf16.
    auto sample = [&](int cell, int cb) -> bf16x8 {
        int p = pt * 64 + cell;
        int y = p / WW, x = p - y * WW;
        int ky = cb / 3, kx = cb - ky * 3;
        float offy = omb[(g0 * 18 + cb * 2) * HW + p];
        float offx = omb[(g0 * 18 + cb * 2 + 1) * HW + p];
        float mm = sigf(omb[(144 + g0 * 9 + cb) * HW + p]);
        float py = (float)(y + ky - 1) + offy;
        float px = (float)(x + kx - 1) + offx;
        float y0f = floorf(py), x0f = floorf(px);
        float wy = py - y0f, wx = px - x0f;
        int y0 = (int)y0f, x0 = (int)x0f;
        int y1 = y0 + 1, x1 = x0 + 1;
        bool vy0 = (y0 >= 0) && (y0 < HH), vy1 = (y1 >= 0) && (y1 < HH);
        bool vx0 = (x0 >= 0) && (x0 < WW), vx1 = (x1 >= 0) && (x1 < WW);
        int cy0 = min(max(y0, 0), HH - 1), cy1 = min(max(y1, 0), HH - 1);
        int cx0 = min(max(x0, 0), WW - 1), cx1 = min(max(x1, 0), WW - 1);
        long i00 = cy0 * WW + cx0, i01 = cy0 * WW + cx1;
        long i10 = cy1 * WW + cx0, i11 = cy1 * WW + cx1;
        float w00 = (1.f - wy) * (1.f - wx) * ((vy0 && vx0) ? mm : 0.f);
        float w01 = (1.f - wy) * wx         * ((vy0 && vx1) ? mm : 0.f);
        float w10 = wy * (1.f - wx)         * ((vy1 && vx0) ? mm : 0.f);
        float w11 = wy * wx                 * ((vy1 && vx1) ? mm : 0.f);
        const unsigned short* hzb = hz + g0 * 8;
        bf16x8 h00 = *(const bf16x8*)(hzb + i00 * 128);
        bf16x8 l00 = *(const bf16x8*)(hzb + i00 * 128 + 64);
        bf16x8 h01 = *(const bf16x8*)(hzb + i01 * 128);
        bf16x8 l01 = *(const bf16x8*)(hzb + i01 * 128 + 64);
        bf16x8 h10 = *(const bf16x8*)(hzb + i10 * 128);
        bf16x8 l10 = *(const bf16x8*)(hzb + i10 * 128 + 64);
        bf16x8 h11 = *(const bf16x8*)(hzb + i11 * 128);
        bf16x8 l11 = *(const bf16x8*)(hzb + i11 * 128 + 64);
        bf16x8 outv;
#pragma unroll
        for (int cg = 0; cg < 8; ++cg) {
            float v00 = b2f((unsigned short)h00[cg]) + b2f((unsigned short)l00[cg]);
            float v01 = b2f((unsigned short)h01[cg]) + b2f((unsigned short)l01[cg]);
            float v10 = b2f((unsigned short)h10[cg]) + b2f((unsigned short)l10[cg]);
            float v11 = b2f((unsigned short)h11[cg]) + b2f((unsigned short)l11[cg]);
            float v = w00 * v00 + w01 * v01 + w10 * v10 + w11 * v11;
            outv[cg] = (short)bhi(v);
        }
        return outv;
    };

    f32x4 acc[4];
#pragma unroll
    for (int nf = 0; nf < 4; ++nf) acc[nf] = (f32x4){0.f, 0.f, 0.f, 0.f};

    for (int cb = 0; cb < 9; ++cb) {
        if (cb) __syncthreads();
        bf16x8 R0 = sample(cellb, cb);
        *(bf16x8*)&sX[cellb * 76 + g0 * 8] = R0;
        __syncthreads();

        bf16x8 Bv[2][4];
#pragma unroll
        for (int sub = 0; sub < 2; ++sub)
#pragma unroll
            for (int nf = 0; nf < 4; ++nf)
                Bv[sub][nf] = *(const bf16x8*)&sX[(nf * 16 + m) * 76 + sub * 32 + quad * 8];
        bf16x8 Ah[2], Al[2];
#pragma unroll
        for (int sub = 0; sub < 2; ++sub) {
            const unsigned short* wp = w1 + ((long)(wave * 16 + m) * 2) * 576
                                       + cb * 64 + sub * 32 + quad * 8;
            Ah[sub] = *(const bf16x8*)wp;
            Al[sub] = *(const bf16x8*)(wp + 576);
        }
#pragma unroll
        for (int sub = 0; sub < 2; ++sub)
#pragma unroll
            for (int nf = 0; nf < 4; ++nf) {
                acc[nf] = __builtin_amdgcn_mfma_f32_16x16x32_bf16(
                    Ah[sub], Bv[sub][nf], acc[nf], 0, 0, 0);
                acc[nf] = __builtin_amdgcn_mfma_f32_16x16x32_bf16(
                    Al[sub], Bv[sub][nf], acc[nf], 0, 0, 0);
            }
    }

    {
        int ocl = wave * 16 + quad * 4;
        float b0 = bias[ocl], b1 = bias[ocl + 1], b2 = bias[ocl + 2], b3 = bias[ocl + 3];
#pragma unroll
        for (int nf = 0; nf < 4; ++nf) {
            int p = pt * 64 + nf * 16 + m;
            float v0 = fmaxf(acc[nf].x + b0, 0.f);
            float v1 = fmaxf(acc[nf].y + b1, 0.f);
            float v2 = fmaxf(acc[nf].z + b2, 0.f);
            float v3 = fmaxf(acc[nf].w + b3, 0.f);
            unsigned short* op = fused + ((long)zz * HW + p) * 256 + ocl;
            ushort4 hv, lv;
            hv.x = bhi(v0); hv.y = bhi(v1); hv.z = bhi(v2); hv.w = bhi(v3);
            lv.x = blo(v0); lv.y = blo(v1); lv.z = blo(v2); lv.w = blo(v3);
            *(ushort4*)op = hv;
            *(ushort4*)(op + 128) = lv;
        }
    }
}

// ---------------------------------------------------------------------------
// Big conv (IC=128 hl, OC=256) FUSED with LSTM gates.
// 16-wave blocks (1024 thr), 6x16 tile, 384 blocks (the proven-fastest block
// count). Each wave owns ONE oc-16 block (wave = oc>>4): acc[6] = 24 VGPR
// (no spill), 6 weight loads per (c,kx) feed 54 MFMAs. R8-measured: 102us,
// WRITE exactly intended, VGPR 56. Best-known config — unchanged this round.
// ---------------------------------------------------------------------------
__global__ __launch_bounds__(1024) void big_conv_gates(
    const unsigned short* __restrict__ fusedb,  // [z][p][256] hl
    const unsigned short* __restrict__ Wc,      // [9][256][2][128]
    const float* __restrict__ bias,
    float* __restrict__ cst,                    // [z][p][64] fp32
    unsigned short* __restrict__ hbuf,          // [z][p][128] hl
    unsigned short* __restrict__ hseq,          // [(t*2+b)][p][128]
    int t0, int t1)
{
    // 39168 ush = 78336 B. Staging: 144 cells x 264 = 38016 ush (76032 B).
    // Gates: 3 regions x 96 px x 68 floats = 19584 floats = 78336 B.
    __shared__ unsigned short sX[39168];
    const int tid = threadIdx.x;
    const int wave = tid >> 6, lane = tid & 63;
    const int m = lane & 15, quad = lane >> 4;
    const int tY = blockIdx.x / 6, tX = blockIdx.x % 6;   // tY 0..15
    const int z = blockIdx.z;

    const unsigned short* fb = fusedb + (long)z * HW * 256;

    for (int i = tid; i < 144 * 32; i += 1024) {
        int cell = i >> 5, v = i & 31;
        int row = cell / 18, col = cell - row * 18;
        int gy = tY * 6 + row - 1, gx = tX * 16 + col - 1;
        int pl = v >> 4, c = (v & 15) >> 2, g = v & 3;
        bf16x8 val = (bf16x8){0,0,0,0,0,0,0,0};
        if (gy >= 0 && gy < HH && gx >= 0 && gx < WW)
            val = *(const bf16x8*)(fb + (long)(gy * WW + gx) * 256 + pl * 128 + c * 32 + g * 8);
        *(bf16x8*)&sX[cell * 264 + (c * 2 + pl) * 32 + g * 8] = val;
    }
    __syncthreads();

    f32x4 acc[6];
#pragma unroll
    for (int nf = 0; nf < 6; ++nf) acc[nf] = (f32x4){0.f, 0.f, 0.f, 0.f};

#pragma unroll
    for (int c = 0; c < 4; ++c) {
#pragma unroll
        for (int kx = 0; kx < 3; ++kx) {
            bf16x8 Ah[3], Al[3];
#pragma unroll
            for (int ky = 0; ky < 3; ++ky) {
                const unsigned short* wp = Wc + (((long)(ky * 3 + kx) * 256 + wave * 16 + m) * 2) * 128 + c * 32 + quad * 8;
                Ah[ky] = *(const bf16x8*)wp;
                Al[ky] = *(const bf16x8*)(wp + 128);
            }
            bf16x8 Bh[8], Bl[8];
#pragma unroll
            for (int r = 0; r < 3; ++r) {
                int base = (r * 18 + kx + m) * 264 + (c * 2) * 32 + quad * 8;
                Bh[r] = *(const bf16x8*)&sX[base];
                Bl[r] = *(const bf16x8*)&sX[base + 32];
            }
            // nf-outer, rolling 3-row B window: row nf+2 loaded at nf>0, rows
            // < nf dead -> ~6 live B regs. Per-acc (ky, term) order unchanged.
#pragma unroll
            for (int nf = 0; nf < 6; ++nf) {
                if (nf) {
                    int r = nf + 2;
                    int base = (r * 18 + kx + m) * 264 + (c * 2) * 32 + quad * 8;
                    Bh[r] = *(const bf16x8*)&sX[base];
                    Bl[r] = *(const bf16x8*)&sX[base + 32];
                }
#pragma unroll
                for (int ky = 0; ky < 3; ++ky) {
                    acc[nf] = __builtin_amdgcn_mfma_f32_16x16x32_bf16(Ah[ky], Bh[nf + ky], acc[nf], 0, 0, 0);
                    acc[nf] = __builtin_amdgcn_mfma_f32_16x16x32_bf16(Al[ky], Bh[nf + ky], acc[nf], 0, 0, 0);
                    acc[nf] = __builtin_amdgcn_mfma_f32_16x16x32_bf16(Ah[ky], Bl[nf + ky], acc[nf], 0, 0, 0);
                }
            }
        }
    }

    // ---- gates epilogue ----
    // wave w owns oc block w: ci = w0-3, cf = w4-7, co = w8-11, cg = w12-15.
    float* sG = (float*)sX;
    float ba[4];
    {
        int oc0 = wave * 16 + quad * 4;
#pragma unroll
        for (int r = 0; r < 4; ++r) ba[r] = bias[oc0 + r];
    }
    __syncthreads();
    if (wave >= 4) {
        int reg = (wave >> 2) - 1;            // 0=cf, 1=co, 2=cg
        int chb = (wave & 3) * 16 + quad * 4;
#pragma unroll
        for (int nf = 0; nf < 6; ++nf) {
            int px = nf * 16 + m;
            float* f = &sG[reg * 96 * 68 + (long)px * 68 + chb];
#pragma unroll
            for (int r = 0; r < 4; ++r) f[r] = acc[nf][r] + ba[r];
        }
    }
    __syncthreads();
    if (wave < 4) {
        int t = (z < 2) ? t0 : t1;
        int b = z & 1, dir = z >> 1;
        int chb = wave * 16 + quad * 4;
        unsigned short* hsq = hseq + ((long)(t * 2 + b) * HW) * 128 + dir * 64;
#pragma unroll
        for (int nf = 0; nf < 6; ++nf) {
            int px = nf * 16 + m;
            int p = (tY * 6 + nf) * WW + tX * 16 + m;
            float4 cf4 = *(float4*)&sG[0 * 96 * 68 + (long)px * 68 + chb];
            float4 co4 = *(float4*)&sG[1 * 96 * 68 + (long)px * 68 + chb];
            float4 cg4 = *(float4*)&sG[2 * 96 * 68 + (long)px * 68 + chb];
            float* cp = &cst[((long)z * HW + p) * 64 + chb];
            float4 cold = *(float4*)cp;
            float cfv[4] = {cf4.x, cf4.y, cf4.z, cf4.w};
            float cov[4] = {co4.x, co4.y, co4.z, co4.w};
            float cgv[4] = {cg4.x, cg4.y, cg4.z, cg4.w};
            float coldv[4] = {cold.x, cold.y, cold.z, cold.w};
            float c2v[4], h2v[4];
#pragma unroll
            for (int r = 0; r < 4; ++r) {
                float civ = acc[nf][r] + ba[r];
                float c2 = sigf(cfv[r]) * coldv[r] + sigf(civ) * tanhf(cgv[r]);
                float h2 = sigf(cov[r]) * tanhf(c2);
                c2v[r] = c2; h2v[r] = h2;
            }
            *(float4*)cp = (float4){c2v[0], c2v[1], c2v[2], c2v[3]};
            unsigned short* hp = hbuf + ((long)z * HW + p) * 128 + chb;
            ushort4 hv = {bhi(h2v[0]), bhi(h2v[1]), bhi(h2v[2]), bhi(h2v[3])};
            ushort4 lv = {blo(h2v[0]), blo(h2v[1]), blo(h2v[2]), blo(h2v[3])};
            *(ushort4*)hp = hv;
            *(ushort4*)(hp + 64) = lv;
            *(ushort4*)&hsq[(long)p * 128 + chb] = hv;
        }
    }
}

// ---------------------------------------------------------------------------
// cat conv: hseq (single-plane, IC=128) -> out fp32 NCHW with (t,b) permute.
// ---------------------------------------------------------------------------
__global__ __launch_bounds__(256) void cat_conv(
    const unsigned short* __restrict__ hseq,
    const unsigned short* __restrict__ Wk,     // [9][64][2][128]
    const float* __restrict__ bias,
    float* __restrict__ out)
{
    __shared__ unsigned short sX[108 * 136];
    const int tid = threadIdx.x;
    const int wave = tid >> 6, lane = tid & 63;
    const int m = lane & 15, quad = lane >> 4;
    const int tY = blockIdx.x / 6, tX = blockIdx.x % 6;
    const int img = blockIdx.z;
    const unsigned short* hp = hseq + (long)img * HW * 128;

    for (int i = tid; i < 108 * 16; i += 256) {
        int cell = i >> 4, v = i & 15;
        int row = cell / 18, col = cell - row * 18;
        int gy = tY * 4 + row - 1, gx = tX * 16 + col - 1;
        bf16x8 val = (bf16x8){0,0,0,0,0,0,0,0};
        if (gy >= 0 && gy < HH && gx >= 0 && gx < WW)
            val = *(const bf16x8*)(hp + (long)(gy * WW + gx) * 128 + v * 8);
        *(bf16x8*)&sX[cell * 136 + v * 8] = val;
    }
    __syncthreads();

    f32x4 acc[4];
#pragma unroll
    for (int nf = 0; nf < 4; ++nf) acc[nf] = (f32x4){0.f, 0.f, 0.f, 0.f};

#pragma unroll
    for (int c = 0; c < 4; ++c) {
#pragma unroll
        for (int kx = 0; kx < 3; ++kx) {
            bf16x8 B[6];
#pragma unroll
            for (int r = 0; r < 6; ++r)
                B[r] = *(const bf16x8*)&sX[(r * 18 + kx + m) * 136 + c * 32 + quad * 8];
            bf16x8 Ah[3], Al[3];
#pragma unroll
            for (int ky = 0; ky < 3; ++ky) {
                const unsigned short* wp = Wk + (((long)(ky * 3 + kx) * 64 + wave * 16 + m) * 2) * 128 + c * 32 + quad * 8;
                Ah[ky] = *(const bf16x8*)wp;
                Al[ky] = *(const bf16x8*)(wp + 128);
            }
#pragma unroll
            for (int ky = 0; ky < 3; ++ky)
#pragma unroll
                for (int nf = 0; nf < 4; ++nf) {
                    acc[nf] = __builtin_amdgcn_mfma_f32_16x16x32_bf16(Ah[ky], B[nf + ky], acc[nf], 0, 0, 0);
                    acc[nf] = __builtin_amdgcn_mfma_f32_16x16x32_bf16(Al[ky], B[nf + ky], acc[nf], 0, 0, 0);
                }
        }
    }

    int t = img >> 1, b = img & 1;
    long imgOut = (long)(b * TT + t) * 64 * HW;
#pragma unroll
    for (int reg = 0; reg < 4; ++reg) {
        int oc = wave * 16 + quad * 4 + reg;
        float bv = bias[oc];
#pragma unroll
        for (int nf = 0; nf < 4; ++nf) {
            int p = (tY * 4 + nf) * WW + tX * 16 + m;
            out[imgOut + (long)oc * HW + p] = acc[nf][reg] + bv;
        }
    }
}

// ---------------------------------------------------------------------------
extern "C" void kernel_launch(void* const* d_in, const int* in_sizes, int n_in,
                              void* d_out, int out_size, void* d_ws, size_t ws_size,
                              hipStream_t stream)
{
    const float* input  = (const float*)d_in[0];
    const float* fuse_w = (const float*)d_in[1];
    const float* fuse_b = (const float*)d_in[2];
    const float* om_w   = (const float*)d_in[3];
    const float* om_b   = (const float*)d_in[4];
    const float* dcn_w  = (const float*)d_in[5];
    const float* dcn_b  = (const float*)d_in[6];
    const float* conv_w = (const float*)d_in[7];
    const float* conv_b = (const float*)d_in[8];
    const float* cat_w  = (const float*)d_in[9];
    const float* cat_b  = (const float*)d_in[10];
    float* out = (float*)d_out;

    char* w = (char*)d_ws;
    size_t off = 0;
    auto alloc = [&](size_t bytes) { void* p = w + off; off += (bytes + 255) & ~(size_t)255; return p; };

    unsigned short* xbf    = (unsigned short*)alloc(10L * HW * 64 * 2);
    unsigned short* hbuf   = (unsigned short*)alloc(4L * HW * 128 * 2);
    unsigned short* comb   = (unsigned short*)alloc(4L * HW * 64 * 2);
    float*          omb    = (float*)alloc(4L * 216 * HW * 4);
    unsigned short* fusedb = (unsigned short*)alloc(4L * HW * 256 * 2);
    float*          cbufs  = (float*)alloc(4L * HW * 64 * 4);
    unsigned short* hseqb  = (unsigned short*)alloc(10L * HW * 128 * 2);
    unsigned short* Wf = (unsigned short*)alloc(9L * 64 * 2 * 128 * 2);
    unsigned short* Wo = (unsigned short*)alloc(9L * 256 * 2 * 64 * 2);
    unsigned short* Wc = (unsigned short*)alloc(9L * 256 * 2 * 128 * 2);
    unsigned short* Wk = (unsigned short*)alloc(9L * 64 * 2 * 128 * 2);
    unsigned short* W1 = (unsigned short*)alloc(128L * 2 * 576 * 2);

    dim3 blk(256);
    wexp3_kernel<<<dim3(288), blk, 0, stream>>>(fuse_w, Wf, 64, 64, 128);
    wexp3_kernel<<<dim3(576), blk, 0, stream>>>(om_w, Wo, 216, 256, 64);
    wexp3_kernel<<<dim3(1152), blk, 0, stream>>>(conv_w, Wc, 256, 256, 128);
    wexp3_kernel<<<dim3(288), blk, 0, stream>>>(cat_w, Wk, 64, 64, 128);
    wexp1_kernel<<<dim3(288), blk, 0, stream>>>(dcn_w, W1);
    xprep_kernel<<<dim3(23040), blk, 0, stream>>>(input, xbf);

    hipMemsetAsync(hbuf, 0, 4L * HW * 128 * 2, stream);
    hipMemsetAsync(cbufs, 0, 4L * HW * 64 * 4, stream);

    for (int s = 0; s < TT; ++s) {
        int t0 = s, t1 = TT - 1 - s;
        fuse_conv<<<dim3(144, 1, 4), blk, 0, stream>>>(
            xbf, hbuf, Wf, fuse_b, comb, t0, t1);
        om_conv<<<dim3(144, 1, 4), dim3(512), 0, stream>>>(
            comb, Wo, om_b, omb);
        conv1x1_fused<<<dim3(576), dim3(512), 0, stream>>>(
            hbuf, omb, W1, dcn_b, fusedb);
        big_conv_gates<<<dim3(96, 1, 4), dim3(1024), 0, stream>>>(
            fusedb, Wc, conv_b, cbufs, hbuf, hseqb, t0, t1);
    }
    cat_conv<<<dim3(144, 1, 10), blk, 0, stream>>>(hseqb, Wk, cat_b, out);
}

// Round 11
// 1589.572 us; speedup vs baseline: 1.1860x; 1.0011x over previous
//
#include <hip/hip_runtime.h>
#include <math.h>

#define HH 96
#define WW 96
#define HW 9216
#define TT 5

typedef __attribute__((ext_vector_type(8))) short bf16x8;
typedef __attribute__((ext_vector_type(4))) float f32x4;

__device__ __forceinline__ float sigf(float x) { return 1.0f / (1.0f + expf(-x)); }
__device__ __forceinline__ unsigned short bhi(float x) {
    return (unsigned short)(__float_as_uint(x) >> 16);
}
__device__ __forceinline__ unsigned short blo(float x) {
    float h = __uint_as_float(__float_as_uint(x) & 0xffff0000u);
    return (unsigned short)(__float_as_uint(x - h) >> 16);
}
__device__ __forceinline__ float b2f(unsigned short u) {
    return __uint_as_float(((unsigned)u) << 16);
}

// ---------------------------------------------------------------------------
// Weight expansion: src [OC][IC][9] fp32 -> dst [9][OCP][2][IC] bf16 hi/lo.
// ---------------------------------------------------------------------------
__global__ __launch_bounds__(256) void wexp3_kernel(
    const float* __restrict__ w, unsigned short* __restrict__ dst,
    int OC, int OCP, int IC)
{
    long i = (long)blockIdx.x * 256 + threadIdx.x;
    int ic = (int)(i % IC);
    long r = i / IC;
    int oc = (int)(r % OCP);
    int tap = (int)(r / OCP);
    float v = (oc < OC) ? w[((long)oc * IC + ic) * 9 + tap] : 0.f;
    long base = (((long)tap * OCP + oc) * 2) * IC + ic;
    dst[base] = bhi(v);
    dst[base + IC] = blo(v);
}

// dcn_w [128][576] (576 = c*9+k) -> [128][2][576] with K re-ordered k-major:
// dst K-slot (k*64 + c) = src (c*9 + k).
__global__ __launch_bounds__(256) void wexp1_kernel(
    const float* __restrict__ w, unsigned short* __restrict__ dst)
{
    int i = blockIdx.x * 256 + threadIdx.x;   // over 128*576 dst slots
    int slot = i % 576;                        // k*64 + c
    int oc = i / 576;
    int k = slot >> 6, c = slot & 63;
    float v = w[(long)oc * 576 + c * 9 + k];
    dst[((long)oc * 2) * 576 + slot] = bhi(v);
    dst[((long)oc * 2 + 1) * 576 + slot] = blo(v);
}

// input [b][t][64][HW] fp32 -> xbf [(t*2+b)][p][64] bf16
__global__ __launch_bounds__(256) void xprep_kernel(
    const float* __restrict__ input, unsigned short* __restrict__ xbf)
{
    long i = (long)blockIdx.x * 256 + threadIdx.x;
    int p = (int)(i % HW);
    long r = i / HW;
    int c = (int)(r % 64);
    long bt = r / 64;
    int b = (int)(bt / TT), t = (int)(bt % TT);
    float v = input[i];
    xbf[(((long)(t * 2 + b) * HW) + p) * 64 + c] = bhi(v);
}

// ===========================================================================
// R10 counters: XCD swizzle killed conv1x1's over-fetch (FETCH 252->22MB,
// dur 133->108.5) but it is now latency/serialization-bound (all pipes idle,
// 2 barriers/tap phase-lock all 8 waves into the gather stall, 2.25 blk/CU).
// R11: double-buffered LDS (ONE barrier/tap) + one-tap-ahead pipeline:
// gathers for tap k+1 issued before tap k's MFMA; om for k+2 loaded a full
// iteration early (breaks the om->gather serial chain). Numerics identical.
// ===========================================================================

// ---------------------------------------------------------------------------
// Fuse conv: x (single, ic 0..63) + h (hl, ic 64..127) -> comb bf16 NHWC.
// ---------------------------------------------------------------------------
__global__ __launch_bounds__(256) void fuse_conv(
    const unsigned short* __restrict__ xbf,
    const unsigned short* __restrict__ hbuf,
    const unsigned short* __restrict__ Wf,   // [9][64][2][128]
    const float* __restrict__ bias,
    unsigned short* __restrict__ comb,
    int t0, int t1)
{
    __shared__ unsigned short sX[108 * 200];
    const int tid = threadIdx.x;
    const int wave = tid >> 6, lane = tid & 63;
    const int m = lane & 15, quad = lane >> 4;
    const int tY = blockIdx.x / 6, tX = blockIdx.x % 6;
    const int z = blockIdx.z;
    const int imgX = ((z < 2) ? t0 : t1) * 2 + (z & 1);

    const unsigned short* xb = xbf + (long)imgX * HW * 64;
    const unsigned short* hb = hbuf + (long)z * HW * 128;

    for (int i = tid; i < 108 * 24; i += 256) {
        int cell = i / 24, v = i - cell * 24;
        int row = cell / 18, col = cell - row * 18;
        int gy = tY * 4 + row - 1, gx = tX * 16 + col - 1;
        bool ok = (gy >= 0 && gy < HH && gx >= 0 && gx < WW);
        int p = gy * WW + gx;
        bf16x8 val = (bf16x8){0,0,0,0,0,0,0,0};
        int dst;
        if (v < 8) {
            if (ok) val = *(const bf16x8*)(xb + (long)p * 64 + v * 8);
            dst = cell * 200 + v * 8;
        } else {
            int v2 = v - 8;
            int pl = v2 >> 3, c = (v2 & 7) >> 2, g = v2 & 3;
            if (ok) val = *(const bf16x8*)(hb + (long)p * 128 + pl * 64 + c * 32 + g * 8);
            dst = cell * 200 + 64 + (c * 2 + pl) * 32 + g * 8;
        }
        *(bf16x8*)&sX[dst] = val;
    }
    __syncthreads();

    f32x4 acc[4];
#pragma unroll
    for (int nf = 0; nf < 4; ++nf) acc[nf] = (f32x4){0.f, 0.f, 0.f, 0.f};

#pragma unroll
    for (int c = 0; c < 2; ++c) {
#pragma unroll
        for (int kx = 0; kx < 3; ++kx) {
            bf16x8 B[6];
#pragma unroll
            for (int r = 0; r < 6; ++r)
                B[r] = *(const bf16x8*)&sX[(r * 18 + kx + m) * 200 + c * 32 + quad * 8];
            bf16x8 Ah[3], Al[3];
#pragma unroll
            for (int ky = 0; ky < 3; ++ky) {
                const unsigned short* wp = Wf + (((long)(ky * 3 + kx) * 64 + wave * 16 + m) * 2) * 128 + c * 32 + quad * 8;
                Ah[ky] = *(const bf16x8*)wp;
                Al[ky] = *(const bf16x8*)(wp + 128);
            }
#pragma unroll
            for (int ky = 0; ky < 3; ++ky)
#pragma unroll
                for (int nf = 0; nf < 4; ++nf) {
                    acc[nf] = __builtin_amdgcn_mfma_f32_16x16x32_bf16(Ah[ky], B[nf + ky], acc[nf], 0, 0, 0);
                    acc[nf] = __builtin_amdgcn_mfma_f32_16x16x32_bf16(Al[ky], B[nf + ky], acc[nf], 0, 0, 0);
                }
        }
    }
#pragma unroll
    for (int c = 0; c < 2; ++c) {
#pragma unroll
        for (int kx = 0; kx < 3; ++kx) {
            bf16x8 Bh[6], Bl[6];
#pragma unroll
            for (int r = 0; r < 6; ++r) {
                int base = (r * 18 + kx + m) * 200 + 64 + (c * 2) * 32 + quad * 8;
                Bh[r] = *(const bf16x8*)&sX[base];
                Bl[r] = *(const bf16x8*)&sX[base + 32];
            }
            bf16x8 Ah[3], Al[3];
#pragma unroll
            for (int ky = 0; ky < 3; ++ky) {
                const unsigned short* wp = Wf + (((long)(ky * 3 + kx) * 64 + wave * 16 + m) * 2) * 128 + (2 + c) * 32 + quad * 8;
                Ah[ky] = *(const bf16x8*)wp;
                Al[ky] = *(const bf16x8*)(wp + 128);
            }
#pragma unroll
            for (int ky = 0; ky < 3; ++ky)
#pragma unroll
                for (int nf = 0; nf < 4; ++nf) {
                    acc[nf] = __builtin_amdgcn_mfma_f32_16x16x32_bf16(Ah[ky], Bh[nf + ky], acc[nf], 0, 0, 0);
                    acc[nf] = __builtin_amdgcn_mfma_f32_16x16x32_bf16(Al[ky], Bh[nf + ky], acc[nf], 0, 0, 0);
                    acc[nf] = __builtin_amdgcn_mfma_f32_16x16x32_bf16(Ah[ky], Bl[nf + ky], acc[nf], 0, 0, 0);
                }
        }
    }

    int ocl = wave * 16 + quad * 4;
    float b0 = bias[ocl], b1 = bias[ocl + 1], b2 = bias[ocl + 2], b3 = bias[ocl + 3];
#pragma unroll
    for (int nf = 0; nf < 4; ++nf) {
        int p = (tY * 4 + nf) * WW + tX * 16 + m;
        ushort4 hv;
        hv.x = bhi(acc[nf].x + b0); hv.y = bhi(acc[nf].y + b1);
        hv.z = bhi(acc[nf].z + b2); hv.w = bhi(acc[nf].w + b3);
        *(ushort4*)&comb[((long)z * HW + p) * 64 + ocl] = hv;
    }
}

// ---------------------------------------------------------------------------
// om conv: comb (single, IC=64) -> om fp32 NCHW (216 of 256 oc).
// ---------------------------------------------------------------------------
__global__ __launch_bounds__(512) void om_conv(
    const unsigned short* __restrict__ comb,
    const unsigned short* __restrict__ Wo,   // [9][256][2][64]
    const float* __restrict__ bias,
    float* __restrict__ om)                  // [z][216][HW]
{
    __shared__ unsigned short sX[108 * 72];
    const int tid = threadIdx.x;
    const int wave = tid >> 6, lane = tid & 63;
    const int m = lane & 15, quad = lane >> 4;
    const int tY = blockIdx.x / 6, tX = blockIdx.x % 6;
    const int z = blockIdx.z;
    const unsigned short* cbp = comb + (long)z * HW * 64;

    for (int i = tid; i < 108 * 8; i += 512) {
        int cell = i >> 3, v = i & 7;
        int row = cell / 18, col = cell - row * 18;
        int gy = tY * 4 + row - 1, gx = tX * 16 + col - 1;
        bf16x8 val = (bf16x8){0,0,0,0,0,0,0,0};
        if (gy >= 0 && gy < HH && gx >= 0 && gx < WW)
            val = *(const bf16x8*)(cbp + (long)(gy * WW + gx) * 64 + v * 8);
        *(bf16x8*)&sX[cell * 72 + v * 8] = val;
    }
    __syncthreads();

    f32x4 acc[2][4];
#pragma unroll
    for (int mi = 0; mi < 2; ++mi)
#pragma unroll
        for (int nf = 0; nf < 4; ++nf) acc[mi][nf] = (f32x4){0.f, 0.f, 0.f, 0.f};

#pragma unroll
    for (int c = 0; c < 2; ++c) {
#pragma unroll
        for (int kx = 0; kx < 3; ++kx) {
            bf16x8 B[6];
#pragma unroll
            for (int r = 0; r < 6; ++r)
                B[r] = *(const bf16x8*)&sX[(r * 18 + kx + m) * 72 + c * 32 + quad * 8];
            bf16x8 Ah[3][2], Al[3][2];
#pragma unroll
            for (int ky = 0; ky < 3; ++ky)
#pragma unroll
                for (int mi = 0; mi < 2; ++mi) {
                    const unsigned short* wp = Wo + (((long)(ky * 3 + kx) * 256 + (wave * 2 + mi) * 16 + m) * 2) * 64 + c * 32 + quad * 8;
                    Ah[ky][mi] = *(const bf16x8*)wp;
                    Al[ky][mi] = *(const bf16x8*)(wp + 64);
                }
#pragma unroll
            for (int ky = 0; ky < 3; ++ky)
#pragma unroll
                for (int mi = 0; mi < 2; ++mi)
#pragma unroll
                    for (int nf = 0; nf < 4; ++nf) {
                        acc[mi][nf] = __builtin_amdgcn_mfma_f32_16x16x32_bf16(Ah[ky][mi], B[nf + ky], acc[mi][nf], 0, 0, 0);
                        acc[mi][nf] = __builtin_amdgcn_mfma_f32_16x16x32_bf16(Al[ky][mi], B[nf + ky], acc[mi][nf], 0, 0, 0);
                    }
        }
    }

#pragma unroll
    for (int mi = 0; mi < 2; ++mi) {
#pragma unroll
        for (int reg = 0; reg < 4; ++reg) {
            int oc = (wave * 2 + mi) * 16 + quad * 4 + reg;
            if (oc < 216) {
                float bv = bias[oc];
#pragma unroll
                for (int nf = 0; nf < 4; ++nf) {
                    int p = (tY * 4 + nf) * WW + tX * 16 + m;
                    om[((long)z * 216 + oc) * HW + p] = acc[mi][nf][reg] + bv;
                }
            }
        }
    }
}

// ---------------------------------------------------------------------------
// FUSED deformable-sampling + 1x1 DCN einsum (512 threads, XCD-swizzled,
// DOUBLE-BUFFERED: one barrier per tap; gathers for tap k+1 issued before
// tap k's MFMA; om for tap k+2 loaded one iteration ahead). All float
// expressions identical to the original sampler -> bitwise-same output.
// ---------------------------------------------------------------------------
__global__ __launch_bounds__(512) void conv1x1_fused(
    const unsigned short* __restrict__ hbuf,  // [4][p][128] hl
    const float* __restrict__ om,             // [4][216][HW]
    const unsigned short* __restrict__ w1,    // [128][2][576] k-major
    const float* __restrict__ bias,
    unsigned short* __restrict__ fused)       // [z][p][256] hl
{
    __shared__ unsigned short sX[2][64 * 76];
    const int tid  = threadIdx.x;
    const int wave = tid >> 6, lane = tid & 63;
    const int m = lane & 15, quad = lane >> 4;

    // bijective XCD swizzle over 576 = 8 XCDs x 72 chunks
    const int bid = blockIdx.x;
    const int work = (bid & 7) * 72 + (bid >> 3);
    const int zz = work / 144;
    const int pt = work - zz * 144;

    const float* omb = om + (long)zz * 216 * HW;
    const unsigned short* hz = hbuf + (long)zz * HW * 128;

    const int g0 = tid >> 6;        // 0..7  (channel group; = wave)
    const int cellb = tid & 63;     // 0..63 (pixel within tile)
    const int p = pt * 64 + cellb;
    const int y = p / WW, x = p - y * WW;
    const unsigned short* hzb = hz + g0 * 8;

    // pipeline state
    bf16x8 G0, G1, G2, G3, G4, G5, G6, G7;   // 8 corner gathers in flight
    float wy, wx;
    bool v00, v01, v10, v11;

    auto loadOmTap = [&](int cb, float& oy, float& ox, float& mr) {
        oy = omb[(g0 * 18 + cb * 2) * HW + p];
        ox = omb[(g0 * 18 + cb * 2 + 1) * HW + p];
        mr = omb[(144 + g0 * 9 + cb) * HW + p];
    };

    auto issueGathers = [&](int cb, float oy, float ox) {
        int ky = cb / 3, kx = cb - ky * 3;
        float py = (float)(y + ky - 1) + oy;
        float px = (float)(x + kx - 1) + ox;
        float y0f = floorf(py), x0f = floorf(px);
        wy = py - y0f; wx = px - x0f;
        int y0 = (int)y0f, x0 = (int)x0f;
        int y1 = y0 + 1, x1 = x0 + 1;
        bool vy0 = (y0 >= 0) && (y0 < HH), vy1 = (y1 >= 0) && (y1 < HH);
        bool vx0 = (x0 >= 0) && (x0 < WW), vx1 = (x1 >= 0) && (x1 < WW);
        v00 = vy0 && vx0; v01 = vy0 && vx1; v10 = vy1 && vx0; v11 = vy1 && vx1;
        int cy0 = min(max(y0, 0), HH - 1), cy1 = min(max(y1, 0), HH - 1);
        int cx0 = min(max(x0, 0), WW - 1), cx1 = min(max(x1, 0), WW - 1);
        long i00 = cy0 * WW + cx0, i01 = cy0 * WW + cx1;
        long i10 = cy1 * WW + cx0, i11 = cy1 * WW + cx1;
        G0 = *(const bf16x8*)(hzb + i00 * 128);
        G1 = *(const bf16x8*)(hzb + i00 * 128 + 64);
        G2 = *(const bf16x8*)(hzb + i01 * 128);
        G3 = *(const bf16x8*)(hzb + i01 * 128 + 64);
        G4 = *(const bf16x8*)(hzb + i10 * 128);
        G5 = *(const bf16x8*)(hzb + i10 * 128 + 64);
        G6 = *(const bf16x8*)(hzb + i11 * 128);
        G7 = *(const bf16x8*)(hzb + i11 * 128 + 64);
    };

    auto combine = [&](float mr) -> bf16x8 {
        float mm = sigf(mr);
        float w00 = (1.f - wy) * (1.f - wx) * (v00 ? mm : 0.f);
        float w01 = (1.f - wy) * wx         * (v01 ? mm : 0.f);
        float w10 = wy * (1.f - wx)         * (v10 ? mm : 0.f);
        float w11 = wy * wx                 * (v11 ? mm : 0.f);
        bf16x8 outv;
#pragma unroll
        for (int cg = 0; cg < 8; ++cg) {
            float c00 = b2f((unsigned short)G0[cg]) + b2f((unsigned short)G1[cg]);
            float c01 = b2f((unsigned short)G2[cg]) + b2f((unsigned short)G3[cg]);
            float c10 = b2f((unsigned short)G4[cg]) + b2f((unsigned short)G5[cg]);
            float c11 = b2f((unsigned short)G6[cg]) + b2f((unsigned short)G7[cg]);
            float v = w00 * c00 + w01 * c01 + w10 * c10 + w11 * c11;
            outv[cg] = (short)bhi(v);
        }
        return outv;
    };

    f32x4 acc[4];
#pragma unroll
    for (int nf = 0; nf < 4; ++nf) acc[nf] = (f32x4){0.f, 0.f, 0.f, 0.f};

    // prologue: sample tap 0; preload om for tap 1
    float oyN, oxN, mrN;
    bf16x8 R;
    {
        float oy0, ox0, mr0;
        loadOmTap(0, oy0, ox0, mr0);
        issueGathers(0, oy0, ox0);
        loadOmTap(1, oyN, oxN, mrN);
        R = combine(mr0);
    }

    for (int cb = 0; cb < 9; ++cb) {
        *(bf16x8*)&sX[cb & 1][cellb * 76 + g0 * 8] = R;
        __syncthreads();

        float mrCur = 0.f;
        if (cb + 1 < 9) {
            issueGathers(cb + 1, oyN, oxN);       // loads in flight across MFMA
            mrCur = mrN;
            if (cb + 2 < 9) loadOmTap(cb + 2, oyN, oxN, mrN);
        }

        bf16x8 Bv[2][4];
#pragma unroll
        for (int sub = 0; sub < 2; ++sub)
#pragma unroll
            for (int nf = 0; nf < 4; ++nf)
                Bv[sub][nf] = *(const bf16x8*)&sX[cb & 1][(nf * 16 + m) * 76 + sub * 32 + quad * 8];
        bf16x8 Ah[2], Al[2];
#pragma unroll
        for (int sub = 0; sub < 2; ++sub) {
            const unsigned short* wp = w1 + ((long)(wave * 16 + m) * 2) * 576
                                       + cb * 64 + sub * 32 + quad * 8;
            Ah[sub] = *(const bf16x8*)wp;
            Al[sub] = *(const bf16x8*)(wp + 576);
        }
#pragma unroll
        for (int sub = 0; sub < 2; ++sub)
#pragma unroll
            for (int nf = 0; nf < 4; ++nf) {
                acc[nf] = __builtin_amdgcn_mfma_f32_16x16x32_bf16(
                    Ah[sub], Bv[sub][nf], acc[nf], 0, 0, 0);
                acc[nf] = __builtin_amdgcn_mfma_f32_16x16x32_bf16(
                    Al[sub], Bv[sub][nf], acc[nf], 0, 0, 0);
            }

        if (cb + 1 < 9) R = combine(mrCur);
    }

    {
        int ocl = wave * 16 + quad * 4;
        float b0 = bias[ocl], b1 = bias[ocl + 1], b2 = bias[ocl + 2], b3 = bias[ocl + 3];
#pragma unroll
        for (int nf = 0; nf < 4; ++nf) {
            int pp = pt * 64 + nf * 16 + m;
            float v0 = fmaxf(acc[nf].x + b0, 0.f);
            float v1 = fmaxf(acc[nf].y + b1, 0.f);
            float v2 = fmaxf(acc[nf].z + b2, 0.f);
            float v3 = fmaxf(acc[nf].w + b3, 0.f);
            unsigned short* op = fused + ((long)zz * HW + pp) * 256 + ocl;
            ushort4 hv, lv;
            hv.x = bhi(v0); hv.y = bhi(v1); hv.z = bhi(v2); hv.w = bhi(v3);
            lv.x = blo(v0); lv.y = blo(v1); lv.z = blo(v2); lv.w = blo(v3);
            *(ushort4*)op = hv;
            *(ushort4*)(op + 128) = lv;
        }
    }
}

// ---------------------------------------------------------------------------
// Big conv (IC=128 hl, OC=256) FUSED with LSTM gates.
// 16-wave blocks (1024 thr), 6x16 tile, 384 blocks (the proven-fastest block
// count). Each wave owns ONE oc-16 block (wave = oc>>4): acc[6] = 24 VGPR
// (no spill), 6 weight loads per (c,kx) feed 54 MFMAs. R8-measured: 102us.
// Best-known config — unchanged.
// ---------------------------------------------------------------------------
__global__ __launch_bounds__(1024) void big_conv_gates(
    const unsigned short* __restrict__ fusedb,  // [z][p][256] hl
    const unsigned short* __restrict__ Wc,      // [9][256][2][128]
    const float* __restrict__ bias,
    float* __restrict__ cst,                    // [z][p][64] fp32
    unsigned short* __restrict__ hbuf,          // [z][p][128] hl
    unsigned short* __restrict__ hseq,          // [(t*2+b)][p][128]
    int t0, int t1)
{
    // 39168 ush = 78336 B. Staging: 144 cells x 264 = 38016 ush (76032 B).
    // Gates: 3 regions x 96 px x 68 floats = 19584 floats = 78336 B.
    __shared__ unsigned short sX[39168];
    const int tid = threadIdx.x;
    const int wave = tid >> 6, lane = tid & 63;
    const int m = lane & 15, quad = lane >> 4;
    const int tY = blockIdx.x / 6, tX = blockIdx.x % 6;   // tY 0..15
    const int z = blockIdx.z;

    const unsigned short* fb = fusedb + (long)z * HW * 256;

    for (int i = tid; i < 144 * 32; i += 1024) {
        int cell = i >> 5, v = i & 31;
        int row = cell / 18, col = cell - row * 18;
        int gy = tY * 6 + row - 1, gx = tX * 16 + col - 1;
        int pl = v >> 4, c = (v & 15) >> 2, g = v & 3;
        bf16x8 val = (bf16x8){0,0,0,0,0,0,0,0};
        if (gy >= 0 && gy < HH && gx >= 0 && gx < WW)
            val = *(const bf16x8*)(fb + (long)(gy * WW + gx) * 256 + pl * 128 + c * 32 + g * 8);
        *(bf16x8*)&sX[cell * 264 + (c * 2 + pl) * 32 + g * 8] = val;
    }
    __syncthreads();

    f32x4 acc[6];
#pragma unroll
    for (int nf = 0; nf < 6; ++nf) acc[nf] = (f32x4){0.f, 0.f, 0.f, 0.f};

#pragma unroll
    for (int c = 0; c < 4; ++c) {
#pragma unroll
        for (int kx = 0; kx < 3; ++kx) {
            bf16x8 Ah[3], Al[3];
#pragma unroll
            for (int ky = 0; ky < 3; ++ky) {
                const unsigned short* wp = Wc + (((long)(ky * 3 + kx) * 256 + wave * 16 + m) * 2) * 128 + c * 32 + quad * 8;
                Ah[ky] = *(const bf16x8*)wp;
                Al[ky] = *(const bf16x8*)(wp + 128);
            }
            bf16x8 Bh[8], Bl[8];
#pragma unroll
            for (int r = 0; r < 3; ++r) {
                int base = (r * 18 + kx + m) * 264 + (c * 2) * 32 + quad * 8;
                Bh[r] = *(const bf16x8*)&sX[base];
                Bl[r] = *(const bf16x8*)&sX[base + 32];
            }
            // nf-outer, rolling 3-row B window: row nf+2 loaded at nf>0, rows
            // < nf dead -> ~6 live B regs. Per-acc (ky, term) order unchanged.
#pragma unroll
            for (int nf = 0; nf < 6; ++nf) {
                if (nf) {
                    int r = nf + 2;
                    int base = (r * 18 + kx + m) * 264 + (c * 2) * 32 + quad * 8;
                    Bh[r] = *(const bf16x8*)&sX[base];
                    Bl[r] = *(const bf16x8*)&sX[base + 32];
                }
#pragma unroll
                for (int ky = 0; ky < 3; ++ky) {
                    acc[nf] = __builtin_amdgcn_mfma_f32_16x16x32_bf16(Ah[ky], Bh[nf + ky], acc[nf], 0, 0, 0);
                    acc[nf] = __builtin_amdgcn_mfma_f32_16x16x32_bf16(Al[ky], Bh[nf + ky], acc[nf], 0, 0, 0);
                    acc[nf] = __builtin_amdgcn_mfma_f32_16x16x32_bf16(Ah[ky], Bl[nf + ky], acc[nf], 0, 0, 0);
                }
            }
        }
    }

    // ---- gates epilogue ----
    // wave w owns oc block w: ci = w0-3, cf = w4-7, co = w8-11, cg = w12-15.
    float* sG = (float*)sX;
    float ba[4];
    {
        int oc0 = wave * 16 + quad * 4;
#pragma unroll
        for (int r = 0; r < 4; ++r) ba[r] = bias[oc0 + r];
    }
    __syncthreads();
    if (wave >= 4) {
        int reg = (wave >> 2) - 1;            // 0=cf, 1=co, 2=cg
        int chb = (wave & 3) * 16 + quad * 4;
#pragma unroll
        for (int nf = 0; nf < 6; ++nf) {
            int px = nf * 16 + m;
            float* f = &sG[reg * 96 * 68 + (long)px * 68 + chb];
#pragma unroll
            for (int r = 0; r < 4; ++r) f[r] = acc[nf][r] + ba[r];
        }
    }
    __syncthreads();
    if (wave < 4) {
        int t = (z < 2) ? t0 : t1;
        int b = z & 1, dir = z >> 1;
        int chb = wave * 16 + quad * 4;
        unsigned short* hsq = hseq + ((long)(t * 2 + b) * HW) * 128 + dir * 64;
#pragma unroll
        for (int nf = 0; nf < 6; ++nf) {
            int px = nf * 16 + m;
            int p = (tY * 6 + nf) * WW + tX * 16 + m;
            float4 cf4 = *(float4*)&sG[0 * 96 * 68 + (long)px * 68 + chb];
            float4 co4 = *(float4*)&sG[1 * 96 * 68 + (long)px * 68 + chb];
            float4 cg4 = *(float4*)&sG[2 * 96 * 68 + (long)px * 68 + chb];
            float* cp = &cst[((long)z * HW + p) * 64 + chb];
            float4 cold = *(float4*)cp;
            float cfv[4] = {cf4.x, cf4.y, cf4.z, cf4.w};
            float cov[4] = {co4.x, co4.y, co4.z, co4.w};
            float cgv[4] = {cg4.x, cg4.y, cg4.z, cg4.w};
            float coldv[4] = {cold.x, cold.y, cold.z, cold.w};
            float c2v[4], h2v[4];
#pragma unroll
            for (int r = 0; r < 4; ++r) {
                float civ = acc[nf][r] + ba[r];
                float c2 = sigf(cfv[r]) * coldv[r] + sigf(civ) * tanhf(cgv[r]);
                float h2 = sigf(cov[r]) * tanhf(c2);
                c2v[r] = c2; h2v[r] = h2;
            }
            *(float4*)cp = (float4){c2v[0], c2v[1], c2v[2], c2v[3]};
            unsigned short* hp = hbuf + ((long)z * HW + p) * 128 + chb;
            ushort4 hv = {bhi(h2v[0]), bhi(h2v[1]), bhi(h2v[2]), bhi(h2v[3])};
            ushort4 lv = {blo(h2v[0]), blo(h2v[1]), blo(h2v[2]), blo(h2v[3])};
            *(ushort4*)hp = hv;
            *(ushort4*)(hp + 64) = lv;
            *(ushort4*)&hsq[(long)p * 128 + chb] = hv;
        }
    }
}

// ---------------------------------------------------------------------------
// cat conv: hseq (single-plane, IC=128) -> out fp32 NCHW with (t,b) permute.
// ---------------------------------------------------------------------------
__global__ __launch_bounds__(256) void cat_conv(
    const unsigned short* __restrict__ hseq,
    const unsigned short* __restrict__ Wk,     // [9][64][2][128]
    const float* __restrict__ bias,
    float* __restrict__ out)
{
    __shared__ unsigned short sX[108 * 136];
    const int tid = threadIdx.x;
    const int wave = tid >> 6, lane = tid & 63;
    const int m = lane & 15, quad = lane >> 4;
    const int tY = blockIdx.x / 6, tX = blockIdx.x % 6;
    const int img = blockIdx.z;
    const unsigned short* hp = hseq + (long)img * HW * 128;

    for (int i = tid; i < 108 * 16; i += 256) {
        int cell = i >> 4, v = i & 15;
        int row = cell / 18, col = cell - row * 18;
        int gy = tY * 4 + row - 1, gx = tX * 16 + col - 1;
        bf16x8 val = (bf16x8){0,0,0,0,0,0,0,0};
        if (gy >= 0 && gy < HH && gx >= 0 && gx < WW)
            val = *(const bf16x8*)(hp + (long)(gy * WW + gx) * 128 + v * 8);
        *(bf16x8*)&sX[cell * 136 + v * 8] = val;
    }
    __syncthreads();

    f32x4 acc[4];
#pragma unroll
    for (int nf = 0; nf < 4; ++nf) acc[nf] = (f32x4){0.f, 0.f, 0.f, 0.f};

#pragma unroll
    for (int c = 0; c < 4; ++c) {
#pragma unroll
        for (int kx = 0; kx < 3; ++kx) {
            bf16x8 B[6];
#pragma unroll
            for (int r = 0; r < 6; ++r)
                B[r] = *(const bf16x8*)&sX[(r * 18 + kx + m) * 136 + c * 32 + quad * 8];
            bf16x8 Ah[3], Al[3];
#pragma unroll
            for (int ky = 0; ky < 3; ++ky) {
                const unsigned short* wp = Wk + (((long)(ky * 3 + kx) * 64 + wave * 16 + m) * 2) * 128 + c * 32 + quad * 8;
                Ah[ky] = *(const bf16x8*)wp;
                Al[ky] = *(const bf16x8*)(wp + 128);
            }
#pragma unroll
            for (int ky = 0; ky < 3; ++ky)
#pragma unroll
                for (int nf = 0; nf < 4; ++nf) {
                    acc[nf] = __builtin_amdgcn_mfma_f32_16x16x32_bf16(Ah[ky], B[nf + ky], acc[nf], 0, 0, 0);
                    acc[nf] = __builtin_amdgcn_mfma_f32_16x16x32_bf16(Al[ky], B[nf + ky], acc[nf], 0, 0, 0);
                }
        }
    }

    int t = img >> 1, b = img & 1;
    long imgOut = (long)(b * TT + t) * 64 * HW;
#pragma unroll
    for (int reg = 0; reg < 4; ++reg) {
        int oc = wave * 16 + quad * 4 + reg;
        float bv = bias[oc];
#pragma unroll
        for (int nf = 0; nf < 4; ++nf) {
            int p = (tY * 4 + nf) * WW + tX * 16 + m;
            out[imgOut + (long)oc * HW + p] = acc[nf][reg] + bv;
        }
    }
}

// ---------------------------------------------------------------------------
extern "C" void kernel_launch(void* const* d_in, const int* in_sizes, int n_in,
                              void* d_out, int out_size, void* d_ws, size_t ws_size,
                              hipStream_t stream)
{
    const float* input  = (const float*)d_in[0];
    const float* fuse_w = (const float*)d_in[1];
    const float* fuse_b = (const float*)d_in[2];
    const float* om_w   = (const float*)d_in[3];
    const float* om_b   = (const float*)d_in[4];
    const float* dcn_w  = (const float*)d_in[5];
    const float* dcn_b  = (const float*)d_in[6];
    const float* conv_w = (const float*)d_in[7];
    const float* conv_b = (const float*)d_in[8];
    const float* cat_w  = (const float*)d_in[9];
    const float* cat_b  = (const float*)d_in[10];
    float* out = (float*)d_out;

    char* w = (char*)d_ws;
    size_t off = 0;
    auto alloc = [&](size_t bytes) { void* p = w + off; off += (bytes + 255) & ~(size_t)255; return p; };

    unsigned short* xbf    = (unsigned short*)alloc(10L * HW * 64 * 2);
    unsigned short* hbuf   = (unsigned short*)alloc(4L * HW * 128 * 2);
    unsigned short* comb   = (unsigned short*)alloc(4L * HW * 64 * 2);
    float*          omb    = (float*)alloc(4L * 216 * HW * 4);
    unsigned short* fusedb = (unsigned short*)alloc(4L * HW * 256 * 2);
    float*          cbufs  = (float*)alloc(4L * HW * 64 * 4);
    unsigned short* hseqb  = (unsigned short*)alloc(10L * HW * 128 * 2);
    unsigned short* Wf = (unsigned short*)alloc(9L * 64 * 2 * 128 * 2);
    unsigned short* Wo = (unsigned short*)alloc(9L * 256 * 2 * 64 * 2);
    unsigned short* Wc = (unsigned short*)alloc(9L * 256 * 2 * 128 * 2);
    unsigned short* Wk = (unsigned short*)alloc(9L * 64 * 2 * 128 * 2);
    unsigned short* W1 = (unsigned short*)alloc(128L * 2 * 576 * 2);

    dim3 blk(256);
    wexp3_kernel<<<dim3(288), blk, 0, stream>>>(fuse_w, Wf, 64, 64, 128);
    wexp3_kernel<<<dim3(576), blk, 0, stream>>>(om_w, Wo, 216, 256, 64);
    wexp3_kernel<<<dim3(1152), blk, 0, stream>>>(conv_w, Wc, 256, 256, 128);
    wexp3_kernel<<<dim3(288), blk, 0, stream>>>(cat_w, Wk, 64, 64, 128);
    wexp1_kernel<<<dim3(288), blk, 0, stream>>>(dcn_w, W1);
    xprep_kernel<<<dim3(23040), blk, 0, stream>>>(input, xbf);

    hipMemsetAsync(hbuf, 0, 4L * HW * 128 * 2, stream);
    hipMemsetAsync(cbufs, 0, 4L * HW * 64 * 4, stream);

    for (int s = 0; s < TT; ++s) {
        int t0 = s, t1 = TT - 1 - s;
        fuse_conv<<<dim3(144, 1, 4), blk, 0, stream>>>(
            xbf, hbuf, Wf, fuse_b, comb, t0, t1);
        om_conv<<<dim3(144, 1, 4), dim3(512), 0, stream>>>(
            comb, Wo, om_b, omb);
        conv1x1_fused<<<dim3(576), dim3(512), 0, stream>>>(
            hbuf, omb, W1, dcn_b, fusedb);
        big_conv_gates<<<dim3(96, 1, 4), dim3(1024), 0, stream>>>(
            fusedb, Wc, conv_b, cbufs, hbuf, hseqb, t0, t1);
    }
    cat_conv<<<dim3(144, 1, 10), blk, 0, stream>>>(hseqb, Wk, cat_b, out);
}

// Round 12
// 1494.020 us; speedup vs baseline: 1.2619x; 1.0640x over previous
//
#include <hip/hip_runtime.h>
#include <math.h>

#define HH 96
#define WW 96
#define HW 9216
#define TT 5

typedef __attribute__((ext_vector_type(8))) short bf16x8;
typedef __attribute__((ext_vector_type(4))) float f32x4;

__device__ __forceinline__ float sigf(float x) { return 1.0f / (1.0f + expf(-x)); }
__device__ __forceinline__ unsigned short bhi(float x) {
    return (unsigned short)(__float_as_uint(x) >> 16);
}
__device__ __forceinline__ unsigned short blo(float x) {
    float h = __uint_as_float(__float_as_uint(x) & 0xffff0000u);
    return (unsigned short)(__float_as_uint(x - h) >> 16);
}
__device__ __forceinline__ float b2f(unsigned short u) {
    return __uint_as_float(((unsigned)u) << 16);
}

// ---------------------------------------------------------------------------
// Weight expansion: src [OC][IC][9] fp32 -> dst [9][OCP][2][IC] bf16 hi/lo.
// ---------------------------------------------------------------------------
__global__ __launch_bounds__(256) void wexp3_kernel(
    const float* __restrict__ w, unsigned short* __restrict__ dst,
    int OC, int OCP, int IC)
{
    long i = (long)blockIdx.x * 256 + threadIdx.x;
    int ic = (int)(i % IC);
    long r = i / IC;
    int oc = (int)(r % OCP);
    int tap = (int)(r / OCP);
    float v = (oc < OC) ? w[((long)oc * IC + ic) * 9 + tap] : 0.f;
    long base = (((long)tap * OCP + oc) * 2) * IC + ic;
    dst[base] = bhi(v);
    dst[base + IC] = blo(v);
}

// dcn_w [128][576] (576 = c*9+k) -> [128][2][576] with K re-ordered k-major:
// dst K-slot (k*64 + c) = src (c*9 + k).
__global__ __launch_bounds__(256) void wexp1_kernel(
    const float* __restrict__ w, unsigned short* __restrict__ dst)
{
    int i = blockIdx.x * 256 + threadIdx.x;   // over 128*576 dst slots
    int slot = i % 576;                        // k*64 + c
    int oc = i / 576;
    int k = slot >> 6, c = slot & 63;
    float v = w[(long)oc * 576 + c * 9 + k];
    dst[((long)oc * 2) * 576 + slot] = bhi(v);
    dst[((long)oc * 2 + 1) * 576 + slot] = blo(v);
}

// input [b][t][64][HW] fp32 -> xbf [(t*2+b)][p][64] bf16
__global__ __launch_bounds__(256) void xprep_kernel(
    const float* __restrict__ input, unsigned short* __restrict__ xbf)
{
    long i = (long)blockIdx.x * 256 + threadIdx.x;
    int p = (int)(i % HW);
    long r = i / HW;
    int c = (int)(r % 64);
    long bt = r / 64;
    int b = (int)(bt / TT), t = (int)(bt % TT);
    float v = input[i];
    xbf[(((long)(t * 2 + b) * HW) + p) * 64 + c] = bhi(v);
}

// ===========================================================================
// R11: conv1x1 pipelining was null (gather path is L1-line-transaction-bound:
// lanes stride 256B so every wave-gather = 64 lines) and cost absmax margin
// -> conv1x1 REVERTED to R10 exact-numerics form. R12 target: om_conv (~39us,
// 13x its MFMA floor, same weight-stream disease big had pre-R8). Clone the
// R8 recipe: 6x16 tile, 16-wave block, wave-owns-one-oc16, rolling-3 B
// window. 576->384 blocks, Wo stream 340->221MB, MFMA:load 4:1 -> 8:1.
// ===========================================================================

// ---------------------------------------------------------------------------
// Fuse conv: x (single, ic 0..63) + h (hl, ic 64..127) -> comb bf16 NHWC.
// ---------------------------------------------------------------------------
__global__ __launch_bounds__(256) void fuse_conv(
    const unsigned short* __restrict__ xbf,
    const unsigned short* __restrict__ hbuf,
    const unsigned short* __restrict__ Wf,   // [9][64][2][128]
    const float* __restrict__ bias,
    unsigned short* __restrict__ comb,
    int t0, int t1)
{
    __shared__ unsigned short sX[108 * 200];
    const int tid = threadIdx.x;
    const int wave = tid >> 6, lane = tid & 63;
    const int m = lane & 15, quad = lane >> 4;
    const int tY = blockIdx.x / 6, tX = blockIdx.x % 6;
    const int z = blockIdx.z;
    const int imgX = ((z < 2) ? t0 : t1) * 2 + (z & 1);

    const unsigned short* xb = xbf + (long)imgX * HW * 64;
    const unsigned short* hb = hbuf + (long)z * HW * 128;

    for (int i = tid; i < 108 * 24; i += 256) {
        int cell = i / 24, v = i - cell * 24;
        int row = cell / 18, col = cell - row * 18;
        int gy = tY * 4 + row - 1, gx = tX * 16 + col - 1;
        bool ok = (gy >= 0 && gy < HH && gx >= 0 && gx < WW);
        int p = gy * WW + gx;
        bf16x8 val = (bf16x8){0,0,0,0,0,0,0,0};
        int dst;
        if (v < 8) {
            if (ok) val = *(const bf16x8*)(xb + (long)p * 64 + v * 8);
            dst = cell * 200 + v * 8;
        } else {
            int v2 = v - 8;
            int pl = v2 >> 3, c = (v2 & 7) >> 2, g = v2 & 3;
            if (ok) val = *(const bf16x8*)(hb + (long)p * 128 + pl * 64 + c * 32 + g * 8);
            dst = cell * 200 + 64 + (c * 2 + pl) * 32 + g * 8;
        }
        *(bf16x8*)&sX[dst] = val;
    }
    __syncthreads();

    f32x4 acc[4];
#pragma unroll
    for (int nf = 0; nf < 4; ++nf) acc[nf] = (f32x4){0.f, 0.f, 0.f, 0.f};

#pragma unroll
    for (int c = 0; c < 2; ++c) {
#pragma unroll
        for (int kx = 0; kx < 3; ++kx) {
            bf16x8 B[6];
#pragma unroll
            for (int r = 0; r < 6; ++r)
                B[r] = *(const bf16x8*)&sX[(r * 18 + kx + m) * 200 + c * 32 + quad * 8];
            bf16x8 Ah[3], Al[3];
#pragma unroll
            for (int ky = 0; ky < 3; ++ky) {
                const unsigned short* wp = Wf + (((long)(ky * 3 + kx) * 64 + wave * 16 + m) * 2) * 128 + c * 32 + quad * 8;
                Ah[ky] = *(const bf16x8*)wp;
                Al[ky] = *(const bf16x8*)(wp + 128);
            }
#pragma unroll
            for (int ky = 0; ky < 3; ++ky)
#pragma unroll
                for (int nf = 0; nf < 4; ++nf) {
                    acc[nf] = __builtin_amdgcn_mfma_f32_16x16x32_bf16(Ah[ky], B[nf + ky], acc[nf], 0, 0, 0);
                    acc[nf] = __builtin_amdgcn_mfma_f32_16x16x32_bf16(Al[ky], B[nf + ky], acc[nf], 0, 0, 0);
                }
        }
    }
#pragma unroll
    for (int c = 0; c < 2; ++c) {
#pragma unroll
        for (int kx = 0; kx < 3; ++kx) {
            bf16x8 Bh[6], Bl[6];
#pragma unroll
            for (int r = 0; r < 6; ++r) {
                int base = (r * 18 + kx + m) * 200 + 64 + (c * 2) * 32 + quad * 8;
                Bh[r] = *(const bf16x8*)&sX[base];
                Bl[r] = *(const bf16x8*)&sX[base + 32];
            }
            bf16x8 Ah[3], Al[3];
#pragma unroll
            for (int ky = 0; ky < 3; ++ky) {
                const unsigned short* wp = Wf + (((long)(ky * 3 + kx) * 64 + wave * 16 + m) * 2) * 128 + (2 + c) * 32 + quad * 8;
                Ah[ky] = *(const bf16x8*)wp;
                Al[ky] = *(const bf16x8*)(wp + 128);
            }
#pragma unroll
            for (int ky = 0; ky < 3; ++ky)
#pragma unroll
                for (int nf = 0; nf < 4; ++nf) {
                    acc[nf] = __builtin_amdgcn_mfma_f32_16x16x32_bf16(Ah[ky], Bh[nf + ky], acc[nf], 0, 0, 0);
                    acc[nf] = __builtin_amdgcn_mfma_f32_16x16x32_bf16(Al[ky], Bh[nf + ky], acc[nf], 0, 0, 0);
                    acc[nf] = __builtin_amdgcn_mfma_f32_16x16x32_bf16(Ah[ky], Bl[nf + ky], acc[nf], 0, 0, 0);
                }
        }
    }

    int ocl = wave * 16 + quad * 4;
    float b0 = bias[ocl], b1 = bias[ocl + 1], b2 = bias[ocl + 2], b3 = bias[ocl + 3];
#pragma unroll
    for (int nf = 0; nf < 4; ++nf) {
        int p = (tY * 4 + nf) * WW + tX * 16 + m;
        ushort4 hv;
        hv.x = bhi(acc[nf].x + b0); hv.y = bhi(acc[nf].y + b1);
        hv.z = bhi(acc[nf].z + b2); hv.w = bhi(acc[nf].w + b3);
        *(ushort4*)&comb[((long)z * HW + p) * 64 + ocl] = hv;
    }
}

// ---------------------------------------------------------------------------
// om conv: comb (single, IC=64) -> om fp32 NCHW (216 of 256 oc).
// R8-recipe clone: 6x16 tile (halo 8x18=144 cells, LDS 20.7KB), 16-wave
// block; wave w owns oc block w (216 oc -> waves 14,15 retire after the
// staging barrier). acc[6]=24 VGPR, rolling-3 B window, 8:1 MFMA:load.
// Per-acc accumulation order (c, kx, ky, hi->lo) unchanged -> bitwise-same.
// ---------------------------------------------------------------------------
__global__ __launch_bounds__(1024) void om_conv(
    const unsigned short* __restrict__ comb,
    const unsigned short* __restrict__ Wo,   // [9][256][2][64]
    const float* __restrict__ bias,
    float* __restrict__ om)                  // [z][216][HW]
{
    __shared__ unsigned short sX[144 * 72];
    const int tid = threadIdx.x;
    const int wave = tid >> 6, lane = tid & 63;
    const int m = lane & 15, quad = lane >> 4;
    const int tY = blockIdx.x / 6, tX = blockIdx.x % 6;   // tY 0..15
    const int z = blockIdx.z;
    const unsigned short* cbp = comb + (long)z * HW * 64;

    for (int i = tid; i < 144 * 8; i += 1024) {
        int cell = i >> 3, v = i & 7;
        int row = cell / 18, col = cell - row * 18;
        int gy = tY * 6 + row - 1, gx = tX * 16 + col - 1;
        bf16x8 val = (bf16x8){0,0,0,0,0,0,0,0};
        if (gy >= 0 && gy < HH && gx >= 0 && gx < WW)
            val = *(const bf16x8*)(cbp + (long)(gy * WW + gx) * 64 + v * 8);
        *(bf16x8*)&sX[cell * 72 + v * 8] = val;
    }
    __syncthreads();

    if (wave * 16 >= 216) return;   // oc blocks 14,15 are pure padding

    f32x4 acc[6];
#pragma unroll
    for (int nf = 0; nf < 6; ++nf) acc[nf] = (f32x4){0.f, 0.f, 0.f, 0.f};

#pragma unroll
    for (int c = 0; c < 2; ++c) {
#pragma unroll
        for (int kx = 0; kx < 3; ++kx) {
            bf16x8 Ah[3], Al[3];
#pragma unroll
            for (int ky = 0; ky < 3; ++ky) {
                const unsigned short* wp = Wo + (((long)(ky * 3 + kx) * 256 + wave * 16 + m) * 2) * 64 + c * 32 + quad * 8;
                Ah[ky] = *(const bf16x8*)wp;
                Al[ky] = *(const bf16x8*)(wp + 64);
            }
            bf16x8 B[8];
#pragma unroll
            for (int r = 0; r < 3; ++r)
                B[r] = *(const bf16x8*)&sX[(r * 18 + kx + m) * 72 + c * 32 + quad * 8];
#pragma unroll
            for (int nf = 0; nf < 6; ++nf) {
                if (nf) {
                    int r = nf + 2;
                    B[r] = *(const bf16x8*)&sX[(r * 18 + kx + m) * 72 + c * 32 + quad * 8];
                }
#pragma unroll
                for (int ky = 0; ky < 3; ++ky) {
                    acc[nf] = __builtin_amdgcn_mfma_f32_16x16x32_bf16(Ah[ky], B[nf + ky], acc[nf], 0, 0, 0);
                    acc[nf] = __builtin_amdgcn_mfma_f32_16x16x32_bf16(Al[ky], B[nf + ky], acc[nf], 0, 0, 0);
                }
            }
        }
    }

#pragma unroll
    for (int reg = 0; reg < 4; ++reg) {
        int oc = wave * 16 + quad * 4 + reg;
        if (oc < 216) {
            float bv = bias[oc];
#pragma unroll
            for (int nf = 0; nf < 6; ++nf) {
                int p = (tY * 6 + nf) * WW + tX * 16 + m;
                om[((long)z * 216 + oc) * HW + p] = acc[nf][reg] + bv;
            }
        }
    }
}

// ---------------------------------------------------------------------------
// FUSED deformable-sampling + 1x1 DCN einsum (512 threads, XCD-swizzled).
// R10 exact form (absmax 0.00098): sampling expressions identical to the
// original dcn_sample_kernel. Pipelining attempts were perf-null and cost
// numeric margin -> kept simple.
// ---------------------------------------------------------------------------
__global__ __launch_bounds__(512) void conv1x1_fused(
    const unsigned short* __restrict__ hbuf,  // [4][p][128] hl
    const float* __restrict__ om,             // [4][216][HW]
    const unsigned short* __restrict__ w1,    // [128][2][576] k-major
    const float* __restrict__ bias,
    unsigned short* __restrict__ fused)       // [z][p][256] hl
{
    __shared__ unsigned short sX[64 * 76];
    const int tid  = threadIdx.x;
    const int wave = tid >> 6, lane = tid & 63;
    const int m = lane & 15, quad = lane >> 4;

    // bijective XCD swizzle over 576 = 8 XCDs x 72 chunks
    const int bid = blockIdx.x;
    const int work = (bid & 7) * 72 + (bid >> 3);
    const int zz = work / 144;
    const int pt = work - zz * 144;

    const float* omb = om + (long)zz * 216 * HW;
    const unsigned short* hz = hbuf + (long)zz * HW * 128;

    const int g0 = tid >> 6;        // 0..7  (channel group; = wave)
    const int cellb = tid & 63;     // 0..63 (pixel within tile)

    // Bilinear-sample 8 channels (group g0) at pixel p=pt*64+cell, tap cb.
    // Expression-identical to the old dcn_sample_kernel -> bitwise-same bf16.
    auto sample = [&](int cell, int cb) -> bf16x8 {
        int p = pt * 64 + cell;
        int y = p / WW, x = p - y * WW;
        int ky = cb / 3, kx = cb - ky * 3;
        float offy = omb[(g0 * 18 + cb * 2) * HW + p];
        float offx = omb[(g0 * 18 + cb * 2 + 1) * HW + p];
        float mm = sigf(omb[(144 + g0 * 9 + cb) * HW + p]);
        float py = (float)(y + ky - 1) + offy;
        float px = (float)(x + kx - 1) + offx;
        float y0f = floorf(py), x0f = floorf(px);
        float wy = py - y0f, wx = px - x0f;
        int y0 = (int)y0f, x0 = (int)x0f;
        int y1 = y0 + 1, x1 = x0 + 1;
        bool vy0 = (y0 >= 0) && (y0 < HH), vy1 = (y1 >= 0) && (y1 < HH);
        bool vx0 = (x0 >= 0) && (x0 < WW), vx1 = (x1 >= 0) && (x1 < WW);
        int cy0 = min(max(y0, 0), HH - 1), cy1 = min(max(y1, 0), HH - 1);
        int cx0 = min(max(x0, 0), WW - 1), cx1 = min(max(x1, 0), WW - 1);
        long i00 = cy0 * WW + cx0, i01 = cy0 * WW + cx1;
        long i10 = cy1 * WW + cx0, i11 = cy1 * WW + cx1;
        float w00 = (1.f - wy) * (1.f - wx) * ((vy0 && vx0) ? mm : 0.f);
        float w01 = (1.f - wy) * wx         * ((vy0 && vx1) ? mm : 0.f);
        float w10 = wy * (1.f - wx)         * ((vy1 && vx0) ? mm : 0.f);
        float w11 = wy * wx                 * ((vy1 && vx1) ? mm : 0.f);
        const unsigned short* hzb = hz + g0 * 8;
        bf16x8 h00 = *(const bf16x8*)(hzb + i00 * 128);
        bf16x8 l00 = *(const bf16x8*)(hzb + i00 * 128 + 64);
        bf16x8 h01 = *(const bf16x8*)(hzb + i01 * 128);
        bf16x8 l01 = *(const bf16x8*)(hzb + i01 * 128 + 64);
        bf16x8 h10 = *(const bf16x8*)(hzb + i10 * 128);
        bf16x8 l10 = *(const bf16x8*)(hzb + i10 * 128 + 64);
        bf16x8 h11 = *(const bf16x8*)(hzb + i11 * 128);
        bf16x8 l11 = *(const bf16x8*)(hzb + i11 * 128 + 64);
        bf16x8 outv;
#pragma unroll
        for (int cg = 0; cg < 8; ++cg) {
            float v00 = b2f((unsigned short)h00[cg]) + b2f((unsigned short)l00[cg]);
            float v01 = b2f((unsigned short)h01[cg]) + b2f((unsigned short)l01[cg]);
            float v10 = b2f((unsigned short)h10[cg]) + b2f((unsigned short)l10[cg]);
            float v11 = b2f((unsigned short)h11[cg]) + b2f((unsigned short)l11[cg]);
            float v = w00 * v00 + w01 * v01 + w10 * v10 + w11 * v11;
            outv[cg] = (short)bhi(v);
        }
        return outv;
    };

    f32x4 acc[4];
#pragma unroll
    for (int nf = 0; nf < 4; ++nf) acc[nf] = (f32x4){0.f, 0.f, 0.f, 0.f};

    for (int cb = 0; cb < 9; ++cb) {
        if (cb) __syncthreads();
        bf16x8 R0 = sample(cellb, cb);
        *(bf16x8*)&sX[cellb * 76 + g0 * 8] = R0;
        __syncthreads();

        bf16x8 Bv[2][4];
#pragma unroll
        for (int sub = 0; sub < 2; ++sub)
#pragma unroll
            for (int nf = 0; nf < 4; ++nf)
                Bv[sub][nf] = *(const bf16x8*)&sX[(nf * 16 + m) * 76 + sub * 32 + quad * 8];
        bf16x8 Ah[2], Al[2];
#pragma unroll
        for (int sub = 0; sub < 2; ++sub) {
            const unsigned short* wp = w1 + ((long)(wave * 16 + m) * 2) * 576
                                       + cb * 64 + sub * 32 + quad * 8;
            Ah[sub] = *(const bf16x8*)wp;
            Al[sub] = *(const bf16x8*)(wp + 576);
        }
#pragma unroll
        for (int sub = 0; sub < 2; ++sub)
#pragma unroll
            for (int nf = 0; nf < 4; ++nf) {
                acc[nf] = __builtin_amdgcn_mfma_f32_16x16x32_bf16(
                    Ah[sub], Bv[sub][nf], acc[nf], 0, 0, 0);
                acc[nf] = __builtin_amdgcn_mfma_f32_16x16x32_bf16(
                    Al[sub], Bv[sub][nf], acc[nf], 0, 0, 0);
            }
    }

    {
        int ocl = wave * 16 + quad * 4;
        float b0 = bias[ocl], b1 = bias[ocl + 1], b2 = bias[ocl + 2], b3 = bias[ocl + 3];
#pragma unroll
        for (int nf = 0; nf < 4; ++nf) {
            int p = pt * 64 + nf * 16 + m;
            float v0 = fmaxf(acc[nf].x + b0, 0.f);
            float v1 = fmaxf(acc[nf].y + b1, 0.f);
            float v2 = fmaxf(acc[nf].z + b2, 0.f);
            float v3 = fmaxf(acc[nf].w + b3, 0.f);
            unsigned short* op = fused + ((long)zz * HW + p) * 256 + ocl;
            ushort4 hv, lv;
            hv.x = bhi(v0); hv.y = bhi(v1); hv.z = bhi(v2); hv.w = bhi(v3);
            lv.x = blo(v0); lv.y = blo(v1); lv.z = blo(v2); lv.w = blo(v3);
            *(ushort4*)op = hv;
            *(ushort4*)(op + 128) = lv;
        }
    }
}

// ---------------------------------------------------------------------------
// Big conv (IC=128 hl, OC=256) FUSED with LSTM gates.
// 16-wave blocks (1024 thr), 6x16 tile, 384 blocks (the proven-fastest block
// count). Each wave owns ONE oc-16 block (wave = oc>>4): acc[6] = 24 VGPR
// (no spill), 6 weight loads per (c,kx) feed 54 MFMAs. R8-measured: 102us.
// Best-known config — unchanged.
// ---------------------------------------------------------------------------
__global__ __launch_bounds__(1024) void big_conv_gates(
    const unsigned short* __restrict__ fusedb,  // [z][p][256] hl
    const unsigned short* __restrict__ Wc,      // [9][256][2][128]
    const float* __restrict__ bias,
    float* __restrict__ cst,                    // [z][p][64] fp32
    unsigned short* __restrict__ hbuf,          // [z][p][128] hl
    unsigned short* __restrict__ hseq,          // [(t*2+b)][p][128]
    int t0, int t1)
{
    // 39168 ush = 78336 B. Staging: 144 cells x 264 = 38016 ush (76032 B).
    // Gates: 3 regions x 96 px x 68 floats = 19584 floats = 78336 B.
    __shared__ unsigned short sX[39168];
    const int tid = threadIdx.x;
    const int wave = tid >> 6, lane = tid & 63;
    const int m = lane & 15, quad = lane >> 4;
    const int tY = blockIdx.x / 6, tX = blockIdx.x % 6;   // tY 0..15
    const int z = blockIdx.z;

    const unsigned short* fb = fusedb + (long)z * HW * 256;

    for (int i = tid; i < 144 * 32; i += 1024) {
        int cell = i >> 5, v = i & 31;
        int row = cell / 18, col = cell - row * 18;
        int gy = tY * 6 + row - 1, gx = tX * 16 + col - 1;
        int pl = v >> 4, c = (v & 15) >> 2, g = v & 3;
        bf16x8 val = (bf16x8){0,0,0,0,0,0,0,0};
        if (gy >= 0 && gy < HH && gx >= 0 && gx < WW)
            val = *(const bf16x8*)(fb + (long)(gy * WW + gx) * 256 + pl * 128 + c * 32 + g * 8);
        *(bf16x8*)&sX[cell * 264 + (c * 2 + pl) * 32 + g * 8] = val;
    }
    __syncthreads();

    f32x4 acc[6];
#pragma unroll
    for (int nf = 0; nf < 6; ++nf) acc[nf] = (f32x4){0.f, 0.f, 0.f, 0.f};

#pragma unroll
    for (int c = 0; c < 4; ++c) {
#pragma unroll
        for (int kx = 0; kx < 3; ++kx) {
            bf16x8 Ah[3], Al[3];
#pragma unroll
            for (int ky = 0; ky < 3; ++ky) {
                const unsigned short* wp = Wc + (((long)(ky * 3 + kx) * 256 + wave * 16 + m) * 2) * 128 + c * 32 + quad * 8;
                Ah[ky] = *(const bf16x8*)wp;
                Al[ky] = *(const bf16x8*)(wp + 128);
            }
            bf16x8 Bh[8], Bl[8];
#pragma unroll
            for (int r = 0; r < 3; ++r) {
                int base = (r * 18 + kx + m) * 264 + (c * 2) * 32 + quad * 8;
                Bh[r] = *(const bf16x8*)&sX[base];
                Bl[r] = *(const bf16x8*)&sX[base + 32];
            }
            // nf-outer, rolling 3-row B window: row nf+2 loaded at nf>0, rows
            // < nf dead -> ~6 live B regs. Per-acc (ky, term) order unchanged.
#pragma unroll
            for (int nf = 0; nf < 6; ++nf) {
                if (nf) {
                    int r = nf + 2;
                    int base = (r * 18 + kx + m) * 264 + (c * 2) * 32 + quad * 8;
                    Bh[r] = *(const bf16x8*)&sX[base];
                    Bl[r] = *(const bf16x8*)&sX[base + 32];
                }
#pragma unroll
                for (int ky = 0; ky < 3; ++ky) {
                    acc[nf] = __builtin_amdgcn_mfma_f32_16x16x32_bf16(Ah[ky], Bh[nf + ky], acc[nf], 0, 0, 0);
                    acc[nf] = __builtin_amdgcn_mfma_f32_16x16x32_bf16(Al[ky], Bh[nf + ky], acc[nf], 0, 0, 0);
                    acc[nf] = __builtin_amdgcn_mfma_f32_16x16x32_bf16(Ah[ky], Bl[nf + ky], acc[nf], 0, 0, 0);
                }
            }
        }
    }

    // ---- gates epilogue ----
    // wave w owns oc block w: ci = w0-3, cf = w4-7, co = w8-11, cg = w12-15.
    float* sG = (float*)sX;
    float ba[4];
    {
        int oc0 = wave * 16 + quad * 4;
#pragma unroll
        for (int r = 0; r < 4; ++r) ba[r] = bias[oc0 + r];
    }
    __syncthreads();
    if (wave >= 4) {
        int reg = (wave >> 2) - 1;            // 0=cf, 1=co, 2=cg
        int chb = (wave & 3) * 16 + quad * 4;
#pragma unroll
        for (int nf = 0; nf < 6; ++nf) {
            int px = nf * 16 + m;
            float* f = &sG[reg * 96 * 68 + (long)px * 68 + chb];
#pragma unroll
            for (int r = 0; r < 4; ++r) f[r] = acc[nf][r] + ba[r];
        }
    }
    __syncthreads();
    if (wave < 4) {
        int t = (z < 2) ? t0 : t1;
        int b = z & 1, dir = z >> 1;
        int chb = wave * 16 + quad * 4;
        unsigned short* hsq = hseq + ((long)(t * 2 + b) * HW) * 128 + dir * 64;
#pragma unroll
        for (int nf = 0; nf < 6; ++nf) {
            int px = nf * 16 + m;
            int p = (tY * 6 + nf) * WW + tX * 16 + m;
            float4 cf4 = *(float4*)&sG[0 * 96 * 68 + (long)px * 68 + chb];
            float4 co4 = *(float4*)&sG[1 * 96 * 68 + (long)px * 68 + chb];
            float4 cg4 = *(float4*)&sG[2 * 96 * 68 + (long)px * 68 + chb];
            float* cp = &cst[((long)z * HW + p) * 64 + chb];
            float4 cold = *(float4*)cp;
            float cfv[4] = {cf4.x, cf4.y, cf4.z, cf4.w};
            float cov[4] = {co4.x, co4.y, co4.z, co4.w};
            float cgv[4] = {cg4.x, cg4.y, cg4.z, cg4.w};
            float coldv[4] = {cold.x, cold.y, cold.z, cold.w};
            float c2v[4], h2v[4];
#pragma unroll
            for (int r = 0; r < 4; ++r) {
                float civ = acc[nf][r] + ba[r];
                float c2 = sigf(cfv[r]) * coldv[r] + sigf(civ) * tanhf(cgv[r]);
                float h2 = sigf(cov[r]) * tanhf(c2);
                c2v[r] = c2; h2v[r] = h2;
            }
            *(float4*)cp = (float4){c2v[0], c2v[1], c2v[2], c2v[3]};
            unsigned short* hp = hbuf + ((long)z * HW + p) * 128 + chb;
            ushort4 hv = {bhi(h2v[0]), bhi(h2v[1]), bhi(h2v[2]), bhi(h2v[3])};
            ushort4 lv = {blo(h2v[0]), blo(h2v[1]), blo(h2v[2]), blo(h2v[3])};
            *(ushort4*)hp = hv;
            *(ushort4*)(hp + 64) = lv;
            *(ushort4*)&hsq[(long)p * 128 + chb] = hv;
        }
    }
}

// ---------------------------------------------------------------------------
// cat conv: hseq (single-plane, IC=128) -> out fp32 NCHW with (t,b) permute.
// ---------------------------------------------------------------------------
__global__ __launch_bounds__(256) void cat_conv(
    const unsigned short* __restrict__ hseq,
    const unsigned short* __restrict__ Wk,     // [9][64][2][128]
    const float* __restrict__ bias,
    float* __restrict__ out)
{
    __shared__ unsigned short sX[108 * 136];
    const int tid = threadIdx.x;
    const int wave = tid >> 6, lane = tid & 63;
    const int m = lane & 15, quad = lane >> 4;
    const int tY = blockIdx.x / 6, tX = blockIdx.x % 6;
    const int img = blockIdx.z;
    const unsigned short* hp = hseq + (long)img * HW * 128;

    for (int i = tid; i < 108 * 16; i += 256) {
        int cell = i >> 4, v = i & 15;
        int row = cell / 18, col = cell - row * 18;
        int gy = tY * 4 + row - 1, gx = tX * 16 + col - 1;
        bf16x8 val = (bf16x8){0,0,0,0,0,0,0,0};
        if (gy >= 0 && gy < HH && gx >= 0 && gx < WW)
            val = *(const bf16x8*)(hp + (long)(gy * WW + gx) * 128 + v * 8);
        *(bf16x8*)&sX[cell * 136 + v * 8] = val;
    }
    __syncthreads();

    f32x4 acc[4];
#pragma unroll
    for (int nf = 0; nf < 4; ++nf) acc[nf] = (f32x4){0.f, 0.f, 0.f, 0.f};

#pragma unroll
    for (int c = 0; c < 4; ++c) {
#pragma unroll
        for (int kx = 0; kx < 3; ++kx) {
            bf16x8 B[6];
#pragma unroll
            for (int r = 0; r < 6; ++r)
                B[r] = *(const bf16x8*)&sX[(r * 18 + kx + m) * 136 + c * 32 + quad * 8];
            bf16x8 Ah[3], Al[3];
#pragma unroll
            for (int ky = 0; ky < 3; ++ky) {
                const unsigned short* wp = Wk + (((long)(ky * 3 + kx) * 64 + wave * 16 + m) * 2) * 128 + c * 32 + quad * 8;
                Ah[ky] = *(const bf16x8*)wp;
                Al[ky] = *(const bf16x8*)(wp + 128);
            }
#pragma unroll
            for (int ky = 0; ky < 3; ++ky)
#pragma unroll
                for (int nf = 0; nf < 4; ++nf) {
                    acc[nf] = __builtin_amdgcn_mfma_f32_16x16x32_bf16(Ah[ky], B[nf + ky], acc[nf], 0, 0, 0);
                    acc[nf] = __builtin_amdgcn_mfma_f32_16x16x32_bf16(Al[ky], B[nf + ky], acc[nf], 0, 0, 0);
                }
        }
    }

    int t = img >> 1, b = img & 1;
    long imgOut = (long)(b * TT + t) * 64 * HW;
#pragma unroll
    for (int reg = 0; reg < 4; ++reg) {
        int oc = wave * 16 + quad * 4 + reg;
        float bv = bias[oc];
#pragma unroll
        for (int nf = 0; nf < 4; ++nf) {
            int p = (tY * 4 + nf) * WW + tX * 16 + m;
            out[imgOut + (long)oc * HW + p] = acc[nf][reg] + bv;
        }
    }
}

// ---------------------------------------------------------------------------
extern "C" void kernel_launch(void* const* d_in, const int* in_sizes, int n_in,
                              void* d_out, int out_size, void* d_ws, size_t ws_size,
                              hipStream_t stream)
{
    const float* input  = (const float*)d_in[0];
    const float* fuse_w = (const float*)d_in[1];
    const float* fuse_b = (const float*)d_in[2];
    const float* om_w   = (const float*)d_in[3];
    const float* om_b   = (const float*)d_in[4];
    const float* dcn_w  = (const float*)d_in[5];
    const float* dcn_b  = (const float*)d_in[6];
    const float* conv_w = (const float*)d_in[7];
    const float* conv_b = (const float*)d_in[8];
    const float* cat_w  = (const float*)d_in[9];
    const float* cat_b  = (const float*)d_in[10];
    float* out = (float*)d_out;

    char* w = (char*)d_ws;
    size_t off = 0;
    auto alloc = [&](size_t bytes) { void* p = w + off; off += (bytes + 255) & ~(size_t)255; return p; };

    unsigned short* xbf    = (unsigned short*)alloc(10L * HW * 64 * 2);
    unsigned short* hbuf   = (unsigned short*)alloc(4L * HW * 128 * 2);
    unsigned short* comb   = (unsigned short*)alloc(4L * HW * 64 * 2);
    float*          omb    = (float*)alloc(4L * 216 * HW * 4);
    unsigned short* fusedb = (unsigned short*)alloc(4L * HW * 256 * 2);
    float*          cbufs  = (float*)alloc(4L * HW * 64 * 4);
    unsigned short* hseqb  = (unsigned short*)alloc(10L * HW * 128 * 2);
    unsigned short* Wf = (unsigned short*)alloc(9L * 64 * 2 * 128 * 2);
    unsigned short* Wo = (unsigned short*)alloc(9L * 256 * 2 * 64 * 2);
    unsigned short* Wc = (unsigned short*)alloc(9L * 256 * 2 * 128 * 2);
    unsigned short* Wk = (unsigned short*)alloc(9L * 64 * 2 * 128 * 2);
    unsigned short* W1 = (unsigned short*)alloc(128L * 2 * 576 * 2);

    dim3 blk(256);
    wexp3_kernel<<<dim3(288), blk, 0, stream>>>(fuse_w, Wf, 64, 64, 128);
    wexp3_kernel<<<dim3(576), blk, 0, stream>>>(om_w, Wo, 216, 256, 64);
    wexp3_kernel<<<dim3(1152), blk, 0, stream>>>(conv_w, Wc, 256, 256, 128);
    wexp3_kernel<<<dim3(288), blk, 0, stream>>>(cat_w, Wk, 64, 64, 128);
    wexp1_kernel<<<dim3(288), blk, 0, stream>>>(dcn_w, W1);
    xprep_kernel<<<dim3(23040), blk, 0, stream>>>(input, xbf);

    hipMemsetAsync(hbuf, 0, 4L * HW * 128 * 2, stream);
    hipMemsetAsync(cbufs, 0, 4L * HW * 64 * 4, stream);

    for (int s = 0; s < TT; ++s) {
        int t0 = s, t1 = TT - 1 - s;
        fuse_conv<<<dim3(144, 1, 4), blk, 0, stream>>>(
            xbf, hbuf, Wf, fuse_b, comb, t0, t1);
        om_conv<<<dim3(96, 1, 4), dim3(1024), 0, stream>>>(
            comb, Wo, om_b, omb);
        conv1x1_fused<<<dim3(576), dim3(512), 0, stream>>>(
            hbuf, omb, W1, dcn_b, fusedb);
        big_conv_gates<<<dim3(96, 1, 4), dim3(1024), 0, stream>>>(
            fusedb, Wc, conv_b, cbufs, hbuf, hseqb, t0, t1);
    }
    cat_conv<<<dim3(144, 1, 10), blk, 0, stream>>>(hseqb, Wk, cat_b, out);
}

// Round 14
// 1440.924 us; speedup vs baseline: 1.3084x; 1.0368x over previous
//
#include <hip/hip_runtime.h>
#include <math.h>

#define HH 96
#define WW 96
#define HW 9216
#define TT 5

typedef __attribute__((ext_vector_type(8))) short bf16x8;
typedef __attribute__((ext_vector_type(4))) float f32x4;

__device__ __forceinline__ float sigf(float x) { return 1.0f / (1.0f + expf(-x)); }
__device__ __forceinline__ unsigned short bhi(float x) {
    return (unsigned short)(__float_as_uint(x) >> 16);
}
__device__ __forceinline__ unsigned short blo(float x) {
    float h = __uint_as_float(__float_as_uint(x) & 0xffff0000u);
    return (unsigned short)(__float_as_uint(x - h) >> 16);
}
__device__ __forceinline__ float b2f(unsigned short u) {
    return __uint_as_float(((unsigned)u) << 16);
}

// ---------------------------------------------------------------------------
// Weight expansion: src [OC][IC][9] fp32 -> dst [9][OCP][2][IC] bf16 hi/lo.
// ---------------------------------------------------------------------------
__global__ __launch_bounds__(256) void wexp3_kernel(
    const float* __restrict__ w, unsigned short* __restrict__ dst,
    int OC, int OCP, int IC)
{
    long i = (long)blockIdx.x * 256 + threadIdx.x;
    int ic = (int)(i % IC);
    long r = i / IC;
    int oc = (int)(r % OCP);
    int tap = (int)(r / OCP);
    float v = (oc < OC) ? w[((long)oc * IC + ic) * 9 + tap] : 0.f;
    long base = (((long)tap * OCP + oc) * 2) * IC + ic;
    dst[base] = bhi(v);
    dst[base + IC] = blo(v);
}

// dcn_w [128][576] (576 = c*9+k) -> [128][2][576] with K re-ordered k-major:
// dst K-slot (k*64 + c) = src (c*9 + k).
__global__ __launch_bounds__(256) void wexp1_kernel(
    const float* __restrict__ w, unsigned short* __restrict__ dst)
{
    int i = blockIdx.x * 256 + threadIdx.x;   // over 128*576 dst slots
    int slot = i % 576;                        // k*64 + c
    int oc = i / 576;
    int k = slot >> 6, c = slot & 63;
    float v = w[(long)oc * 576 + c * 9 + k];
    dst[((long)oc * 2) * 576 + slot] = bhi(v);
    dst[((long)oc * 2 + 1) * 576 + slot] = blo(v);
}

// input [b][t][64][HW] fp32 -> xbf [(t*2+b)][p][64] bf16
__global__ __launch_bounds__(256) void xprep_kernel(
    const float* __restrict__ input, unsigned short* __restrict__ xbf)
{
    long i = (long)blockIdx.x * 256 + threadIdx.x;
    int p = (int)(i % HW);
    long r = i / HW;
    int c = (int)(r % 64);
    long bt = r / 64;
    int b = (int)(bt / TT), t = (int)(bt % TT);
    float v = input[i];
    xbf[(((long)(t * 2 + b) * HW) + p) * 64 + c] = bhi(v);
}

// ===========================================================================
// R13 resubmission (round-13 bench was an infra container failure; kernel
// audited clean). fuse_conv and cat_conv get the R8/R12-proven retile:
//   fuse_conv: 6x16 tile, 576->384 blocks (Wf stream -33%), acc[6],
//              rolling-B, LDS 57.6KB (all 384 resident).
//   cat_conv:  6x16 tile, 1440->960 blocks (Wk stream 423->282MB), acc[6].
// Per-acc accumulation order unchanged everywhere -> bitwise-identical.
// conv1x1 gather path is at an L1-line-transaction floor (per-group offsets
// make corner addresses unshareable) - left at R10 form.
// ===========================================================================

// ---------------------------------------------------------------------------
// Fuse conv: x (single, ic 0..63) + h (hl, ic 64..127) -> comb bf16 NHWC.
// 6x16 tile, 4 waves, wave owns one oc-16 block. acc[6]=24 VGPR, rolling-B.
// ---------------------------------------------------------------------------
__global__ __launch_bounds__(256) void fuse_conv(
    const unsigned short* __restrict__ xbf,
    const unsigned short* __restrict__ hbuf,
    const unsigned short* __restrict__ Wf,   // [9][64][2][128]
    const float* __restrict__ bias,
    unsigned short* __restrict__ comb,
    int t0, int t1)
{
    __shared__ unsigned short sX[144 * 200];
    const int tid = threadIdx.x;
    const int wave = tid >> 6, lane = tid & 63;
    const int m = lane & 15, quad = lane >> 4;
    const int tY = blockIdx.x / 6, tX = blockIdx.x % 6;   // tY 0..15
    const int z = blockIdx.z;
    const int imgX = ((z < 2) ? t0 : t1) * 2 + (z & 1);

    const unsigned short* xb = xbf + (long)imgX * HW * 64;
    const unsigned short* hb = hbuf + (long)z * HW * 128;

    for (int i = tid; i < 144 * 24; i += 256) {
        int cell = i / 24, v = i - cell * 24;
        int row = cell / 18, col = cell - row * 18;
        int gy = tY * 6 + row - 1, gx = tX * 16 + col - 1;
        bool ok = (gy >= 0 && gy < HH && gx >= 0 && gx < WW);
        int p = gy * WW + gx;
        bf16x8 val = (bf16x8){0,0,0,0,0,0,0,0};
        int dst;
        if (v < 8) {
            if (ok) val = *(const bf16x8*)(xb + (long)p * 64 + v * 8);
            dst = cell * 200 + v * 8;
        } else {
            int v2 = v - 8;
            int pl = v2 >> 3, c = (v2 & 7) >> 2, g = v2 & 3;
            if (ok) val = *(const bf16x8*)(hb + (long)p * 128 + pl * 64 + c * 32 + g * 8);
            dst = cell * 200 + 64 + (c * 2 + pl) * 32 + g * 8;
        }
        *(bf16x8*)&sX[dst] = val;
    }
    __syncthreads();

    f32x4 acc[6];
#pragma unroll
    for (int nf = 0; nf < 6; ++nf) acc[nf] = (f32x4){0.f, 0.f, 0.f, 0.f};

    // part 1: x channels (single precision), c = 0,1
#pragma unroll
    for (int c = 0; c < 2; ++c) {
#pragma unroll
        for (int kx = 0; kx < 3; ++kx) {
            bf16x8 Ah[3], Al[3];
#pragma unroll
            for (int ky = 0; ky < 3; ++ky) {
                const unsigned short* wp = Wf + (((long)(ky * 3 + kx) * 64 + wave * 16 + m) * 2) * 128 + c * 32 + quad * 8;
                Ah[ky] = *(const bf16x8*)wp;
                Al[ky] = *(const bf16x8*)(wp + 128);
            }
            bf16x8 B[8];
#pragma unroll
            for (int r = 0; r < 3; ++r)
                B[r] = *(const bf16x8*)&sX[(r * 18 + kx + m) * 200 + c * 32 + quad * 8];
#pragma unroll
            for (int nf = 0; nf < 6; ++nf) {
                if (nf) {
                    int r = nf + 2;
                    B[r] = *(const bf16x8*)&sX[(r * 18 + kx + m) * 200 + c * 32 + quad * 8];
                }
#pragma unroll
                for (int ky = 0; ky < 3; ++ky) {
                    acc[nf] = __builtin_amdgcn_mfma_f32_16x16x32_bf16(Ah[ky], B[nf + ky], acc[nf], 0, 0, 0);
                    acc[nf] = __builtin_amdgcn_mfma_f32_16x16x32_bf16(Al[ky], B[nf + ky], acc[nf], 0, 0, 0);
                }
            }
        }
    }
    // part 2: h channels (hl), c = 0,1
#pragma unroll
    for (int c = 0; c < 2; ++c) {
#pragma unroll
        for (int kx = 0; kx < 3; ++kx) {
            bf16x8 Ah[3], Al[3];
#pragma unroll
            for (int ky = 0; ky < 3; ++ky) {
                const unsigned short* wp = Wf + (((long)(ky * 3 + kx) * 64 + wave * 16 + m) * 2) * 128 + (2 + c) * 32 + quad * 8;
                Ah[ky] = *(const bf16x8*)wp;
                Al[ky] = *(const bf16x8*)(wp + 128);
            }
            bf16x8 Bh[8], Bl[8];
#pragma unroll
            for (int r = 0; r < 3; ++r) {
                int base = (r * 18 + kx + m) * 200 + 64 + (c * 2) * 32 + quad * 8;
                Bh[r] = *(const bf16x8*)&sX[base];
                Bl[r] = *(const bf16x8*)&sX[base + 32];
            }
#pragma unroll
            for (int nf = 0; nf < 6; ++nf) {
                if (nf) {
                    int r = nf + 2;
                    int base = (r * 18 + kx + m) * 200 + 64 + (c * 2) * 32 + quad * 8;
                    Bh[r] = *(const bf16x8*)&sX[base];
                    Bl[r] = *(const bf16x8*)&sX[base + 32];
                }
#pragma unroll
                for (int ky = 0; ky < 3; ++ky) {
                    acc[nf] = __builtin_amdgcn_mfma_f32_16x16x32_bf16(Ah[ky], Bh[nf + ky], acc[nf], 0, 0, 0);
                    acc[nf] = __builtin_amdgcn_mfma_f32_16x16x32_bf16(Al[ky], Bh[nf + ky], acc[nf], 0, 0, 0);
                    acc[nf] = __builtin_amdgcn_mfma_f32_16x16x32_bf16(Ah[ky], Bl[nf + ky], acc[nf], 0, 0, 0);
                }
            }
        }
    }

    int ocl = wave * 16 + quad * 4;
    float b0 = bias[ocl], b1 = bias[ocl + 1], b2 = bias[ocl + 2], b3 = bias[ocl + 3];
#pragma unroll
    for (int nf = 0; nf < 6; ++nf) {
        int p = (tY * 6 + nf) * WW + tX * 16 + m;
        ushort4 hv;
        hv.x = bhi(acc[nf].x + b0); hv.y = bhi(acc[nf].y + b1);
        hv.z = bhi(acc[nf].z + b2); hv.w = bhi(acc[nf].w + b3);
        *(ushort4*)&comb[((long)z * HW + p) * 64 + ocl] = hv;
    }
}

// ---------------------------------------------------------------------------
// om conv: comb (single, IC=64) -> om fp32 NCHW (216 of 256 oc).
// R8-recipe clone (R12-measured win): 6x16 tile, 16-wave block, wave owns
// one oc-16 block, acc[6], rolling-3 B window, 8:1 MFMA:load.
// ---------------------------------------------------------------------------
__global__ __launch_bounds__(1024) void om_conv(
    const unsigned short* __restrict__ comb,
    const unsigned short* __restrict__ Wo,   // [9][256][2][64]
    const float* __restrict__ bias,
    float* __restrict__ om)                  // [z][216][HW]
{
    __shared__ unsigned short sX[144 * 72];
    const int tid = threadIdx.x;
    const int wave = tid >> 6, lane = tid & 63;
    const int m = lane & 15, quad = lane >> 4;
    const int tY = blockIdx.x / 6, tX = blockIdx.x % 6;   // tY 0..15
    const int z = blockIdx.z;
    const unsigned short* cbp = comb + (long)z * HW * 64;

    for (int i = tid; i < 144 * 8; i += 1024) {
        int cell = i >> 3, v = i & 7;
        int row = cell / 18, col = cell - row * 18;
        int gy = tY * 6 + row - 1, gx = tX * 16 + col - 1;
        bf16x8 val = (bf16x8){0,0,0,0,0,0,0,0};
        if (gy >= 0 && gy < HH && gx >= 0 && gx < WW)
            val = *(const bf16x8*)(cbp + (long)(gy * WW + gx) * 64 + v * 8);
        *(bf16x8*)&sX[cell * 72 + v * 8] = val;
    }
    __syncthreads();

    if (wave * 16 >= 216) return;   // oc blocks 14,15 are pure padding

    f32x4 acc[6];
#pragma unroll
    for (int nf = 0; nf < 6; ++nf) acc[nf] = (f32x4){0.f, 0.f, 0.f, 0.f};

#pragma unroll
    for (int c = 0; c < 2; ++c) {
#pragma unroll
        for (int kx = 0; kx < 3; ++kx) {
            bf16x8 Ah[3], Al[3];
#pragma unroll
            for (int ky = 0; ky < 3; ++ky) {
                const unsigned short* wp = Wo + (((long)(ky * 3 + kx) * 256 + wave * 16 + m) * 2) * 64 + c * 32 + quad * 8;
                Ah[ky] = *(const bf16x8*)wp;
                Al[ky] = *(const bf16x8*)(wp + 64);
            }
            bf16x8 B[8];
#pragma unroll
            for (int r = 0; r < 3; ++r)
                B[r] = *(const bf16x8*)&sX[(r * 18 + kx + m) * 72 + c * 32 + quad * 8];
#pragma unroll
            for (int nf = 0; nf < 6; ++nf) {
                if (nf) {
                    int r = nf + 2;
                    B[r] = *(const bf16x8*)&sX[(r * 18 + kx + m) * 72 + c * 32 + quad * 8];
                }
#pragma unroll
                for (int ky = 0; ky < 3; ++ky) {
                    acc[nf] = __builtin_amdgcn_mfma_f32_16x16x32_bf16(Ah[ky], B[nf + ky], acc[nf], 0, 0, 0);
                    acc[nf] = __builtin_amdgcn_mfma_f32_16x16x32_bf16(Al[ky], B[nf + ky], acc[nf], 0, 0, 0);
                }
            }
        }
    }

#pragma unroll
    for (int reg = 0; reg < 4; ++reg) {
        int oc = wave * 16 + quad * 4 + reg;
        if (oc < 216) {
            float bv = bias[oc];
#pragma unroll
            for (int nf = 0; nf < 6; ++nf) {
                int p = (tY * 6 + nf) * WW + tX * 16 + m;
                om[((long)z * 216 + oc) * HW + p] = acc[nf][reg] + bv;
            }
        }
    }
}

// ---------------------------------------------------------------------------
// FUSED deformable-sampling + 1x1 DCN einsum (512 threads, XCD-swizzled).
// R10 exact form (absmax 0.00098): sampling expressions identical to the
// original dcn_sample_kernel. Pipelining attempts were perf-null and cost
// numeric margin -> kept simple.
// ---------------------------------------------------------------------------
__global__ __launch_bounds__(512) void conv1x1_fused(
    const unsigned short* __restrict__ hbuf,  // [4][p][128] hl
    const float* __restrict__ om,             // [4][216][HW]
    const unsigned short* __restrict__ w1,    // [128][2][576] k-major
    const float* __restrict__ bias,
    unsigned short* __restrict__ fused)       // [z][p][256] hl
{
    __shared__ unsigned short sX[64 * 76];
    const int tid  = threadIdx.x;
    const int wave = tid >> 6, lane = tid & 63;
    const int m = lane & 15, quad = lane >> 4;

    // bijective XCD swizzle over 576 = 8 XCDs x 72 chunks
    const int bid = blockIdx.x;
    const int work = (bid & 7) * 72 + (bid >> 3);
    const int zz = work / 144;
    const int pt = work - zz * 144;

    const float* omb = om + (long)zz * 216 * HW;
    const unsigned short* hz = hbuf + (long)zz * HW * 128;

    const int g0 = tid >> 6;        // 0..7  (channel group; = wave)
    const int cellb = tid & 63;     // 0..63 (pixel within tile)

    // Bilinear-sample 8 channels (group g0) at pixel p=pt*64+cell, tap cb.
    // Expression-identical to the old dcn_sample_kernel -> bitwise-same bf16.
    auto sample = [&](int cell, int cb) -> bf16x8 {
        int p = pt * 64 + cell;
        int y = p / WW, x = p - y * WW;
        int ky = cb / 3, kx = cb - ky * 3;
        float offy = omb[(g0 * 18 + cb * 2) * HW + p];
        float offx = omb[(g0 * 18 + cb * 2 + 1) * HW + p];
        float mm = sigf(omb[(144 + g0 * 9 + cb) * HW + p]);
        float py = (float)(y + ky - 1) + offy;
        float px = (float)(x + kx - 1) + offx;
        float y0f = floorf(py), x0f = floorf(px);
        float wy = py - y0f, wx = px - x0f;
        int y0 = (int)y0f, x0 = (int)x0f;
        int y1 = y0 + 1, x1 = x0 + 1;
        bool vy0 = (y0 >= 0) && (y0 < HH), vy1 = (y1 >= 0) && (y1 < HH);
        bool vx0 = (x0 >= 0) && (x0 < WW), vx1 = (x1 >= 0) && (x1 < WW);
        int cy0 = min(max(y0, 0), HH - 1), cy1 = min(max(y1, 0), HH - 1);
        int cx0 = min(max(x0, 0), WW - 1), cx1 = min(max(x1, 0), WW - 1);
        long i00 = cy0 * WW + cx0, i01 = cy0 * WW + cx1;
        long i10 = cy1 * WW + cx0, i11 = cy1 * WW + cx1;
        float w00 = (1.f - wy) * (1.f - wx) * ((vy0 && vx0) ? mm : 0.f);
        float w01 = (1.f - wy) * wx         * ((vy0 && vx1) ? mm : 0.f);
        float w10 = wy * (1.f - wx)         * ((vy1 && vx0) ? mm : 0.f);
        float w11 = wy * wx                 * ((vy1 && vx1) ? mm : 0.f);
        const unsigned short* hzb = hz + g0 * 8;
        bf16x8 h00 = *(const bf16x8*)(hzb + i00 * 128);
        bf16x8 l00 = *(const bf16x8*)(hzb + i00 * 128 + 64);
        bf16x8 h01 = *(const bf16x8*)(hzb + i01 * 128);
        bf16x8 l01 = *(const bf16x8*)(hzb + i01 * 128 + 64);
        bf16x8 h10 = *(const bf16x8*)(hzb + i10 * 128);
        bf16x8 l10 = *(const bf16x8*)(hzb + i10 * 128 + 64);
        bf16x8 h11 = *(const bf16x8*)(hzb + i11 * 128);
        bf16x8 l11 = *(const bf16x8*)(hzb + i11 * 128 + 64);
        bf16x8 outv;
#pragma unroll
        for (int cg = 0; cg < 8; ++cg) {
            float v00 = b2f((unsigned short)h00[cg]) + b2f((unsigned short)l00[cg]);
            float v01 = b2f((unsigned short)h01[cg]) + b2f((unsigned short)l01[cg]);
            float v10 = b2f((unsigned short)h10[cg]) + b2f((unsigned short)l10[cg]);
            float v11 = b2f((unsigned short)h11[cg]) + b2f((unsigned short)l11[cg]);
            float v = w00 * v00 + w01 * v01 + w10 * v10 + w11 * v11;
            outv[cg] = (short)bhi(v);
        }
        return outv;
    };

    f32x4 acc[4];
#pragma unroll
    for (int nf = 0; nf < 4; ++nf) acc[nf] = (f32x4){0.f, 0.f, 0.f, 0.f};

    for (int cb = 0; cb < 9; ++cb) {
        if (cb) __syncthreads();
        bf16x8 R0 = sample(cellb, cb);
        *(bf16x8*)&sX[cellb * 76 + g0 * 8] = R0;
        __syncthreads();

        bf16x8 Bv[2][4];
#pragma unroll
        for (int sub = 0; sub < 2; ++sub)
#pragma unroll
            for (int nf = 0; nf < 4; ++nf)
                Bv[sub][nf] = *(const bf16x8*)&sX[(nf * 16 + m) * 76 + sub * 32 + quad * 8];
        bf16x8 Ah[2], Al[2];
#pragma unroll
        for (int sub = 0; sub < 2; ++sub) {
            const unsigned short* wp = w1 + ((long)(wave * 16 + m) * 2) * 576
                                       + cb * 64 + sub * 32 + quad * 8;
            Ah[sub] = *(const bf16x8*)wp;
            Al[sub] = *(const bf16x8*)(wp + 576);
        }
#pragma unroll
        for (int sub = 0; sub < 2; ++sub)
#pragma unroll
            for (int nf = 0; nf < 4; ++nf) {
                acc[nf] = __builtin_amdgcn_mfma_f32_16x16x32_bf16(
                    Ah[sub], Bv[sub][nf], acc[nf], 0, 0, 0);
                acc[nf] = __builtin_amdgcn_mfma_f32_16x16x32_bf16(
                    Al[sub], Bv[sub][nf], acc[nf], 0, 0, 0);
            }
    }

    {
        int ocl = wave * 16 + quad * 4;
        float b0 = bias[ocl], b1 = bias[ocl + 1], b2 = bias[ocl + 2], b3 = bias[ocl + 3];
#pragma unroll
        for (int nf = 0; nf < 4; ++nf) {
            int p = pt * 64 + nf * 16 + m;
            float v0 = fmaxf(acc[nf].x + b0, 0.f);
            float v1 = fmaxf(acc[nf].y + b1, 0.f);
            float v2 = fmaxf(acc[nf].z + b2, 0.f);
            float v3 = fmaxf(acc[nf].w + b3, 0.f);
            unsigned short* op = fused + ((long)zz * HW + p) * 256 + ocl;
            ushort4 hv, lv;
            hv.x = bhi(v0); hv.y = bhi(v1); hv.z = bhi(v2); hv.w = bhi(v3);
            lv.x = blo(v0); lv.y = blo(v1); lv.z = blo(v2); lv.w = blo(v3);
            *(ushort4*)op = hv;
            *(ushort4*)(op + 128) = lv;
        }
    }
}

// ---------------------------------------------------------------------------
// Big conv (IC=128 hl, OC=256) FUSED with LSTM gates.
// 16-wave blocks (1024 thr), 6x16 tile, 384 blocks (the proven-fastest block
// count). Each wave owns ONE oc-16 block (wave = oc>>4): acc[6] = 24 VGPR
// (no spill), 6 weight loads per (c,kx) feed 54 MFMAs. R8-measured: 102us.
// Best-known config — unchanged.
// ---------------------------------------------------------------------------
__global__ __launch_bounds__(1024) void big_conv_gates(
    const unsigned short* __restrict__ fusedb,  // [z][p][256] hl
    const unsigned short* __restrict__ Wc,      // [9][256][2][128]
    const float* __restrict__ bias,
    float* __restrict__ cst,                    // [z][p][64] fp32
    unsigned short* __restrict__ hbuf,          // [z][p][128] hl
    unsigned short* __restrict__ hseq,          // [(t*2+b)][p][128]
    int t0, int t1)
{
    // 39168 ush = 78336 B. Staging: 144 cells x 264 = 38016 ush (76032 B).
    // Gates: 3 regions x 96 px x 68 floats = 19584 floats = 78336 B.
    __shared__ unsigned short sX[39168];
    const int tid = threadIdx.x;
    const int wave = tid >> 6, lane = tid & 63;
    const int m = lane & 15, quad = lane >> 4;
    const int tY = blockIdx.x / 6, tX = blockIdx.x % 6;   // tY 0..15
    const int z = blockIdx.z;

    const unsigned short* fb = fusedb + (long)z * HW * 256;

    for (int i = tid; i < 144 * 32; i += 1024) {
        int cell = i >> 5, v = i & 31;
        int row = cell / 18, col = cell - row * 18;
        int gy = tY * 6 + row - 1, gx = tX * 16 + col - 1;
        int pl = v >> 4, c = (v & 15) >> 2, g = v & 3;
        bf16x8 val = (bf16x8){0,0,0,0,0,0,0,0};
        if (gy >= 0 && gy < HH && gx >= 0 && gx < WW)
            val = *(const bf16x8*)(fb + (long)(gy * WW + gx) * 256 + pl * 128 + c * 32 + g * 8);
        *(bf16x8*)&sX[cell * 264 + (c * 2 + pl) * 32 + g * 8] = val;
    }
    __syncthreads();

    f32x4 acc[6];
#pragma unroll
    for (int nf = 0; nf < 6; ++nf) acc[nf] = (f32x4){0.f, 0.f, 0.f, 0.f};

#pragma unroll
    for (int c = 0; c < 4; ++c) {
#pragma unroll
        for (int kx = 0; kx < 3; ++kx) {
            bf16x8 Ah[3], Al[3];
#pragma unroll
            for (int ky = 0; ky < 3; ++ky) {
                const unsigned short* wp = Wc + (((long)(ky * 3 + kx) * 256 + wave * 16 + m) * 2) * 128 + c * 32 + quad * 8;
                Ah[ky] = *(const bf16x8*)wp;
                Al[ky] = *(const bf16x8*)(wp + 128);
            }
            bf16x8 Bh[8], Bl[8];
#pragma unroll
            for (int r = 0; r < 3; ++r) {
                int base = (r * 18 + kx + m) * 264 + (c * 2) * 32 + quad * 8;
                Bh[r] = *(const bf16x8*)&sX[base];
                Bl[r] = *(const bf16x8*)&sX[base + 32];
            }
            // nf-outer, rolling 3-row B window: row nf+2 loaded at nf>0, rows
            // < nf dead -> ~6 live B regs. Per-acc (ky, term) order unchanged.
#pragma unroll
            for (int nf = 0; nf < 6; ++nf) {
                if (nf) {
                    int r = nf + 2;
                    int base = (r * 18 + kx + m) * 264 + (c * 2) * 32 + quad * 8;
                    Bh[r] = *(const bf16x8*)&sX[base];
                    Bl[r] = *(const bf16x8*)&sX[base + 32];
                }
#pragma unroll
                for (int ky = 0; ky < 3; ++ky) {
                    acc[nf] = __builtin_amdgcn_mfma_f32_16x16x32_bf16(Ah[ky], Bh[nf + ky], acc[nf], 0, 0, 0);
                    acc[nf] = __builtin_amdgcn_mfma_f32_16x16x32_bf16(Al[ky], Bh[nf + ky], acc[nf], 0, 0, 0);
                    acc[nf] = __builtin_amdgcn_mfma_f32_16x16x32_bf16(Ah[ky], Bl[nf + ky], acc[nf], 0, 0, 0);
                }
            }
        }
    }

    // ---- gates epilogue ----
    // wave w owns oc block w: ci = w0-3, cf = w4-7, co = w8-11, cg = w12-15.
    float* sG = (float*)sX;
    float ba[4];
    {
        int oc0 = wave * 16 + quad * 4;
#pragma unroll
        for (int r = 0; r < 4; ++r) ba[r] = bias[oc0 + r];
    }
    __syncthreads();
    if (wave >= 4) {
        int reg = (wave >> 2) - 1;            // 0=cf, 1=co, 2=cg
        int chb = (wave & 3) * 16 + quad * 4;
#pragma unroll
        for (int nf = 0; nf < 6; ++nf) {
            int px = nf * 16 + m;
            float* f = &sG[reg * 96 * 68 + (long)px * 68 + chb];
#pragma unroll
            for (int r = 0; r < 4; ++r) f[r] = acc[nf][r] + ba[r];
        }
    }
    __syncthreads();
    if (wave < 4) {
        int t = (z < 2) ? t0 : t1;
        int b = z & 1, dir = z >> 1;
        int chb = wave * 16 + quad * 4;
        unsigned short* hsq = hseq + ((long)(t * 2 + b) * HW) * 128 + dir * 64;
#pragma unroll
        for (int nf = 0; nf < 6; ++nf) {
            int px = nf * 16 + m;
            int p = (tY * 6 + nf) * WW + tX * 16 + m;
            float4 cf4 = *(float4*)&sG[0 * 96 * 68 + (long)px * 68 + chb];
            float4 co4 = *(float4*)&sG[1 * 96 * 68 + (long)px * 68 + chb];
            float4 cg4 = *(float4*)&sG[2 * 96 * 68 + (long)px * 68 + chb];
            float* cp = &cst[((long)z * HW + p) * 64 + chb];
            float4 cold = *(float4*)cp;
            float cfv[4] = {cf4.x, cf4.y, cf4.z, cf4.w};
            float cov[4] = {co4.x, co4.y, co4.z, co4.w};
            float cgv[4] = {cg4.x, cg4.y, cg4.z, cg4.w};
            float coldv[4] = {cold.x, cold.y, cold.z, cold.w};
            float c2v[4], h2v[4];
#pragma unroll
            for (int r = 0; r < 4; ++r) {
                float civ = acc[nf][r] + ba[r];
                float c2 = sigf(cfv[r]) * coldv[r] + sigf(civ) * tanhf(cgv[r]);
                float h2 = sigf(cov[r]) * tanhf(c2);
                c2v[r] = c2; h2v[r] = h2;
            }
            *(float4*)cp = (float4){c2v[0], c2v[1], c2v[2], c2v[3]};
            unsigned short* hp = hbuf + ((long)z * HW + p) * 128 + chb;
            ushort4 hv = {bhi(h2v[0]), bhi(h2v[1]), bhi(h2v[2]), bhi(h2v[3])};
            ushort4 lv = {blo(h2v[0]), blo(h2v[1]), blo(h2v[2]), blo(h2v[3])};
            *(ushort4*)hp = hv;
            *(ushort4*)(hp + 64) = lv;
            *(ushort4*)&hsq[(long)p * 128 + chb] = hv;
        }
    }
}

// ---------------------------------------------------------------------------
// cat conv: hseq (single-plane, IC=128) -> out fp32 NCHW with (t,b) permute.
// 6x16 tile: grid 96x10 = 960 blocks (was 1440), acc[6], rolling-B.
// ---------------------------------------------------------------------------
__global__ __launch_bounds__(256) void cat_conv(
    const unsigned short* __restrict__ hseq,
    const unsigned short* __restrict__ Wk,     // [9][64][2][128]
    const float* __restrict__ bias,
    float* __restrict__ out)
{
    __shared__ unsigned short sX[144 * 136];
    const int tid = threadIdx.x;
    const int wave = tid >> 6, lane = tid & 63;
    const int m = lane & 15, quad = lane >> 4;
    const int tY = blockIdx.x / 6, tX = blockIdx.x % 6;   // tY 0..15
    const int img = blockIdx.z;
    const unsigned short* hp = hseq + (long)img * HW * 128;

    for (int i = tid; i < 144 * 16; i += 256) {
        int cell = i >> 4, v = i & 15;
        int row = cell / 18, col = cell - row * 18;
        int gy = tY * 6 + row - 1, gx = tX * 16 + col - 1;
        bf16x8 val = (bf16x8){0,0,0,0,0,0,0,0};
        if (gy >= 0 && gy < HH && gx >= 0 && gx < WW)
            val = *(const bf16x8*)(hp + (long)(gy * WW + gx) * 128 + v * 8);
        *(bf16x8*)&sX[cell * 136 + v * 8] = val;
    }
    __syncthreads();

    f32x4 acc[6];
#pragma unroll
    for (int nf = 0; nf < 6; ++nf) acc[nf] = (f32x4){0.f, 0.f, 0.f, 0.f};

#pragma unroll
    for (int c = 0; c < 4; ++c) {
#pragma unroll
        for (int kx = 0; kx < 3; ++kx) {
            bf16x8 Ah[3], Al[3];
#pragma unroll
            for (int ky = 0; ky < 3; ++ky) {
                const unsigned short* wp = Wk + (((long)(ky * 3 + kx) * 64 + wave * 16 + m) * 2) * 128 + c * 32 + quad * 8;
                Ah[ky] = *(const bf16x8*)wp;
                Al[ky] = *(const bf16x8*)(wp + 128);
            }
            bf16x8 B[8];
#pragma unroll
            for (int r = 0; r < 3; ++r)
                B[r] = *(const bf16x8*)&sX[(r * 18 + kx + m) * 136 + c * 32 + quad * 8];
#pragma unroll
            for (int nf = 0; nf < 6; ++nf) {
                if (nf) {
                    int r = nf + 2;
                    B[r] = *(const bf16x8*)&sX[(r * 18 + kx + m) * 136 + c * 32 + quad * 8];
                }
#pragma unroll
                for (int ky = 0; ky < 3; ++ky) {
                    acc[nf] = __builtin_amdgcn_mfma_f32_16x16x32_bf16(Ah[ky], B[nf + ky], acc[nf], 0, 0, 0);
                    acc[nf] = __builtin_amdgcn_mfma_f32_16x16x32_bf16(Al[ky], B[nf + ky], acc[nf], 0, 0, 0);
                }
            }
        }
    }

    int t = img >> 1, b = img & 1;
    long imgOut = (long)(b * TT + t) * 64 * HW;
#pragma unroll
    for (int reg = 0; reg < 4; ++reg) {
        int oc = wave * 16 + quad * 4 + reg;
        float bv = bias[oc];
#pragma unroll
        for (int nf = 0; nf < 6; ++nf) {
            int p = (tY * 6 + nf) * WW + tX * 16 + m;
            out[imgOut + (long)oc * HW + p] = acc[nf][reg] + bv;
        }
    }
}

// ---------------------------------------------------------------------------
extern "C" void kernel_launch(void* const* d_in, const int* in_sizes, int n_in,
                              void* d_out, int out_size, void* d_ws, size_t ws_size,
                              hipStream_t stream)
{
    const float* input  = (const float*)d_in[0];
    const float* fuse_w = (const float*)d_in[1];
    const float* fuse_b = (const float*)d_in[2];
    const float* om_w   = (const float*)d_in[3];
    const float* om_b   = (const float*)d_in[4];
    const float* dcn_w  = (const float*)d_in[5];
    const float* dcn_b  = (const float*)d_in[6];
    const float* conv_w = (const float*)d_in[7];
    const float* conv_b = (const float*)d_in[8];
    const float* cat_w  = (const float*)d_in[9];
    const float* cat_b  = (const float*)d_in[10];
    float* out = (float*)d_out;

    char* w = (char*)d_ws;
    size_t off = 0;
    auto alloc = [&](size_t bytes) { void* p = w + off; off += (bytes + 255) & ~(size_t)255; return p; };

    unsigned short* xbf    = (unsigned short*)alloc(10L * HW * 64 * 2);
    unsigned short* hbuf   = (unsigned short*)alloc(4L * HW * 128 * 2);
    unsigned short* comb   = (unsigned short*)alloc(4L * HW * 64 * 2);
    float*          omb    = (float*)alloc(4L * 216 * HW * 4);
    unsigned short* fusedb = (unsigned short*)alloc(4L * HW * 256 * 2);
    float*          cbufs  = (float*)alloc(4L * HW * 64 * 4);
    unsigned short* hseqb  = (unsigned short*)alloc(10L * HW * 128 * 2);
    unsigned short* Wf = (unsigned short*)alloc(9L * 64 * 2 * 128 * 2);
    unsigned short* Wo = (unsigned short*)alloc(9L * 256 * 2 * 64 * 2);
    unsigned short* Wc = (unsigned short*)alloc(9L * 256 * 2 * 128 * 2);
    unsigned short* Wk = (unsigned short*)alloc(9L * 64 * 2 * 128 * 2);
    unsigned short* W1 = (unsigned short*)alloc(128L * 2 * 576 * 2);

    dim3 blk(256);
    wexp3_kernel<<<dim3(288), blk, 0, stream>>>(fuse_w, Wf, 64, 64, 128);
    wexp3_kernel<<<dim3(576), blk, 0, stream>>>(om_w, Wo, 216, 256, 64);
    wexp3_kernel<<<dim3(1152), blk, 0, stream>>>(conv_w, Wc, 256, 256, 128);
    wexp3_kernel<<<dim3(288), blk, 0, stream>>>(cat_w, Wk, 64, 64, 128);
    wexp1_kernel<<<dim3(288), blk, 0, stream>>>(dcn_w, W1);
    xprep_kernel<<<dim3(23040), blk, 0, stream>>>(input, xbf);

    hipMemsetAsync(hbuf, 0, 4L * HW * 128 * 2, stream);
    hipMemsetAsync(cbufs, 0, 4L * HW * 64 * 4, stream);

    for (int s = 0; s < TT; ++s) {
        int t0 = s, t1 = TT - 1 - s;
        fuse_conv<<<dim3(96, 1, 4), blk, 0, stream>>>(
            xbf, hbuf, Wf, fuse_b, comb, t0, t1);
        om_conv<<<dim3(96, 1, 4), dim3(1024), 0, stream>>>(
            comb, Wo, om_b, omb);
        conv1x1_fused<<<dim3(576), dim3(512), 0, stream>>>(
            hbuf, omb, W1, dcn_b, fusedb);
        big_conv_gates<<<dim3(96, 1, 4), dim3(1024), 0, stream>>>(
            fusedb, Wc, conv_b, cbufs, hbuf, hseqb, t0, t1);
    }
    cat_conv<<<dim3(96, 1, 10), blk, 0, stream>>>(hseqb, Wk, cat_b, out);
}

// Round 15
// 1384.081 us; speedup vs baseline: 1.3621x; 1.0411x over previous
//
#include <hip/hip_runtime.h>
#include <math.h>

#define HH 96
#define WW 96
#define HW 9216
#define TT 5

typedef __attribute__((ext_vector_type(8))) short bf16x8;
typedef __attribute__((ext_vector_type(4))) float f32x4;

__device__ __forceinline__ float sigf(float x) { return 1.0f / (1.0f + expf(-x)); }
__device__ __forceinline__ unsigned short bhi(float x) {
    return (unsigned short)(__float_as_uint(x) >> 16);
}
__device__ __forceinline__ unsigned short blo(float x) {
    float h = __uint_as_float(__float_as_uint(x) & 0xffff0000u);
    return (unsigned short)(__float_as_uint(x - h) >> 16);
}
__device__ __forceinline__ float b2f(unsigned short u) {
    return __uint_as_float(((unsigned)u) << 16);
}

// ---------------------------------------------------------------------------
// Weight expansion: src [OC][IC][9] fp32 -> dst [9][OCP][2][IC] bf16 hi/lo.
// ---------------------------------------------------------------------------
__global__ __launch_bounds__(256) void wexp3_kernel(
    const float* __restrict__ w, unsigned short* __restrict__ dst,
    int OC, int OCP, int IC)
{
    long i = (long)blockIdx.x * 256 + threadIdx.x;
    int ic = (int)(i % IC);
    long r = i / IC;
    int oc = (int)(r % OCP);
    int tap = (int)(r / OCP);
    float v = (oc < OC) ? w[((long)oc * IC + ic) * 9 + tap] : 0.f;
    long base = (((long)tap * OCP + oc) * 2) * IC + ic;
    dst[base] = bhi(v);
    dst[base + IC] = blo(v);
}

// dcn_w [128][576] (576 = c*9+k) -> [128][2][576] with K re-ordered k-major:
// dst K-slot (k*64 + c) = src (c*9 + k).
__global__ __launch_bounds__(256) void wexp1_kernel(
    const float* __restrict__ w, unsigned short* __restrict__ dst)
{
    int i = blockIdx.x * 256 + threadIdx.x;   // over 128*576 dst slots
    int slot = i % 576;                        // k*64 + c
    int oc = i / 576;
    int k = slot >> 6, c = slot & 63;
    float v = w[(long)oc * 576 + c * 9 + k];
    dst[((long)oc * 2) * 576 + slot] = bhi(v);
    dst[((long)oc * 2 + 1) * 576 + slot] = blo(v);
}

// input [b][t][64][HW] fp32 -> xbf [(t*2+b)][p][64] bf16
__global__ __launch_bounds__(256) void xprep_kernel(
    const float* __restrict__ input, unsigned short* __restrict__ xbf)
{
    long i = (long)blockIdx.x * 256 + threadIdx.x;
    int p = (int)(i % HW);
    long r = i / HW;
    int c = (int)(r % 64);
    long bt = r / 64;
    int b = (int)(bt / TT), t = (int)(bt % TT);
    float v = input[i];
    xbf[(((long)(t * 2 + b) * HW) + p) * 64 + c] = bhi(v);
}

// ===========================================================================
// R15: hbuf RECORD RE-INTERLEAVED from [p][hi64|lo64] to [p][16 groups of
// hi8|lo8]. Every bilinear corner's hi+lo is now one contiguous 32B (same
// 64B line) instead of two reads 128B apart -> conv1x1's gather touches 4
// lines/thread-tap instead of 8. Pure relocation: identical values, bitwise-
// identical output. Touch-points: big's h-write, fuse's staging read,
// conv1x1's corner loads. All other kernels at R14 measured-best configs.
// ===========================================================================

// ---------------------------------------------------------------------------
// Fuse conv: x (single, ic 0..63) + h (hl, ic 64..127) -> comb bf16 NHWC.
// 6x16 tile, 4 waves, wave owns one oc-16 block. acc[6]=24 VGPR, rolling-B.
// ---------------------------------------------------------------------------
__global__ __launch_bounds__(256) void fuse_conv(
    const unsigned short* __restrict__ xbf,
    const unsigned short* __restrict__ hbuf,
    const unsigned short* __restrict__ Wf,   // [9][64][2][128]
    const float* __restrict__ bias,
    unsigned short* __restrict__ comb,
    int t0, int t1)
{
    __shared__ unsigned short sX[144 * 200];
    const int tid = threadIdx.x;
    const int wave = tid >> 6, lane = tid & 63;
    const int m = lane & 15, quad = lane >> 4;
    const int tY = blockIdx.x / 6, tX = blockIdx.x % 6;   // tY 0..15
    const int z = blockIdx.z;
    const int imgX = ((z < 2) ? t0 : t1) * 2 + (z & 1);

    const unsigned short* xb = xbf + (long)imgX * HW * 64;
    const unsigned short* hb = hbuf + (long)z * HW * 128;

    for (int i = tid; i < 144 * 24; i += 256) {
        int cell = i / 24, v = i - cell * 24;
        int row = cell / 18, col = cell - row * 18;
        int gy = tY * 6 + row - 1, gx = tX * 16 + col - 1;
        bool ok = (gy >= 0 && gy < HH && gx >= 0 && gx < WW);
        int p = gy * WW + gx;
        bf16x8 val = (bf16x8){0,0,0,0,0,0,0,0};
        int dst;
        if (v < 8) {
            if (ok) val = *(const bf16x8*)(xb + (long)p * 64 + v * 8);
            dst = cell * 200 + v * 8;
        } else {
            int v2 = v - 8;
            int pl = v2 >> 3, c = (v2 & 7) >> 2, g = v2 & 3;
            // hbuf record: [16 groups][hi8|lo8]; channels c*32+g*8 = group c*4+g
            if (ok) val = *(const bf16x8*)(hb + (long)p * 128 + (c * 4 + g) * 16 + pl * 8);
            dst = cell * 200 + 64 + (c * 2 + pl) * 32 + g * 8;
        }
        *(bf16x8*)&sX[dst] = val;
    }
    __syncthreads();

    f32x4 acc[6];
#pragma unroll
    for (int nf = 0; nf < 6; ++nf) acc[nf] = (f32x4){0.f, 0.f, 0.f, 0.f};

    // part 1: x channels (single precision), c = 0,1
#pragma unroll
    for (int c = 0; c < 2; ++c) {
#pragma unroll
        for (int kx = 0; kx < 3; ++kx) {
            bf16x8 Ah[3], Al[3];
#pragma unroll
            for (int ky = 0; ky < 3; ++ky) {
                const unsigned short* wp = Wf + (((long)(ky * 3 + kx) * 64 + wave * 16 + m) * 2) * 128 + c * 32 + quad * 8;
                Ah[ky] = *(const bf16x8*)wp;
                Al[ky] = *(const bf16x8*)(wp + 128);
            }
            bf16x8 B[8];
#pragma unroll
            for (int r = 0; r < 3; ++r)
                B[r] = *(const bf16x8*)&sX[(r * 18 + kx + m) * 200 + c * 32 + quad * 8];
#pragma unroll
            for (int nf = 0; nf < 6; ++nf) {
                if (nf) {
                    int r = nf + 2;
                    B[r] = *(const bf16x8*)&sX[(r * 18 + kx + m) * 200 + c * 32 + quad * 8];
                }
#pragma unroll
                for (int ky = 0; ky < 3; ++ky) {
                    acc[nf] = __builtin_amdgcn_mfma_f32_16x16x32_bf16(Ah[ky], B[nf + ky], acc[nf], 0, 0, 0);
                    acc[nf] = __builtin_amdgcn_mfma_f32_16x16x32_bf16(Al[ky], B[nf + ky], acc[nf], 0, 0, 0);
                }
            }
        }
    }
    // part 2: h channels (hl), c = 0,1
#pragma unroll
    for (int c = 0; c < 2; ++c) {
#pragma unroll
        for (int kx = 0; kx < 3; ++kx) {
            bf16x8 Ah[3], Al[3];
#pragma unroll
            for (int ky = 0; ky < 3; ++ky) {
                const unsigned short* wp = Wf + (((long)(ky * 3 + kx) * 64 + wave * 16 + m) * 2) * 128 + (2 + c) * 32 + quad * 8;
                Ah[ky] = *(const bf16x8*)wp;
                Al[ky] = *(const bf16x8*)(wp + 128);
            }
            bf16x8 Bh[8], Bl[8];
#pragma unroll
            for (int r = 0; r < 3; ++r) {
                int base = (r * 18 + kx + m) * 200 + 64 + (c * 2) * 32 + quad * 8;
                Bh[r] = *(const bf16x8*)&sX[base];
                Bl[r] = *(const bf16x8*)&sX[base + 32];
            }
#pragma unroll
            for (int nf = 0; nf < 6; ++nf) {
                if (nf) {
                    int r = nf + 2;
                    int base = (r * 18 + kx + m) * 200 + 64 + (c * 2) * 32 + quad * 8;
                    Bh[r] = *(const bf16x8*)&sX[base];
                    Bl[r] = *(const bf16x8*)&sX[base + 32];
                }
#pragma unroll
                for (int ky = 0; ky < 3; ++ky) {
                    acc[nf] = __builtin_amdgcn_mfma_f32_16x16x32_bf16(Ah[ky], Bh[nf + ky], acc[nf], 0, 0, 0);
                    acc[nf] = __builtin_amdgcn_mfma_f32_16x16x32_bf16(Al[ky], Bh[nf + ky], acc[nf], 0, 0, 0);
                    acc[nf] = __builtin_amdgcn_mfma_f32_16x16x32_bf16(Ah[ky], Bl[nf + ky], acc[nf], 0, 0, 0);
                }
            }
        }
    }

    int ocl = wave * 16 + quad * 4;
    float b0 = bias[ocl], b1 = bias[ocl + 1], b2 = bias[ocl + 2], b3 = bias[ocl + 3];
#pragma unroll
    for (int nf = 0; nf < 6; ++nf) {
        int p = (tY * 6 + nf) * WW + tX * 16 + m;
        ushort4 hv;
        hv.x = bhi(acc[nf].x + b0); hv.y = bhi(acc[nf].y + b1);
        hv.z = bhi(acc[nf].z + b2); hv.w = bhi(acc[nf].w + b3);
        *(ushort4*)&comb[((long)z * HW + p) * 64 + ocl] = hv;
    }
}

// ---------------------------------------------------------------------------
// om conv: comb (single, IC=64) -> om fp32 NCHW (216 of 256 oc).
// R8-recipe clone (R12-measured win): 6x16 tile, 16-wave block, wave owns
// one oc-16 block, acc[6], rolling-3 B window, 8:1 MFMA:load.
// ---------------------------------------------------------------------------
__global__ __launch_bounds__(1024) void om_conv(
    const unsigned short* __restrict__ comb,
    const unsigned short* __restrict__ Wo,   // [9][256][2][64]
    const float* __restrict__ bias,
    float* __restrict__ om)                  // [z][216][HW]
{
    __shared__ unsigned short sX[144 * 72];
    const int tid = threadIdx.x;
    const int wave = tid >> 6, lane = tid & 63;
    const int m = lane & 15, quad = lane >> 4;
    const int tY = blockIdx.x / 6, tX = blockIdx.x % 6;   // tY 0..15
    const int z = blockIdx.z;
    const unsigned short* cbp = comb + (long)z * HW * 64;

    for (int i = tid; i < 144 * 8; i += 1024) {
        int cell = i >> 3, v = i & 7;
        int row = cell / 18, col = cell - row * 18;
        int gy = tY * 6 + row - 1, gx = tX * 16 + col - 1;
        bf16x8 val = (bf16x8){0,0,0,0,0,0,0,0};
        if (gy >= 0 && gy < HH && gx >= 0 && gx < WW)
            val = *(const bf16x8*)(cbp + (long)(gy * WW + gx) * 64 + v * 8);
        *(bf16x8*)&sX[cell * 72 + v * 8] = val;
    }
    __syncthreads();

    if (wave * 16 >= 216) return;   // oc blocks 14,15 are pure padding

    f32x4 acc[6];
#pragma unroll
    for (int nf = 0; nf < 6; ++nf) acc[nf] = (f32x4){0.f, 0.f, 0.f, 0.f};

#pragma unroll
    for (int c = 0; c < 2; ++c) {
#pragma unroll
        for (int kx = 0; kx < 3; ++kx) {
            bf16x8 Ah[3], Al[3];
#pragma unroll
            for (int ky = 0; ky < 3; ++ky) {
                const unsigned short* wp = Wo + (((long)(ky * 3 + kx) * 256 + wave * 16 + m) * 2) * 64 + c * 32 + quad * 8;
                Ah[ky] = *(const bf16x8*)wp;
                Al[ky] = *(const bf16x8*)(wp + 64);
            }
            bf16x8 B[8];
#pragma unroll
            for (int r = 0; r < 3; ++r)
                B[r] = *(const bf16x8*)&sX[(r * 18 + kx + m) * 72 + c * 32 + quad * 8];
#pragma unroll
            for (int nf = 0; nf < 6; ++nf) {
                if (nf) {
                    int r = nf + 2;
                    B[r] = *(const bf16x8*)&sX[(r * 18 + kx + m) * 72 + c * 32 + quad * 8];
                }
#pragma unroll
                for (int ky = 0; ky < 3; ++ky) {
                    acc[nf] = __builtin_amdgcn_mfma_f32_16x16x32_bf16(Ah[ky], B[nf + ky], acc[nf], 0, 0, 0);
                    acc[nf] = __builtin_amdgcn_mfma_f32_16x16x32_bf16(Al[ky], B[nf + ky], acc[nf], 0, 0, 0);
                }
            }
        }
    }

#pragma unroll
    for (int reg = 0; reg < 4; ++reg) {
        int oc = wave * 16 + quad * 4 + reg;
        if (oc < 216) {
            float bv = bias[oc];
#pragma unroll
            for (int nf = 0; nf < 6; ++nf) {
                int p = (tY * 6 + nf) * WW + tX * 16 + m;
                om[((long)z * 216 + oc) * HW + p] = acc[nf][reg] + bv;
            }
        }
    }
}

// ---------------------------------------------------------------------------
// FUSED deformable-sampling + 1x1 DCN einsum (512 threads, XCD-swizzled).
// hbuf record now [16 groups][hi8|lo8]: each corner's hi+lo is 32B
// contiguous (one 64B line) -> 4 line-touches/thread-tap instead of 8.
// Sampling expressions identical -> bitwise-same output.
// ---------------------------------------------------------------------------
__global__ __launch_bounds__(512) void conv1x1_fused(
    const unsigned short* __restrict__ hbuf,  // [4][p][16][2][8] group-interleaved
    const float* __restrict__ om,             // [4][216][HW]
    const unsigned short* __restrict__ w1,    // [128][2][576] k-major
    const float* __restrict__ bias,
    unsigned short* __restrict__ fused)       // [z][p][256] hl
{
    __shared__ unsigned short sX[64 * 76];
    const int tid  = threadIdx.x;
    const int wave = tid >> 6, lane = tid & 63;
    const int m = lane & 15, quad = lane >> 4;

    // bijective XCD swizzle over 576 = 8 XCDs x 72 chunks
    const int bid = blockIdx.x;
    const int work = (bid & 7) * 72 + (bid >> 3);
    const int zz = work / 144;
    const int pt = work - zz * 144;

    const float* omb = om + (long)zz * 216 * HW;
    const unsigned short* hz = hbuf + (long)zz * HW * 128;

    const int g0 = tid >> 6;        // 0..7  (channel group; = wave)
    const int cellb = tid & 63;     // 0..63 (pixel within tile)

    // Bilinear-sample 8 channels (group g0) at pixel p=pt*64+cell, tap cb.
    // Expression-identical to the old dcn_sample_kernel -> bitwise-same bf16.
    auto sample = [&](int cell, int cb) -> bf16x8 {
        int p = pt * 64 + cell;
        int y = p / WW, x = p - y * WW;
        int ky = cb / 3, kx = cb - ky * 3;
        float offy = omb[(g0 * 18 + cb * 2) * HW + p];
        float offx = omb[(g0 * 18 + cb * 2 + 1) * HW + p];
        float mm = sigf(omb[(144 + g0 * 9 + cb) * HW + p]);
        float py = (float)(y + ky - 1) + offy;
        float px = (float)(x + kx - 1) + offx;
        float y0f = floorf(py), x0f = floorf(px);
        float wy = py - y0f, wx = px - x0f;
        int y0 = (int)y0f, x0 = (int)x0f;
        int y1 = y0 + 1, x1 = x0 + 1;
        bool vy0 = (y0 >= 0) && (y0 < HH), vy1 = (y1 >= 0) && (y1 < HH);
        bool vx0 = (x0 >= 0) && (x0 < WW), vx1 = (x1 >= 0) && (x1 < WW);
        int cy0 = min(max(y0, 0), HH - 1), cy1 = min(max(y1, 0), HH - 1);
        int cx0 = min(max(x0, 0), WW - 1), cx1 = min(max(x1, 0), WW - 1);
        long i00 = cy0 * WW + cx0, i01 = cy0 * WW + cx1;
        long i10 = cy1 * WW + cx0, i11 = cy1 * WW + cx1;
        float w00 = (1.f - wy) * (1.f - wx) * ((vy0 && vx0) ? mm : 0.f);
        float w01 = (1.f - wy) * wx         * ((vy0 && vx1) ? mm : 0.f);
        float w10 = wy * (1.f - wx)         * ((vy1 && vx0) ? mm : 0.f);
        float w11 = wy * wx                 * ((vy1 && vx1) ? mm : 0.f);
        // group-interleaved record: hi at p*128 + g0*16, lo at +8 (same 64B line)
        const unsigned short* hzb = hz + g0 * 16;
        bf16x8 h00 = *(const bf16x8*)(hzb + i00 * 128);
        bf16x8 l00 = *(const bf16x8*)(hzb + i00 * 128 + 8);
        bf16x8 h01 = *(const bf16x8*)(hzb + i01 * 128);
        bf16x8 l01 = *(const bf16x8*)(hzb + i01 * 128 + 8);
        bf16x8 h10 = *(const bf16x8*)(hzb + i10 * 128);
        bf16x8 l10 = *(const bf16x8*)(hzb + i10 * 128 + 8);
        bf16x8 h11 = *(const bf16x8*)(hzb + i11 * 128);
        bf16x8 l11 = *(const bf16x8*)(hzb + i11 * 128 + 8);
        bf16x8 outv;
#pragma unroll
        for (int cg = 0; cg < 8; ++cg) {
            float v00 = b2f((unsigned short)h00[cg]) + b2f((unsigned short)l00[cg]);
            float v01 = b2f((unsigned short)h01[cg]) + b2f((unsigned short)l01[cg]);
            float v10 = b2f((unsigned short)h10[cg]) + b2f((unsigned short)l10[cg]);
            float v11 = b2f((unsigned short)h11[cg]) + b2f((unsigned short)l11[cg]);
            float v = w00 * v00 + w01 * v01 + w10 * v10 + w11 * v11;
            outv[cg] = (short)bhi(v);
        }
        return outv;
    };

    f32x4 acc[4];
#pragma unroll
    for (int nf = 0; nf < 4; ++nf) acc[nf] = (f32x4){0.f, 0.f, 0.f, 0.f};

    for (int cb = 0; cb < 9; ++cb) {
        if (cb) __syncthreads();
        bf16x8 R0 = sample(cellb, cb);
        *(bf16x8*)&sX[cellb * 76 + g0 * 8] = R0;
        __syncthreads();

        bf16x8 Bv[2][4];
#pragma unroll
        for (int sub = 0; sub < 2; ++sub)
#pragma unroll
            for (int nf = 0; nf < 4; ++nf)
                Bv[sub][nf] = *(const bf16x8*)&sX[(nf * 16 + m) * 76 + sub * 32 + quad * 8];
        bf16x8 Ah[2], Al[2];
#pragma unroll
        for (int sub = 0; sub < 2; ++sub) {
            const unsigned short* wp = w1 + ((long)(wave * 16 + m) * 2) * 576
                                       + cb * 64 + sub * 32 + quad * 8;
            Ah[sub] = *(const bf16x8*)wp;
            Al[sub] = *(const bf16x8*)(wp + 576);
        }
#pragma unroll
        for (int sub = 0; sub < 2; ++sub)
#pragma unroll
            for (int nf = 0; nf < 4; ++nf) {
                acc[nf] = __builtin_amdgcn_mfma_f32_16x16x32_bf16(
                    Ah[sub], Bv[sub][nf], acc[nf], 0, 0, 0);
                acc[nf] = __builtin_amdgcn_mfma_f32_16x16x32_bf16(
                    Al[sub], Bv[sub][nf], acc[nf], 0, 0, 0);
            }
    }

    {
        int ocl = wave * 16 + quad * 4;
        float b0 = bias[ocl], b1 = bias[ocl + 1], b2 = bias[ocl + 2], b3 = bias[ocl + 3];
#pragma unroll
        for (int nf = 0; nf < 4; ++nf) {
            int p = pt * 64 + nf * 16 + m;
            float v0 = fmaxf(acc[nf].x + b0, 0.f);
            float v1 = fmaxf(acc[nf].y + b1, 0.f);
            float v2 = fmaxf(acc[nf].z + b2, 0.f);
            float v3 = fmaxf(acc[nf].w + b3, 0.f);
            unsigned short* op = fused + ((long)zz * HW + p) * 256 + ocl;
            ushort4 hv, lv;
            hv.x = bhi(v0); hv.y = bhi(v1); hv.z = bhi(v2); hv.w = bhi(v3);
            lv.x = blo(v0); lv.y = blo(v1); lv.z = blo(v2); lv.w = blo(v3);
            *(ushort4*)op = hv;
            *(ushort4*)(op + 128) = lv;
        }
    }
}

// ---------------------------------------------------------------------------
// Big conv (IC=128 hl, OC=256) FUSED with LSTM gates.
// 16-wave blocks (1024 thr), 6x16 tile, 384 blocks. R8-measured 102us.
// hbuf write updated to the group-interleaved record (hi at group*16+off,
// lo at +8) — pure relocation, same values.
// ---------------------------------------------------------------------------
__global__ __launch_bounds__(1024) void big_conv_gates(
    const unsigned short* __restrict__ fusedb,  // [z][p][256] hl
    const unsigned short* __restrict__ Wc,      // [9][256][2][128]
    const float* __restrict__ bias,
    float* __restrict__ cst,                    // [z][p][64] fp32
    unsigned short* __restrict__ hbuf,          // [z][p][16][2][8] group-interleaved
    unsigned short* __restrict__ hseq,          // [(t*2+b)][p][128]
    int t0, int t1)
{
    // 39168 ush = 78336 B. Staging: 144 cells x 264 = 38016 ush (76032 B).
    // Gates: 3 regions x 96 px x 68 floats = 19584 floats = 78336 B.
    __shared__ unsigned short sX[39168];
    const int tid = threadIdx.x;
    const int wave = tid >> 6, lane = tid & 63;
    const int m = lane & 15, quad = lane >> 4;
    const int tY = blockIdx.x / 6, tX = blockIdx.x % 6;   // tY 0..15
    const int z = blockIdx.z;

    const unsigned short* fb = fusedb + (long)z * HW * 256;

    for (int i = tid; i < 144 * 32; i += 1024) {
        int cell = i >> 5, v = i & 31;
        int row = cell / 18, col = cell - row * 18;
        int gy = tY * 6 + row - 1, gx = tX * 16 + col - 1;
        int pl = v >> 4, c = (v & 15) >> 2, g = v & 3;
        bf16x8 val = (bf16x8){0,0,0,0,0,0,0,0};
        if (gy >= 0 && gy < HH && gx >= 0 && gx < WW)
            val = *(const bf16x8*)(fb + (long)(gy * WW + gx) * 256 + pl * 128 + c * 32 + g * 8);
        *(bf16x8*)&sX[cell * 264 + (c * 2 + pl) * 32 + g * 8] = val;
    }
    __syncthreads();

    f32x4 acc[6];
#pragma unroll
    for (int nf = 0; nf < 6; ++nf) acc[nf] = (f32x4){0.f, 0.f, 0.f, 0.f};

#pragma unroll
    for (int c = 0; c < 4; ++c) {
#pragma unroll
        for (int kx = 0; kx < 3; ++kx) {
            bf16x8 Ah[3], Al[3];
#pragma unroll
            for (int ky = 0; ky < 3; ++ky) {
                const unsigned short* wp = Wc + (((long)(ky * 3 + kx) * 256 + wave * 16 + m) * 2) * 128 + c * 32 + quad * 8;
                Ah[ky] = *(const bf16x8*)wp;
                Al[ky] = *(const bf16x8*)(wp + 128);
            }
            bf16x8 Bh[8], Bl[8];
#pragma unroll
            for (int r = 0; r < 3; ++r) {
                int base = (r * 18 + kx + m) * 264 + (c * 2) * 32 + quad * 8;
                Bh[r] = *(const bf16x8*)&sX[base];
                Bl[r] = *(const bf16x8*)&sX[base + 32];
            }
            // nf-outer, rolling 3-row B window: row nf+2 loaded at nf>0, rows
            // < nf dead -> ~6 live B regs. Per-acc (ky, term) order unchanged.
#pragma unroll
            for (int nf = 0; nf < 6; ++nf) {
                if (nf) {
                    int r = nf + 2;
                    int base = (r * 18 + kx + m) * 264 + (c * 2) * 32 + quad * 8;
                    Bh[r] = *(const bf16x8*)&sX[base];
                    Bl[r] = *(const bf16x8*)&sX[base + 32];
                }
#pragma unroll
                for (int ky = 0; ky < 3; ++ky) {
                    acc[nf] = __builtin_amdgcn_mfma_f32_16x16x32_bf16(Ah[ky], Bh[nf + ky], acc[nf], 0, 0, 0);
                    acc[nf] = __builtin_amdgcn_mfma_f32_16x16x32_bf16(Al[ky], Bh[nf + ky], acc[nf], 0, 0, 0);
                    acc[nf] = __builtin_amdgcn_mfma_f32_16x16x32_bf16(Ah[ky], Bl[nf + ky], acc[nf], 0, 0, 0);
                }
            }
        }
    }

    // ---- gates epilogue ----
    // wave w owns oc block w: ci = w0-3, cf = w4-7, co = w8-11, cg = w12-15.
    float* sG = (float*)sX;
    float ba[4];
    {
        int oc0 = wave * 16 + quad * 4;
#pragma unroll
        for (int r = 0; r < 4; ++r) ba[r] = bias[oc0 + r];
    }
    __syncthreads();
    if (wave >= 4) {
        int reg = (wave >> 2) - 1;            // 0=cf, 1=co, 2=cg
        int chb = (wave & 3) * 16 + quad * 4;
#pragma unroll
        for (int nf = 0; nf < 6; ++nf) {
            int px = nf * 16 + m;
            float* f = &sG[reg * 96 * 68 + (long)px * 68 + chb];
#pragma unroll
            for (int r = 0; r < 4; ++r) f[r] = acc[nf][r] + ba[r];
        }
    }
    __syncthreads();
    if (wave < 4) {
        int t = (z < 2) ? t0 : t1;
        int b = z & 1, dir = z >> 1;
        int chb = wave * 16 + quad * 4;
        unsigned short* hsq = hseq + ((long)(t * 2 + b) * HW) * 128 + dir * 64;
#pragma unroll
        for (int nf = 0; nf < 6; ++nf) {
            int px = nf * 16 + m;
            int p = (tY * 6 + nf) * WW + tX * 16 + m;
            float4 cf4 = *(float4*)&sG[0 * 96 * 68 + (long)px * 68 + chb];
            float4 co4 = *(float4*)&sG[1 * 96 * 68 + (long)px * 68 + chb];
            float4 cg4 = *(float4*)&sG[2 * 96 * 68 + (long)px * 68 + chb];
            float* cp = &cst[((long)z * HW + p) * 64 + chb];
            float4 cold = *(float4*)cp;
            float cfv[4] = {cf4.x, cf4.y, cf4.z, cf4.w};
            float cov[4] = {co4.x, co4.y, co4.z, co4.w};
            float cgv[4] = {cg4.x, cg4.y, cg4.z, cg4.w};
            float coldv[4] = {cold.x, cold.y, cold.z, cold.w};
            float c2v[4], h2v[4];
#pragma unroll
            for (int r = 0; r < 4; ++r) {
                float civ = acc[nf][r] + ba[r];
                float c2 = sigf(cfv[r]) * coldv[r] + sigf(civ) * tanhf(cgv[r]);
                float h2 = sigf(cov[r]) * tanhf(c2);
                c2v[r] = c2; h2v[r] = h2;
            }
            *(float4*)cp = (float4){c2v[0], c2v[1], c2v[2], c2v[3]};
            // group-interleaved hbuf record: hi at group*16 + (chb&7), lo at +8
            unsigned short* hp = hbuf + ((long)z * HW + p) * 128 + (chb >> 3) * 16 + (chb & 7);
            ushort4 hv = {bhi(h2v[0]), bhi(h2v[1]), bhi(h2v[2]), bhi(h2v[3])};
            ushort4 lv = {blo(h2v[0]), blo(h2v[1]), blo(h2v[2]), blo(h2v[3])};
            *(ushort4*)hp = hv;
            *(ushort4*)(hp + 8) = lv;
            *(ushort4*)&hsq[(long)p * 128 + chb] = hv;
        }
    }
}

// ---------------------------------------------------------------------------
// cat conv: hseq (single-plane, IC=128) -> out fp32 NCHW with (t,b) permute.
// 6x16 tile: grid 96x10 = 960 blocks, acc[6], rolling-B.
// ---------------------------------------------------------------------------
__global__ __launch_bounds__(256) void cat_conv(
    const unsigned short* __restrict__ hseq,
    const unsigned short* __restrict__ Wk,     // [9][64][2][128]
    const float* __restrict__ bias,
    float* __restrict__ out)
{
    __shared__ unsigned short sX[144 * 136];
    const int tid = threadIdx.x;
    const int wave = tid >> 6, lane = tid & 63;
    const int m = lane & 15, quad = lane >> 4;
    const int tY = blockIdx.x / 6, tX = blockIdx.x % 6;   // tY 0..15
    const int img = blockIdx.z;
    const unsigned short* hp = hseq + (long)img * HW * 128;

    for (int i = tid; i < 144 * 16; i += 256) {
        int cell = i >> 4, v = i & 15;
        int row = cell / 18, col = cell - row * 18;
        int gy = tY * 6 + row - 1, gx = tX * 16 + col - 1;
        bf16x8 val = (bf16x8){0,0,0,0,0,0,0,0};
        if (gy >= 0 && gy < HH && gx >= 0 && gx < WW)
            val = *(const bf16x8*)(hp + (long)(gy * WW + gx) * 128 + v * 8);
        *(bf16x8*)&sX[cell * 136 + v * 8] = val;
    }
    __syncthreads();

    f32x4 acc[6];
#pragma unroll
    for (int nf = 0; nf < 6; ++nf) acc[nf] = (f32x4){0.f, 0.f, 0.f, 0.f};

#pragma unroll
    for (int c = 0; c < 4; ++c) {
#pragma unroll
        for (int kx = 0; kx < 3; ++kx) {
            bf16x8 Ah[3], Al[3];
#pragma unroll
            for (int ky = 0; ky < 3; ++ky) {
                const unsigned short* wp = Wk + (((long)(ky * 3 + kx) * 64 + wave * 16 + m) * 2) * 128 + c * 32 + quad * 8;
                Ah[ky] = *(const bf16x8*)wp;
                Al[ky] = *(const bf16x8*)(wp + 128);
            }
            bf16x8 B[8];
#pragma unroll
            for (int r = 0; r < 3; ++r)
                B[r] = *(const bf16x8*)&sX[(r * 18 + kx + m) * 136 + c * 32 + quad * 8];
#pragma unroll
            for (int nf = 0; nf < 6; ++nf) {
                if (nf) {
                    int r = nf + 2;
                    B[r] = *(const bf16x8*)&sX[(r * 18 + kx + m) * 136 + c * 32 + quad * 8];
                }
#pragma unroll
                for (int ky = 0; ky < 3; ++ky) {
                    acc[nf] = __builtin_amdgcn_mfma_f32_16x16x32_bf16(Ah[ky], B[nf + ky], acc[nf], 0, 0, 0);
                    acc[nf] = __builtin_amdgcn_mfma_f32_16x16x32_bf16(Al[ky], B[nf + ky], acc[nf], 0, 0, 0);
                }
            }
        }
    }

    int t = img >> 1, b = img & 1;
    long imgOut = (long)(b * TT + t) * 64 * HW;
#pragma unroll
    for (int reg = 0; reg < 4; ++reg) {
        int oc = wave * 16 + quad * 4 + reg;
        float bv = bias[oc];
#pragma unroll
        for (int nf = 0; nf < 6; ++nf) {
            int p = (tY * 6 + nf) * WW + tX * 16 + m;
            out[imgOut + (long)oc * HW + p] = acc[nf][reg] + bv;
        }
    }
}

// ---------------------------------------------------------------------------
extern "C" void kernel_launch(void* const* d_in, const int* in_sizes, int n_in,
                              void* d_out, int out_size, void* d_ws, size_t ws_size,
                              hipStream_t stream)
{
    const float* input  = (const float*)d_in[0];
    const float* fuse_w = (const float*)d_in[1];
    const float* fuse_b = (const float*)d_in[2];
    const float* om_w   = (const float*)d_in[3];
    const float* om_b   = (const float*)d_in[4];
    const float* dcn_w  = (const float*)d_in[5];
    const float* dcn_b  = (const float*)d_in[6];
    const float* conv_w = (const float*)d_in[7];
    const float* conv_b = (const float*)d_in[8];
    const float* cat_w  = (const float*)d_in[9];
    const float* cat_b  = (const float*)d_in[10];
    float* out = (float*)d_out;

    char* w = (char*)d_ws;
    size_t off = 0;
    auto alloc = [&](size_t bytes) { void* p = w + off; off += (bytes + 255) & ~(size_t)255; return p; };

    unsigned short* xbf    = (unsigned short*)alloc(10L * HW * 64 * 2);
    unsigned short* hbuf   = (unsigned short*)alloc(4L * HW * 128 * 2);
    unsigned short* comb   = (unsigned short*)alloc(4L * HW * 64 * 2);
    float*          omb    = (float*)alloc(4L * 216 * HW * 4);
    unsigned short* fusedb = (unsigned short*)alloc(4L * HW * 256 * 2);
    float*          cbufs  = (float*)alloc(4L * HW * 64 * 4);
    unsigned short* hseqb  = (unsigned short*)alloc(10L * HW * 128 * 2);
    unsigned short* Wf = (unsigned short*)alloc(9L * 64 * 2 * 128 * 2);
    unsigned short* Wo = (unsigned short*)alloc(9L * 256 * 2 * 64 * 2);
    unsigned short* Wc = (unsigned short*)alloc(9L * 256 * 2 * 128 * 2);
    unsigned short* Wk = (unsigned short*)alloc(9L * 64 * 2 * 128 * 2);
    unsigned short* W1 = (unsigned short*)alloc(128L * 2 * 576 * 2);

    dim3 blk(256);
    wexp3_kernel<<<dim3(288), blk, 0, stream>>>(fuse_w, Wf, 64, 64, 128);
    wexp3_kernel<<<dim3(576), blk, 0, stream>>>(om_w, Wo, 216, 256, 64);
    wexp3_kernel<<<dim3(1152), blk, 0, stream>>>(conv_w, Wc, 256, 256, 128);
    wexp3_kernel<<<dim3(288), blk, 0, stream>>>(cat_w, Wk, 64, 64, 128);
    wexp1_kernel<<<dim3(288), blk, 0, stream>>>(dcn_w, W1);
    xprep_kernel<<<dim3(23040), blk, 0, stream>>>(input, xbf);

    hipMemsetAsync(hbuf, 0, 4L * HW * 128 * 2, stream);
    hipMemsetAsync(cbufs, 0, 4L * HW * 64 * 4, stream);

    for (int s = 0; s < TT; ++s) {
        int t0 = s, t1 = TT - 1 - s;
        fuse_conv<<<dim3(96, 1, 4), blk, 0, stream>>>(
            xbf, hbuf, Wf, fuse_b, comb, t0, t1);
        om_conv<<<dim3(96, 1, 4), dim3(1024), 0, stream>>>(
            comb, Wo, om_b, omb);
        conv1x1_fused<<<dim3(576), dim3(512), 0, stream>>>(
            hbuf, omb, W1, dcn_b, fusedb);
        big_conv_gates<<<dim3(96, 1, 4), dim3(1024), 0, stream>>>(
            fusedb, Wc, conv_b, cbufs, hbuf, hseqb, t0, t1);
    }
    cat_conv<<<dim3(96, 1, 10), blk, 0, stream>>>(hseqb, Wk, cat_b, out);
}

// Round 16
// 1291.937 us; speedup vs baseline: 1.4593x; 1.0713x over previous
//
#include <hip/hip_runtime.h>
#include <math.h>

#define HH 96
#define WW 96
#define HW 9216
#define TT 5

typedef __attribute__((ext_vector_type(8))) short bf16x8;
typedef __attribute__((ext_vector_type(4))) float f32x4;

__device__ __forceinline__ float sigf(float x) { return 1.0f / (1.0f + expf(-x)); }
__device__ __forceinline__ unsigned short bhi(float x) {
    return (unsigned short)(__float_as_uint(x) >> 16);
}
__device__ __forceinline__ unsigned short blo(float x) {
    float h = __uint_as_float(__float_as_uint(x) & 0xffff0000u);
    return (unsigned short)(__float_as_uint(x - h) >> 16);
}
__device__ __forceinline__ float b2f(unsigned short u) {
    return __uint_as_float(((unsigned)u) << 16);
}

// ---------------------------------------------------------------------------
// Weight expansion: src [OC][IC][9] fp32 -> dst [9][OCP][2][IC] bf16 hi/lo.
// ---------------------------------------------------------------------------
__global__ __launch_bounds__(256) void wexp3_kernel(
    const float* __restrict__ w, unsigned short* __restrict__ dst,
    int OC, int OCP, int IC)
{
    long i = (long)blockIdx.x * 256 + threadIdx.x;
    int ic = (int)(i % IC);
    long r = i / IC;
    int oc = (int)(r % OCP);
    int tap = (int)(r / OCP);
    float v = (oc < OC) ? w[((long)oc * IC + ic) * 9 + tap] : 0.f;
    long base = (((long)tap * OCP + oc) * 2) * IC + ic;
    dst[base] = bhi(v);
    dst[base + IC] = blo(v);
}

// dcn_w [128][576] (576 = c*9+k) -> [128][2][576] with K re-ordered k-major:
// dst K-slot (k*64 + c) = src (c*9 + k).
__global__ __launch_bounds__(256) void wexp1_kernel(
    const float* __restrict__ w, unsigned short* __restrict__ dst)
{
    int i = blockIdx.x * 256 + threadIdx.x;   // over 128*576 dst slots
    int slot = i % 576;                        // k*64 + c
    int oc = i / 576;
    int k = slot >> 6, c = slot & 63;
    float v = w[(long)oc * 576 + c * 9 + k];
    dst[((long)oc * 2) * 576 + slot] = bhi(v);
    dst[((long)oc * 2 + 1) * 576 + slot] = blo(v);
}

// input [b][t][64][HW] fp32 -> xbf [(t*2+b)][p][64] bf16
__global__ __launch_bounds__(256) void xprep_kernel(
    const float* __restrict__ input, unsigned short* __restrict__ xbf)
{
    long i = (long)blockIdx.x * 256 + threadIdx.x;
    int p = (int)(i % HW);
    long r = i / HW;
    int c = (int)(r % 64);
    long bt = r / 64;
    int b = (int)(bt / TT), t = (int)(bt % TT);
    float v = input[i];
    xbf[(((long)(t * 2 + b) * HW) + p) * 64 + c] = bhi(v);
}

// ===========================================================================
// R16: big_conv_gates Z-PAIR weight amortization. Grid 384 (1.5 blk/CU,
// critical path = 2-block CUs each streaming 2x1.18MB Wc) -> 192 blocks:
// one block = one 6x16 tile x TWO z-planes (z, z+2), both staged in LDS
// (2x76KB = 148.5KB, 1 blk/CU). Each (c,kx)'s 6 weight fragments load ONCE
// for 108 MFMAs (18:1 vs 9:1). Wc stream 453->227MB; critical-path weight
// loads halved. acc[2][6]=48 f32 may spill (R4 precedent: tolerable).
// Per-acc accumulation order unchanged -> bitwise-identical.
// ===========================================================================

// ---------------------------------------------------------------------------
// Fuse conv: x (single, ic 0..63) + h (hl, ic 64..127) -> comb bf16 NHWC.
// 6x16 tile, 4 waves, wave owns one oc-16 block. acc[6]=24 VGPR, rolling-B.
// ---------------------------------------------------------------------------
__global__ __launch_bounds__(256) void fuse_conv(
    const unsigned short* __restrict__ xbf,
    const unsigned short* __restrict__ hbuf,
    const unsigned short* __restrict__ Wf,   // [9][64][2][128]
    const float* __restrict__ bias,
    unsigned short* __restrict__ comb,
    int t0, int t1)
{
    __shared__ unsigned short sX[144 * 200];
    const int tid = threadIdx.x;
    const int wave = tid >> 6, lane = tid & 63;
    const int m = lane & 15, quad = lane >> 4;
    const int tY = blockIdx.x / 6, tX = blockIdx.x % 6;   // tY 0..15
    const int z = blockIdx.z;
    const int imgX = ((z < 2) ? t0 : t1) * 2 + (z & 1);

    const unsigned short* xb = xbf + (long)imgX * HW * 64;
    const unsigned short* hb = hbuf + (long)z * HW * 128;

    for (int i = tid; i < 144 * 24; i += 256) {
        int cell = i / 24, v = i - cell * 24;
        int row = cell / 18, col = cell - row * 18;
        int gy = tY * 6 + row - 1, gx = tX * 16 + col - 1;
        bool ok = (gy >= 0 && gy < HH && gx >= 0 && gx < WW);
        int p = gy * WW + gx;
        bf16x8 val = (bf16x8){0,0,0,0,0,0,0,0};
        int dst;
        if (v < 8) {
            if (ok) val = *(const bf16x8*)(xb + (long)p * 64 + v * 8);
            dst = cell * 200 + v * 8;
        } else {
            int v2 = v - 8;
            int pl = v2 >> 3, c = (v2 & 7) >> 2, g = v2 & 3;
            // hbuf record: [16 groups][hi8|lo8]; channels c*32+g*8 = group c*4+g
            if (ok) val = *(const bf16x8*)(hb + (long)p * 128 + (c * 4 + g) * 16 + pl * 8);
            dst = cell * 200 + 64 + (c * 2 + pl) * 32 + g * 8;
        }
        *(bf16x8*)&sX[dst] = val;
    }
    __syncthreads();

    f32x4 acc[6];
#pragma unroll
    for (int nf = 0; nf < 6; ++nf) acc[nf] = (f32x4){0.f, 0.f, 0.f, 0.f};

    // part 1: x channels (single precision), c = 0,1
#pragma unroll
    for (int c = 0; c < 2; ++c) {
#pragma unroll
        for (int kx = 0; kx < 3; ++kx) {
            bf16x8 Ah[3], Al[3];
#pragma unroll
            for (int ky = 0; ky < 3; ++ky) {
                const unsigned short* wp = Wf + (((long)(ky * 3 + kx) * 64 + wave * 16 + m) * 2) * 128 + c * 32 + quad * 8;
                Ah[ky] = *(const bf16x8*)wp;
                Al[ky] = *(const bf16x8*)(wp + 128);
            }
            bf16x8 B[8];
#pragma unroll
            for (int r = 0; r < 3; ++r)
                B[r] = *(const bf16x8*)&sX[(r * 18 + kx + m) * 200 + c * 32 + quad * 8];
#pragma unroll
            for (int nf = 0; nf < 6; ++nf) {
                if (nf) {
                    int r = nf + 2;
                    B[r] = *(const bf16x8*)&sX[(r * 18 + kx + m) * 200 + c * 32 + quad * 8];
                }
#pragma unroll
                for (int ky = 0; ky < 3; ++ky) {
                    acc[nf] = __builtin_amdgcn_mfma_f32_16x16x32_bf16(Ah[ky], B[nf + ky], acc[nf], 0, 0, 0);
                    acc[nf] = __builtin_amdgcn_mfma_f32_16x16x32_bf16(Al[ky], B[nf + ky], acc[nf], 0, 0, 0);
                }
            }
        }
    }
    // part 2: h channels (hl), c = 0,1
#pragma unroll
    for (int c = 0; c < 2; ++c) {
#pragma unroll
        for (int kx = 0; kx < 3; ++kx) {
            bf16x8 Ah[3], Al[3];
#pragma unroll
            for (int ky = 0; ky < 3; ++ky) {
                const unsigned short* wp = Wf + (((long)(ky * 3 + kx) * 64 + wave * 16 + m) * 2) * 128 + (2 + c) * 32 + quad * 8;
                Ah[ky] = *(const bf16x8*)wp;
                Al[ky] = *(const bf16x8*)(wp + 128);
            }
            bf16x8 Bh[8], Bl[8];
#pragma unroll
            for (int r = 0; r < 3; ++r) {
                int base = (r * 18 + kx + m) * 200 + 64 + (c * 2) * 32 + quad * 8;
                Bh[r] = *(const bf16x8*)&sX[base];
                Bl[r] = *(const bf16x8*)&sX[base + 32];
            }
#pragma unroll
            for (int nf = 0; nf < 6; ++nf) {
                if (nf) {
                    int r = nf + 2;
                    int base = (r * 18 + kx + m) * 200 + 64 + (c * 2) * 32 + quad * 8;
                    Bh[r] = *(const bf16x8*)&sX[base];
                    Bl[r] = *(const bf16x8*)&sX[base + 32];
                }
#pragma unroll
                for (int ky = 0; ky < 3; ++ky) {
                    acc[nf] = __builtin_amdgcn_mfma_f32_16x16x32_bf16(Ah[ky], Bh[nf + ky], acc[nf], 0, 0, 0);
                    acc[nf] = __builtin_amdgcn_mfma_f32_16x16x32_bf16(Al[ky], Bh[nf + ky], acc[nf], 0, 0, 0);
                    acc[nf] = __builtin_amdgcn_mfma_f32_16x16x32_bf16(Ah[ky], Bl[nf + ky], acc[nf], 0, 0, 0);
                }
            }
        }
    }

    int ocl = wave * 16 + quad * 4;
    float b0 = bias[ocl], b1 = bias[ocl + 1], b2 = bias[ocl + 2], b3 = bias[ocl + 3];
#pragma unroll
    for (int nf = 0; nf < 6; ++nf) {
        int p = (tY * 6 + nf) * WW + tX * 16 + m;
        ushort4 hv;
        hv.x = bhi(acc[nf].x + b0); hv.y = bhi(acc[nf].y + b1);
        hv.z = bhi(acc[nf].z + b2); hv.w = bhi(acc[nf].w + b3);
        *(ushort4*)&comb[((long)z * HW + p) * 64 + ocl] = hv;
    }
}

// ---------------------------------------------------------------------------
// om conv: comb (single, IC=64) -> om fp32 NCHW (216 of 256 oc).
// R8-recipe clone (R12-measured win): 6x16 tile, 16-wave block, wave owns
// one oc-16 block, acc[6], rolling-3 B window, 8:1 MFMA:load.
// ---------------------------------------------------------------------------
__global__ __launch_bounds__(1024) void om_conv(
    const unsigned short* __restrict__ comb,
    const unsigned short* __restrict__ Wo,   // [9][256][2][64]
    const float* __restrict__ bias,
    float* __restrict__ om)                  // [z][216][HW]
{
    __shared__ unsigned short sX[144 * 72];
    const int tid = threadIdx.x;
    const int wave = tid >> 6, lane = tid & 63;
    const int m = lane & 15, quad = lane >> 4;
    const int tY = blockIdx.x / 6, tX = blockIdx.x % 6;   // tY 0..15
    const int z = blockIdx.z;
    const unsigned short* cbp = comb + (long)z * HW * 64;

    for (int i = tid; i < 144 * 8; i += 1024) {
        int cell = i >> 3, v = i & 7;
        int row = cell / 18, col = cell - row * 18;
        int gy = tY * 6 + row - 1, gx = tX * 16 + col - 1;
        bf16x8 val = (bf16x8){0,0,0,0,0,0,0,0};
        if (gy >= 0 && gy < HH && gx >= 0 && gx < WW)
            val = *(const bf16x8*)(cbp + (long)(gy * WW + gx) * 64 + v * 8);
        *(bf16x8*)&sX[cell * 72 + v * 8] = val;
    }
    __syncthreads();

    if (wave * 16 >= 216) return;   // oc blocks 14,15 are pure padding

    f32x4 acc[6];
#pragma unroll
    for (int nf = 0; nf < 6; ++nf) acc[nf] = (f32x4){0.f, 0.f, 0.f, 0.f};

#pragma unroll
    for (int c = 0; c < 2; ++c) {
#pragma unroll
        for (int kx = 0; kx < 3; ++kx) {
            bf16x8 Ah[3], Al[3];
#pragma unroll
            for (int ky = 0; ky < 3; ++ky) {
                const unsigned short* wp = Wo + (((long)(ky * 3 + kx) * 256 + wave * 16 + m) * 2) * 64 + c * 32 + quad * 8;
                Ah[ky] = *(const bf16x8*)wp;
                Al[ky] = *(const bf16x8*)(wp + 64);
            }
            bf16x8 B[8];
#pragma unroll
            for (int r = 0; r < 3; ++r)
                B[r] = *(const bf16x8*)&sX[(r * 18 + kx + m) * 72 + c * 32 + quad * 8];
#pragma unroll
            for (int nf = 0; nf < 6; ++nf) {
                if (nf) {
                    int r = nf + 2;
                    B[r] = *(const bf16x8*)&sX[(r * 18 + kx + m) * 72 + c * 32 + quad * 8];
                }
#pragma unroll
                for (int ky = 0; ky < 3; ++ky) {
                    acc[nf] = __builtin_amdgcn_mfma_f32_16x16x32_bf16(Ah[ky], B[nf + ky], acc[nf], 0, 0, 0);
                    acc[nf] = __builtin_amdgcn_mfma_f32_16x16x32_bf16(Al[ky], B[nf + ky], acc[nf], 0, 0, 0);
                }
            }
        }
    }

#pragma unroll
    for (int reg = 0; reg < 4; ++reg) {
        int oc = wave * 16 + quad * 4 + reg;
        if (oc < 216) {
            float bv = bias[oc];
#pragma unroll
            for (int nf = 0; nf < 6; ++nf) {
                int p = (tY * 6 + nf) * WW + tX * 16 + m;
                om[((long)z * 216 + oc) * HW + p] = acc[nf][reg] + bv;
            }
        }
    }
}

// ---------------------------------------------------------------------------
// FUSED deformable-sampling + 1x1 DCN einsum (512 threads, XCD-swizzled).
// hbuf record [16 groups][hi8|lo8]: each corner's hi+lo is one 64B line.
// R15-measured win; unchanged.
// ---------------------------------------------------------------------------
__global__ __launch_bounds__(512) void conv1x1_fused(
    const unsigned short* __restrict__ hbuf,  // [4][p][16][2][8] group-interleaved
    const float* __restrict__ om,             // [4][216][HW]
    const unsigned short* __restrict__ w1,    // [128][2][576] k-major
    const float* __restrict__ bias,
    unsigned short* __restrict__ fused)       // [z][p][256] hl
{
    __shared__ unsigned short sX[64 * 76];
    const int tid  = threadIdx.x;
    const int wave = tid >> 6, lane = tid & 63;
    const int m = lane & 15, quad = lane >> 4;

    // bijective XCD swizzle over 576 = 8 XCDs x 72 chunks
    const int bid = blockIdx.x;
    const int work = (bid & 7) * 72 + (bid >> 3);
    const int zz = work / 144;
    const int pt = work - zz * 144;

    const float* omb = om + (long)zz * 216 * HW;
    const unsigned short* hz = hbuf + (long)zz * HW * 128;

    const int g0 = tid >> 6;        // 0..7  (channel group; = wave)
    const int cellb = tid & 63;     // 0..63 (pixel within tile)

    // Bilinear-sample 8 channels (group g0) at pixel p=pt*64+cell, tap cb.
    // Expression-identical to the old dcn_sample_kernel -> bitwise-same bf16.
    auto sample = [&](int cell, int cb) -> bf16x8 {
        int p = pt * 64 + cell;
        int y = p / WW, x = p - y * WW;
        int ky = cb / 3, kx = cb - ky * 3;
        float offy = omb[(g0 * 18 + cb * 2) * HW + p];
        float offx = omb[(g0 * 18 + cb * 2 + 1) * HW + p];
        float mm = sigf(omb[(144 + g0 * 9 + cb) * HW + p]);
        float py = (float)(y + ky - 1) + offy;
        float px = (float)(x + kx - 1) + offx;
        float y0f = floorf(py), x0f = floorf(px);
        float wy = py - y0f, wx = px - x0f;
        int y0 = (int)y0f, x0 = (int)x0f;
        int y1 = y0 + 1, x1 = x0 + 1;
        bool vy0 = (y0 >= 0) && (y0 < HH), vy1 = (y1 >= 0) && (y1 < HH);
        bool vx0 = (x0 >= 0) && (x0 < WW), vx1 = (x1 >= 0) && (x1 < WW);
        int cy0 = min(max(y0, 0), HH - 1), cy1 = min(max(y1, 0), HH - 1);
        int cx0 = min(max(x0, 0), WW - 1), cx1 = min(max(x1, 0), WW - 1);
        long i00 = cy0 * WW + cx0, i01 = cy0 * WW + cx1;
        long i10 = cy1 * WW + cx0, i11 = cy1 * WW + cx1;
        float w00 = (1.f - wy) * (1.f - wx) * ((vy0 && vx0) ? mm : 0.f);
        float w01 = (1.f - wy) * wx         * ((vy0 && vx1) ? mm : 0.f);
        float w10 = wy * (1.f - wx)         * ((vy1 && vx0) ? mm : 0.f);
        float w11 = wy * wx                 * ((vy1 && vx1) ? mm : 0.f);
        // group-interleaved record: hi at p*128 + g0*16, lo at +8 (same 64B line)
        const unsigned short* hzb = hz + g0 * 16;
        bf16x8 h00 = *(const bf16x8*)(hzb + i00 * 128);
        bf16x8 l00 = *(const bf16x8*)(hzb + i00 * 128 + 8);
        bf16x8 h01 = *(const bf16x8*)(hzb + i01 * 128);
        bf16x8 l01 = *(const bf16x8*)(hzb + i01 * 128 + 8);
        bf16x8 h10 = *(const bf16x8*)(hzb + i10 * 128);
        bf16x8 l10 = *(const bf16x8*)(hzb + i10 * 128 + 8);
        bf16x8 h11 = *(const bf16x8*)(hzb + i11 * 128);
        bf16x8 l11 = *(const bf16x8*)(hzb + i11 * 128 + 8);
        bf16x8 outv;
#pragma unroll
        for (int cg = 0; cg < 8; ++cg) {
            float v00 = b2f((unsigned short)h00[cg]) + b2f((unsigned short)l00[cg]);
            float v01 = b2f((unsigned short)h01[cg]) + b2f((unsigned short)l01[cg]);
            float v10 = b2f((unsigned short)h10[cg]) + b2f((unsigned short)l10[cg]);
            float v11 = b2f((unsigned short)h11[cg]) + b2f((unsigned short)l11[cg]);
            float v = w00 * v00 + w01 * v01 + w10 * v10 + w11 * v11;
            outv[cg] = (short)bhi(v);
        }
        return outv;
    };

    f32x4 acc[4];
#pragma unroll
    for (int nf = 0; nf < 4; ++nf) acc[nf] = (f32x4){0.f, 0.f, 0.f, 0.f};

    for (int cb = 0; cb < 9; ++cb) {
        if (cb) __syncthreads();
        bf16x8 R0 = sample(cellb, cb);
        *(bf16x8*)&sX[cellb * 76 + g0 * 8] = R0;
        __syncthreads();

        bf16x8 Bv[2][4];
#pragma unroll
        for (int sub = 0; sub < 2; ++sub)
#pragma unroll
            for (int nf = 0; nf < 4; ++nf)
                Bv[sub][nf] = *(const bf16x8*)&sX[(nf * 16 + m) * 76 + sub * 32 + quad * 8];
        bf16x8 Ah[2], Al[2];
#pragma unroll
        for (int sub = 0; sub < 2; ++sub) {
            const unsigned short* wp = w1 + ((long)(wave * 16 + m) * 2) * 576
                                       + cb * 64 + sub * 32 + quad * 8;
            Ah[sub] = *(const bf16x8*)wp;
            Al[sub] = *(const bf16x8*)(wp + 576);
        }
#pragma unroll
        for (int sub = 0; sub < 2; ++sub)
#pragma unroll
            for (int nf = 0; nf < 4; ++nf) {
                acc[nf] = __builtin_amdgcn_mfma_f32_16x16x32_bf16(
                    Ah[sub], Bv[sub][nf], acc[nf], 0, 0, 0);
                acc[nf] = __builtin_amdgcn_mfma_f32_16x16x32_bf16(
                    Al[sub], Bv[sub][nf], acc[nf], 0, 0, 0);
            }
    }

    {
        int ocl = wave * 16 + quad * 4;
        float b0 = bias[ocl], b1 = bias[ocl + 1], b2 = bias[ocl + 2], b3 = bias[ocl + 3];
#pragma unroll
        for (int nf = 0; nf < 4; ++nf) {
            int p = pt * 64 + nf * 16 + m;
            float v0 = fmaxf(acc[nf].x + b0, 0.f);
            float v1 = fmaxf(acc[nf].y + b1, 0.f);
            float v2 = fmaxf(acc[nf].z + b2, 0.f);
            float v3 = fmaxf(acc[nf].w + b3, 0.f);
            unsigned short* op = fused + ((long)zz * HW + p) * 256 + ocl;
            ushort4 hv, lv;
            hv.x = bhi(v0); hv.y = bhi(v1); hv.z = bhi(v2); hv.w = bhi(v3);
            lv.x = blo(v0); lv.y = blo(v1); lv.z = blo(v2); lv.w = blo(v3);
            *(ushort4*)op = hv;
            *(ushort4*)(op + 128) = lv;
        }
    }
}

// ---------------------------------------------------------------------------
// Big conv (IC=128 hl, OC=256) FUSED with LSTM gates. Z-PAIRED:
// block = one 6x16 tile x two z-planes (zp, zp+2), both staged in LDS
// (2 x 38016 ush = 152064 B, 1 block/CU). Per (c,kx): 6 weight loads feed
// 2x54 = 108 MFMAs (2x amortization). Grid 96x2 = 192 blocks; Wc stream
// halved. acc[2][6] = 48 f32 (spill possible; R4 precedent tolerable).
// Per-acc accumulation order (c,kx,ky,term) unchanged -> bitwise-identical.
// ---------------------------------------------------------------------------
__global__ __launch_bounds__(1024) void big_conv_gates(
    const unsigned short* __restrict__ fusedb,  // [z][p][256] hl
    const unsigned short* __restrict__ Wc,      // [9][256][2][128]
    const float* __restrict__ bias,
    float* __restrict__ cst,                    // [z][p][64] fp32
    unsigned short* __restrict__ hbuf,          // [z][p][16][2][8] group-interleaved
    unsigned short* __restrict__ hseq,          // [(t*2+b)][p][128]
    int t0, int t1)
{
    // 2 planes x 144 cells x 264 ush = 152064 B. Gates region (after both
    // K-loops) reuses the front: 3 x 96 x 68 floats = 78336 B <= 152064.
    __shared__ unsigned short sX[2][144 * 264];
    const int tid = threadIdx.x;
    const int wave = tid >> 6, lane = tid & 63;
    const int m = lane & 15, quad = lane >> 4;
    const int tY = blockIdx.x / 6, tX = blockIdx.x % 6;   // tY 0..15
    const int zp = blockIdx.z;                             // 0,1: z = zp + zi*2

#pragma unroll
    for (int zi = 0; zi < 2; ++zi) {
        const unsigned short* fb = fusedb + (long)(zp + zi * 2) * HW * 256;
        for (int i = tid; i < 144 * 32; i += 1024) {
            int cell = i >> 5, v = i & 31;
            int row = cell / 18, col = cell - row * 18;
            int gy = tY * 6 + row - 1, gx = tX * 16 + col - 1;
            int pl = v >> 4, c = (v & 15) >> 2, g = v & 3;
            bf16x8 val = (bf16x8){0,0,0,0,0,0,0,0};
            if (gy >= 0 && gy < HH && gx >= 0 && gx < WW)
                val = *(const bf16x8*)(fb + (long)(gy * WW + gx) * 256 + pl * 128 + c * 32 + g * 8);
            *(bf16x8*)&sX[zi][cell * 264 + (c * 2 + pl) * 32 + g * 8] = val;
        }
    }
    __syncthreads();

    f32x4 acc[2][6];
#pragma unroll
    for (int zi = 0; zi < 2; ++zi)
#pragma unroll
        for (int nf = 0; nf < 6; ++nf) acc[zi][nf] = (f32x4){0.f, 0.f, 0.f, 0.f};

#pragma unroll
    for (int c = 0; c < 4; ++c) {
#pragma unroll
        for (int kx = 0; kx < 3; ++kx) {
            bf16x8 Ah[3], Al[3];
#pragma unroll
            for (int ky = 0; ky < 3; ++ky) {
                const unsigned short* wp = Wc + (((long)(ky * 3 + kx) * 256 + wave * 16 + m) * 2) * 128 + c * 32 + quad * 8;
                Ah[ky] = *(const bf16x8*)wp;
                Al[ky] = *(const bf16x8*)(wp + 128);
            }
#pragma unroll
            for (int zi = 0; zi < 2; ++zi) {
                bf16x8 Bh[8], Bl[8];
#pragma unroll
                for (int r = 0; r < 3; ++r) {
                    int base = (r * 18 + kx + m) * 264 + (c * 2) * 32 + quad * 8;
                    Bh[r] = *(const bf16x8*)&sX[zi][base];
                    Bl[r] = *(const bf16x8*)&sX[zi][base + 32];
                }
#pragma unroll
                for (int nf = 0; nf < 6; ++nf) {
                    if (nf) {
                        int r = nf + 2;
                        int base = (r * 18 + kx + m) * 264 + (c * 2) * 32 + quad * 8;
                        Bh[r] = *(const bf16x8*)&sX[zi][base];
                        Bl[r] = *(const bf16x8*)&sX[zi][base + 32];
                    }
#pragma unroll
                    for (int ky = 0; ky < 3; ++ky) {
                        acc[zi][nf] = __builtin_amdgcn_mfma_f32_16x16x32_bf16(Ah[ky], Bh[nf + ky], acc[zi][nf], 0, 0, 0);
                        acc[zi][nf] = __builtin_amdgcn_mfma_f32_16x16x32_bf16(Al[ky], Bh[nf + ky], acc[zi][nf], 0, 0, 0);
                        acc[zi][nf] = __builtin_amdgcn_mfma_f32_16x16x32_bf16(Ah[ky], Bl[nf + ky], acc[zi][nf], 0, 0, 0);
                    }
                }
            }
        }
    }

    // ---- gates epilogue (per z-plane; gates region reuses staging LDS) ----
    // wave w owns oc block w: ci = w0-3, cf = w4-7, co = w8-11, cg = w12-15.
    float* sG = (float*)&sX[0][0];
    float ba[4];
    {
        int oc0 = wave * 16 + quad * 4;
#pragma unroll
        for (int r = 0; r < 4; ++r) ba[r] = bias[oc0 + r];
    }
#pragma unroll
    for (int zi = 0; zi < 2; ++zi) {
        const int z = zp + zi * 2;
        __syncthreads();   // staging reads (zi=0) / prior gate reads (zi=1) done
        if (wave >= 4) {
            int reg = (wave >> 2) - 1;            // 0=cf, 1=co, 2=cg
            int chb = (wave & 3) * 16 + quad * 4;
#pragma unroll
            for (int nf = 0; nf < 6; ++nf) {
                int px = nf * 16 + m;
                float* f = &sG[reg * 96 * 68 + (long)px * 68 + chb];
#pragma unroll
                for (int r = 0; r < 4; ++r) f[r] = acc[zi][nf][r] + ba[r];
            }
        }
        __syncthreads();
        if (wave < 4) {
            int t = (zi == 0) ? t0 : t1;
            int b = zp & 1, dir = zi;
            int chb = wave * 16 + quad * 4;
            unsigned short* hsq = hseq + ((long)(t * 2 + b) * HW) * 128 + dir * 64;
#pragma unroll
            for (int nf = 0; nf < 6; ++nf) {
                int px = nf * 16 + m;
                int p = (tY * 6 + nf) * WW + tX * 16 + m;
                float4 cf4 = *(float4*)&sG[0 * 96 * 68 + (long)px * 68 + chb];
                float4 co4 = *(float4*)&sG[1 * 96 * 68 + (long)px * 68 + chb];
                float4 cg4 = *(float4*)&sG[2 * 96 * 68 + (long)px * 68 + chb];
                float* cp = &cst[((long)z * HW + p) * 64 + chb];
                float4 cold = *(float4*)cp;
                float cfv[4] = {cf4.x, cf4.y, cf4.z, cf4.w};
                float cov[4] = {co4.x, co4.y, co4.z, co4.w};
                float cgv[4] = {cg4.x, cg4.y, cg4.z, cg4.w};
                float coldv[4] = {cold.x, cold.y, cold.z, cold.w};
                float c2v[4], h2v[4];
#pragma unroll
                for (int r = 0; r < 4; ++r) {
                    float civ = acc[zi][nf][r] + ba[r];
                    float c2 = sigf(cfv[r]) * coldv[r] + sigf(civ) * tanhf(cgv[r]);
                    float h2 = sigf(cov[r]) * tanhf(c2);
                    c2v[r] = c2; h2v[r] = h2;
                }
                *(float4*)cp = (float4){c2v[0], c2v[1], c2v[2], c2v[3]};
                // group-interleaved hbuf record: hi at group*16 + (chb&7), lo at +8
                unsigned short* hp = hbuf + ((long)z * HW + p) * 128 + (chb >> 3) * 16 + (chb & 7);
                ushort4 hv = {bhi(h2v[0]), bhi(h2v[1]), bhi(h2v[2]), bhi(h2v[3])};
                ushort4 lv = {blo(h2v[0]), blo(h2v[1]), blo(h2v[2]), blo(h2v[3])};
                *(ushort4*)hp = hv;
                *(ushort4*)(hp + 8) = lv;
                *(ushort4*)&hsq[(long)p * 128 + chb] = hv;
            }
        }
    }
}

// ---------------------------------------------------------------------------
// cat conv: hseq (single-plane, IC=128) -> out fp32 NCHW with (t,b) permute.
// 6x16 tile: grid 96x10 = 960 blocks, acc[6], rolling-B.
// ---------------------------------------------------------------------------
__global__ __launch_bounds__(256) void cat_conv(
    const unsigned short* __restrict__ hseq,
    const unsigned short* __restrict__ Wk,     // [9][64][2][128]
    const float* __restrict__ bias,
    float* __restrict__ out)
{
    __shared__ unsigned short sX[144 * 136];
    const int tid = threadIdx.x;
    const int wave = tid >> 6, lane = tid & 63;
    const int m = lane & 15, quad = lane >> 4;
    const int tY = blockIdx.x / 6, tX = blockIdx.x % 6;   // tY 0..15
    const int img = blockIdx.z;
    const unsigned short* hp = hseq + (long)img * HW * 128;

    for (int i = tid; i < 144 * 16; i += 256) {
        int cell = i >> 4, v = i & 15;
        int row = cell / 18, col = cell - row * 18;
        int gy = tY * 6 + row - 1, gx = tX * 16 + col - 1;
        bf16x8 val = (bf16x8){0,0,0,0,0,0,0,0};
        if (gy >= 0 && gy < HH && gx >= 0 && gx < WW)
            val = *(const bf16x8*)(hp + (long)(gy * WW + gx) * 128 + v * 8);
        *(bf16x8*)&sX[cell * 136 + v * 8] = val;
    }
    __syncthreads();

    f32x4 acc[6];
#pragma unroll
    for (int nf = 0; nf < 6; ++nf) acc[nf] = (f32x4){0.f, 0.f, 0.f, 0.f};

#pragma unroll
    for (int c = 0; c < 4; ++c) {
#pragma unroll
        for (int kx = 0; kx < 3; ++kx) {
            bf16x8 Ah[3], Al[3];
#pragma unroll
            for (int ky = 0; ky < 3; ++ky) {
                const unsigned short* wp = Wk + (((long)(ky * 3 + kx) * 64 + wave * 16 + m) * 2) * 128 + c * 32 + quad * 8;
                Ah[ky] = *(const bf16x8*)wp;
                Al[ky] = *(const bf16x8*)(wp + 128);
            }
            bf16x8 B[8];
#pragma unroll
            for (int r = 0; r < 3; ++r)
                B[r] = *(const bf16x8*)&sX[(r * 18 + kx + m) * 136 + c * 32 + quad * 8];
#pragma unroll
            for (int nf = 0; nf < 6; ++nf) {
                if (nf) {
                    int r = nf + 2;
                    B[r] = *(const bf16x8*)&sX[(r * 18 + kx + m) * 136 + c * 32 + quad * 8];
                }
#pragma unroll
                for (int ky = 0; ky < 3; ++ky) {
                    acc[nf] = __builtin_amdgcn_mfma_f32_16x16x32_bf16(Ah[ky], B[nf + ky], acc[nf], 0, 0, 0);
                    acc[nf] = __builtin_amdgcn_mfma_f32_16x16x32_bf16(Al[ky], B[nf + ky], acc[nf], 0, 0, 0);
                }
            }
        }
    }

    int t = img >> 1, b = img & 1;
    long imgOut = (long)(b * TT + t) * 64 * HW;
#pragma unroll
    for (int reg = 0; reg < 4; ++reg) {
        int oc = wave * 16 + quad * 4 + reg;
        float bv = bias[oc];
#pragma unroll
        for (int nf = 0; nf < 6; ++nf) {
            int p = (tY * 6 + nf) * WW + tX * 16 + m;
            out[imgOut + (long)oc * HW + p] = acc[nf][reg] + bv;
        }
    }
}

// ---------------------------------------------------------------------------
extern "C" void kernel_launch(void* const* d_in, const int* in_sizes, int n_in,
                              void* d_out, int out_size, void* d_ws, size_t ws_size,
                              hipStream_t stream)
{
    const float* input  = (const float*)d_in[0];
    const float* fuse_w = (const float*)d_in[1];
    const float* fuse_b = (const float*)d_in[2];
    const float* om_w   = (const float*)d_in[3];
    const float* om_b   = (const float*)d_in[4];
    const float* dcn_w  = (const float*)d_in[5];
    const float* dcn_b  = (const float*)d_in[6];
    const float* conv_w = (const float*)d_in[7];
    const float* conv_b = (const float*)d_in[8];
    const float* cat_w  = (const float*)d_in[9];
    const float* cat_b  = (const float*)d_in[10];
    float* out = (float*)d_out;

    char* w = (char*)d_ws;
    size_t off = 0;
    auto alloc = [&](size_t bytes) { void* p = w + off; off += (bytes + 255) & ~(size_t)255; return p; };

    unsigned short* xbf    = (unsigned short*)alloc(10L * HW * 64 * 2);
    unsigned short* hbuf   = (unsigned short*)alloc(4L * HW * 128 * 2);
    unsigned short* comb   = (unsigned short*)alloc(4L * HW * 64 * 2);
    float*          omb    = (float*)alloc(4L * 216 * HW * 4);
    unsigned short* fusedb = (unsigned short*)alloc(4L * HW * 256 * 2);
    float*          cbufs  = (float*)alloc(4L * HW * 64 * 4);
    unsigned short* hseqb  = (unsigned short*)alloc(10L * HW * 128 * 2);
    unsigned short* Wf = (unsigned short*)alloc(9L * 64 * 2 * 128 * 2);
    unsigned short* Wo = (unsigned short*)alloc(9L * 256 * 2 * 64 * 2);
    unsigned short* Wc = (unsigned short*)alloc(9L * 256 * 2 * 128 * 2);
    unsigned short* Wk = (unsigned short*)alloc(9L * 64 * 2 * 128 * 2);
    unsigned short* W1 = (unsigned short*)alloc(128L * 2 * 576 * 2);

    dim3 blk(256);
    wexp3_kernel<<<dim3(288), blk, 0, stream>>>(fuse_w, Wf, 64, 64, 128);
    wexp3_kernel<<<dim3(576), blk, 0, stream>>>(om_w, Wo, 216, 256, 64);
    wexp3_kernel<<<dim3(1152), blk, 0, stream>>>(conv_w, Wc, 256, 256, 128);
    wexp3_kernel<<<dim3(288), blk, 0, stream>>>(cat_w, Wk, 64, 64, 128);
    wexp1_kernel<<<dim3(288), blk, 0, stream>>>(dcn_w, W1);
    xprep_kernel<<<dim3(23040), blk, 0, stream>>>(input, xbf);

    hipMemsetAsync(hbuf, 0, 4L * HW * 128 * 2, stream);
    hipMemsetAsync(cbufs, 0, 4L * HW * 64 * 4, stream);

    for (int s = 0; s < TT; ++s) {
        int t0 = s, t1 = TT - 1 - s;
        fuse_conv<<<dim3(96, 1, 4), blk, 0, stream>>>(
            xbf, hbuf, Wf, fuse_b, comb, t0, t1);
        om_conv<<<dim3(96, 1, 4), dim3(1024), 0, stream>>>(
            comb, Wo, om_b, omb);
        conv1x1_fused<<<dim3(576), dim3(512), 0, stream>>>(
            hbuf, omb, W1, dcn_b, fusedb);
        big_conv_gates<<<dim3(96, 1, 2), dim3(1024), 0, stream>>>(
            fusedb, Wc, conv_b, cbufs, hbuf, hseqb, t0, t1);
    }
    cat_conv<<<dim3(96, 1, 10), blk, 0, stream>>>(hseqb, Wk, cat_b, out);
}